// Round 11
// baseline (2410.911 us; speedup 1.0000x reference)
//
#include <hip/hip_runtime.h>
#include <hip/hip_bf16.h>

#define NG   8
#define LSZ  256
#define NN   2048
#define KK   30
#define EE   61440
#define IND  1280
#define EMB  256
#define V3   15
#define EAP  156
#define QRM  768
#define QRN  5

#define F32_EPS    5.9604645e-08f
#define F32_EPS2   3.5527137e-15f
#define F32_SAFMIN 1.17549435e-38f

__device__ __forceinline__ float bsumf(float v, float* rbuf){
  int t = threadIdx.x;
  __syncthreads();
  rbuf[t] = v;
  __syncthreads();
  for (int s=128; s>0; s>>=1){
    if (t < s) rbuf[t] += rbuf[t+s];
    __syncthreads();
  }
  float r = rbuf[0];
  __syncthreads();
  return r;
}
__device__ __forceinline__ float gelu_f(float x){
  return 0.5f*x*(1.0f + erff(x*0.70710678f));
}
__device__ __forceinline__ float s_sign(float a, float b){ return (b >= 0.0f) ? fabsf(a) : -fabsf(a); }
__device__ __forceinline__ float slapy2(float x, float y){
  float xa = fabsf(x), ya = fabsf(y);
  float w = fmaxf(xa, ya), z = fminf(xa, ya);
  if (z == 0.0f) return w;
  float t = z/w;
  return w*sqrtf(1.0f + t*t);
}
// LAPACK >=3.10 slartg (f32)
__device__ void slartg(float f, float g, float& c, float& s, float& r){
  const float safmin = F32_SAFMIN;
  const float safmax = 8.5070592e+37f;
  const float rtmin  = 1.0842022e-19f;
  const float rtmax  = 6.5243586e+18f;
  float f1 = fabsf(f), g1 = fabsf(g);
  if (g == 0.0f){ c = 1.0f; s = 0.0f; r = f; }
  else if (f == 0.0f){ c = 0.0f; s = (g >= 0.0f ? 1.0f : -1.0f); r = g1; }
  else {
    if (f1 > rtmin && f1 < rtmax && g1 > rtmin && g1 < rtmax){
      float d = sqrtf(f*f + g*g);
      c = f1/d;
      r = (f >= 0.0f ? d : -d);
      s = g/r;
    } else {
      float u = fminf(safmax, fmaxf(safmin, fmaxf(f1,g1)));
      float fs = f/u, gs = g/u;
      float d = sqrtf(fs*fs + gs*gs);
      c = fabsf(fs)/d;
      r = (f >= 0.0f ? d : -d);
      s = gs/r;
      r = r*u;
    }
  }
}
__device__ void slaev2(float a, float b, float c, float& rt1, float& rt2, float& cs1, float& sn1){
  float sm = a + c, df = a - c, adf = fabsf(df), tb = b + b, ab = fabsf(tb);
  float acmx, acmn;
  if (fabsf(a) > fabsf(c)) { acmx=a; acmn=c; } else { acmx=c; acmn=a; }
  float rt;
  if (adf > ab){ float t = ab/adf; rt = adf*sqrtf(1.0f+t*t); }
  else if (adf < ab){ float t = adf/ab; rt = ab*sqrtf(1.0f+t*t); }
  else rt = ab*sqrtf(2.0f);
  int sgn1;
  if (sm < 0.0f){ rt1 = 0.5f*(sm-rt); sgn1 = -1; rt2 = (acmx/rt1)*acmn - (b/rt1)*b; }
  else if (sm > 0.0f){ rt1 = 0.5f*(sm+rt); sgn1 = 1; rt2 = (acmx/rt1)*acmn - (b/rt1)*b; }
  else { rt1 = 0.5f*rt; rt2 = -0.5f*rt; sgn1 = 1; }
  float cs; int sgn2;
  if (df >= 0.0f){ cs = df + rt; sgn2 = 1; } else { cs = df - rt; sgn2 = -1; }
  float acs = fabsf(cs);
  if (acs > ab){
    float ct = -tb/cs; sn1 = 1.0f/sqrtf(1.0f+ct*ct); cs1 = ct*sn1;
  } else {
    if (ab == 0.0f){ cs1 = 1.0f; sn1 = 0.0f; }
    else { float tn = -cs/tb; cs1 = 1.0f/sqrtf(1.0f+tn*tn); sn1 = tn*cs1; }
  }
  if (sgn1 == sgn2){ float tn = cs1; cs1 = -sn1; sn1 = tn; }
}

// f32 ssytd2('L') + ssteqr('I') for 4x4; returns eigvec of largest eigenvalue.
__device__ void sym4_quat_f32(float (&a)[4][4], float* q){
  float d[4], e[3];
  float tau0 = 0.0f, tau1 = 0.0f;
  float v31 = 0.0f, v41 = 0.0f, v42 = 0.0f;
  {
    float alpha = a[1][0];
    float x1 = a[2][0], x2 = a[3][0];
    float xnorm = sqrtf(x1*x1 + x2*x2);
    if (xnorm == 0.0f){ tau0 = 0.0f; e[0] = alpha; }
    else {
      float beta = -s_sign(slapy2(alpha, xnorm), alpha);
      tau0 = (beta - alpha)/beta;
      float sc = 1.0f/(alpha - beta);
      x1 *= sc; x2 *= sc;
      e[0] = beta;
      float p0 = tau0*(a[1][1] + a[2][1]*x1 + a[3][1]*x2);
      float p1 = tau0*(a[2][1] + a[2][2]*x1 + a[3][2]*x2);
      float p2 = tau0*(a[3][1] + a[3][2]*x1 + a[3][3]*x2);
      float al = -0.5f*tau0*(p0 + p1*x1 + p2*x2);
      p0 += al; p1 += al*x1; p2 += al*x2;
      a[1][1] -= 2.0f*p0;
      a[2][1] -= x1*p0 + p1;
      a[3][1] -= x2*p0 + p2;
      a[2][2] -= 2.0f*x1*p1;
      a[3][2] -= x2*p1 + p2*x1;
      a[3][3] -= 2.0f*x2*p2;
    }
    v31 = x1; v41 = x2;
  }
  {
    float alpha = a[2][1];
    float x1 = a[3][1];
    float xnorm = fabsf(x1);
    if (xnorm == 0.0f){ tau1 = 0.0f; e[1] = alpha; }
    else {
      float beta = -s_sign(slapy2(alpha, xnorm), alpha);
      tau1 = (beta - alpha)/beta;
      x1 *= 1.0f/(alpha - beta);
      e[1] = beta;
      float p0 = tau1*(a[2][2] + a[3][2]*x1);
      float p1 = tau1*(a[3][2] + a[3][3]*x1);
      float al = -0.5f*tau1*(p0 + p1*x1);
      p0 += al; p1 += al*x1;
      a[2][2] -= 2.0f*p0;
      a[3][2] -= x1*p0 + p1;
      a[3][3] -= 2.0f*x1*p1;
    }
    v42 = x1;
  }
  e[2] = a[3][2];
  d[0]=a[0][0]; d[1]=a[1][1]; d[2]=a[2][2]; d[3]=a[3][3];
  float z[4][4] = {{1,0,0,0},{0,1,0,0},{0,0,1,0},{0,0,0,1}};
  const float eps = F32_EPS;
  const float eps2 = F32_EPS2;
  const float safmin = F32_SAFMIN;
  int jtot = 0;
  const int nmaxit = 120;
  int l1 = 0;
  bool fail = false;
  while (!fail){
    if (l1 > 3) break;
    if (l1 > 0) e[l1-1] = 0.0f;
    int lend = 3;
    for (int mm = l1; mm <= 2; ++mm){
      float tst = fabsf(e[mm]);
      if (tst == 0.0f){ lend = mm; break; }
      if (tst <= (sqrtf(fabsf(d[mm]))*sqrtf(fabsf(d[mm+1])))*eps){ e[mm] = 0.0f; lend = mm; break; }
    }
    int l = l1;
    int lsv = l, lendsv = lend;
    l1 = lend + 1;
    if (lend == l) continue;
    float anorm = fabsf(d[l]);
    for (int ii=l+1; ii<=lend; ++ii) anorm = fmaxf(anorm, fabsf(d[ii]));
    for (int ii=l; ii<lend; ++ii)    anorm = fmaxf(anorm, fabsf(e[ii]));
    if (anorm == 0.0f) continue;
    if (fabsf(d[lend]) < fabsf(d[l])){ lend = lsv; l = lendsv; }
    if (lend > l){
      for (;;){
        int m = lend;
        if (l != lend){
          for (int mm=l; mm<=lend-1; ++mm){
            float tst = e[mm]*e[mm];
            if (tst <= (eps2*fabsf(d[mm]))*fabsf(d[mm+1]) + safmin){ m = mm; break; }
          }
        }
        if (m < lend) e[m] = 0.0f;
        float p = d[l];
        if (m == l){
          d[l] = p; ++l;
          if (l <= lend) continue;
          break;
        }
        if (m == l+1){
          float rt1, rt2, c, s;
          slaev2(d[l], e[l], d[l+1], rt1, rt2, c, s);
          #pragma unroll
          for (int r2=0;r2<4;r2++){
            float t_ = z[r2][l+1];
            z[r2][l+1] = c*t_ - s*z[r2][l];
            z[r2][l]   = s*t_ + c*z[r2][l];
          }
          d[l]=rt1; d[l+1]=rt2; e[l]=0.0f;
          l += 2;
          if (l <= lend) continue;
          break;
        }
        if (jtot == nmaxit){ fail = true; break; }
        ++jtot;
        float g = (d[l+1]-p)/(2.0f*e[l]);
        float r_ = slapy2(g, 1.0f);
        g = d[m] - p + e[l]/(g + s_sign(r_, g));
        float s = 1.0f, c = 1.0f;
        p = 0.0f;
        float csv[3], snv[3];
        for (int i=m-1; i>=l; --i){
          float f = s*e[i], b = c*e[i];
          slartg(g, f, c, s, r_);
          if (i != m-1) e[i+1] = r_;
          g = d[i+1] - p;
          r_ = (d[i]-g)*s + 2.0f*c*b;
          p = s*r_;
          d[i+1] = g + p;
          g = c*r_ - b;
          csv[i] = c; snv[i] = -s;
        }
        for (int i=m-1; i>=l; --i){
          float cc = csv[i], ss = snv[i];
          #pragma unroll
          for (int r2=0;r2<4;r2++){
            float t_ = z[r2][i+1];
            z[r2][i+1] = cc*t_ - ss*z[r2][i];
            z[r2][i]   = ss*t_ + cc*z[r2][i];
          }
        }
        d[l] -= p; e[l] = g;
      }
    } else {
      for (;;){
        int m = lend;
        if (l != lend){
          for (int mm=l; mm>=lend+1; --mm){
            float tst = e[mm-1]*e[mm-1];
            if (tst <= (eps2*fabsf(d[mm]))*fabsf(d[mm-1]) + safmin){ m = mm; break; }
          }
        }
        if (m > lend) e[m-1] = 0.0f;
        float p = d[l];
        if (m == l){
          d[l] = p; --l;
          if (l >= lend) continue;
          break;
        }
        if (m == l-1){
          float rt1, rt2, c, s;
          slaev2(d[l-1], e[l-1], d[l], rt1, rt2, c, s);
          #pragma unroll
          for (int r2=0;r2<4;r2++){
            float t_ = z[r2][l];
            z[r2][l]   = c*t_ - s*z[r2][l-1];
            z[r2][l-1] = s*t_ + c*z[r2][l-1];
          }
          d[l-1]=rt1; d[l]=rt2; e[l-1]=0.0f;
          l -= 2;
          if (l >= lend) continue;
          break;
        }
        if (jtot == nmaxit){ fail = true; break; }
        ++jtot;
        float g = (d[l-1]-p)/(2.0f*e[l-1]);
        float r_ = slapy2(g, 1.0f);
        g = d[m] - p + e[l-1]/(g + s_sign(r_, g));
        float s = 1.0f, c = 1.0f;
        p = 0.0f;
        float csv[3], snv[3];
        for (int i=m; i<=l-1; ++i){
          float f = s*e[i], b = c*e[i];
          slartg(g, f, c, s, r_);
          if (i != m) e[i-1] = r_;
          g = d[i] - p;
          r_ = (d[i+1]-g)*s + 2.0f*c*b;
          p = s*r_;
          d[i] = g + p;
          g = c*r_ - b;
          csv[i] = c; snv[i] = s;
        }
        for (int i=m; i<=l-1; ++i){
          float cc = csv[i], ss = snv[i];
          #pragma unroll
          for (int r2=0;r2<4;r2++){
            float t_ = z[r2][i+1];
            z[r2][i+1] = cc*t_ - ss*z[r2][i];
            z[r2][i]   = ss*t_ + cc*z[r2][i];
          }
        }
        d[l] -= p; e[l-1] = g;
      }
    }
  }
  for (int ii=1; ii<4; ++ii){
    int i0 = ii-1, k0 = i0;
    float p = d[i0];
    for (int j2=ii; j2<4; ++j2) if (d[j2] < p){ k0 = j2; p = d[j2]; }
    if (k0 != i0){
      d[k0] = d[i0]; d[i0] = p;
      #pragma unroll
      for (int r2=0;r2<4;r2++){ float t_ = z[r2][i0]; z[r2][i0] = z[r2][k0]; z[r2][k0] = t_; }
    }
  }
  float w0 = z[0][3], w1 = z[1][3], w2 = z[2][3], w3 = z[3][3];
  if (tau1 != 0.0f){
    float dv = w2 + v42*w3;
    w2 -= tau1*dv;
    w3 -= tau1*dv*v42;
  }
  if (tau0 != 0.0f){
    float dv = w1 + v31*w2 + v41*w3;
    w1 -= tau0*dv;
    w2 -= tau0*dv*v31;
    w3 -= tau0*dv*v41;
  }
  q[0]=w0; q[1]=w1; q[2]=w2; q[3]=w3;
}

// ---------------- kernels ----------------
__global__ void fill_kernel(float* __restrict__ p, int nelem, float val){
  int i = blockIdx.x*blockDim.x + threadIdx.x;
  if (i < nelem) p[i] = val;
}

__global__ void rigid_kernel(const float* __restrict__ bb, float* __restrict__ Rg, float* __restrict__ tg){
  int n = blockIdx.x*blockDim.x + threadIdx.x;
  if (n >= NN) return;
  const float* p = bb + (size_t)n*9;
  float nx=p[0],ny=p[1],nz=p[2], cax=p[3],cay=p[4],caz=p[5], cx=p[6],cy=p[7],cz=p[8];
  float e1x=cx-cax, e1y=cy-cay, e1z=cz-caz;
  float n1 = sqrtf(e1x*e1x+e1y*e1y+e1z*e1z);
  e1x/=n1; e1y/=n1; e1z/=n1;
  float ux=nx-cax, uy=ny-cay, uz=nz-caz;
  float du = ux*e1x+uy*e1y+uz*e1z;
  float e2x=ux-du*e1x, e2y=uy-du*e1y, e2z=uz-du*e1z;
  float n2 = sqrtf(e2x*e2x+e2y*e2y+e2z*e2z);
  e2x/=n2; e2y/=n2; e2z/=n2;
  float e3x=e1y*e2z-e1z*e2y, e3y=e1z*e2x-e1x*e2z, e3z=e1x*e2y-e1y*e2x;
  float* R = Rg + (size_t)n*9;
  R[0]=e1x; R[1]=e2x; R[2]=e3x;
  R[3]=e1y; R[4]=e2y; R[5]=e3y;
  R[6]=e1z; R[7]=e2z; R[8]=e3z;
  tg[(size_t)n*3+0]=cax; tg[(size_t)n*3+1]=cay; tg[(size_t)n*3+2]=caz;
}

__global__ __launch_bounds__(256) void ln_kernel(const float* __restrict__ x,
    const float* __restrict__ g, const float* __restrict__ b, float* __restrict__ xln){
  int n = blockIdx.x, t = threadIdx.x;
  __shared__ float rbuf[256];
  float v[5];
  float s = 0.0f;
  #pragma unroll
  for (int i=0;i<5;i++){ v[i] = x[(size_t)n*IND + t + i*256]; s += v[i]; }
  float mu = bsumf(s, rbuf)*(1.0f/IND);
  float pv = 0.0f;
  #pragma unroll
  for (int i=0;i<5;i++){ float dd = v[i]-mu; pv += dd*dd; }
  float var = bsumf(pv, rbuf)*(1.0f/IND);
  float rs = 1.0f/sqrtf(var + 1e-5f);
  #pragma unroll
  for (int i=0;i<5;i++){
    int k = t + i*256;
    xln[(size_t)n*IND + k] = g[k]*((v[i]-mu)*rs) + b[k];
  }
}

// emb0 with LDS staging + float4 LDS reads + k-group 8 (per-acc addend order preserved).
__global__ __launch_bounds__(256) void emb0_kernel(const float* __restrict__ xln,
    const float* __restrict__ W, const float* __restrict__ bias, float* __restrict__ emb){
  int n0 = blockIdx.x*8, j = threadIdx.x;
  __shared__ float s_x[8][IND];   // 40 KB
  for (int idx=j; idx<8*IND; idx+=256){
    int i = idx/IND, k = idx - i*IND;
    s_x[i][k] = xln[(size_t)(n0+i)*IND + k];
  }
  __syncthreads();
  float acc[8];
  #pragma unroll
  for (int i=0;i<8;i++) acc[i] = bias[j];
  for (int k=0;k<IND;k+=8){
    float w[8];
    #pragma unroll
    for (int u=0;u<8;u++) w[u] = W[(size_t)(k+u)*EMB+j];
    #pragma unroll
    for (int i=0;i<8;i++){
      float4 x0 = *(const float4*)&s_x[i][k];
      float4 x1 = *(const float4*)&s_x[i][k+4];
      acc[i] += x0.x*w[0] + x0.y*w[1] + x0.z*w[2] + x0.w*w[3];
      acc[i] += x1.x*w[4] + x1.y*w[5] + x1.z*w[6] + x1.w*w[7];
    }
  }
  #pragma unroll
  for (int i=0;i<8;i++) emb[(size_t)(n0+i)*EMB + j] = acc[i];
}

__global__ __launch_bounds__(64) void edge_kernel(const float* __restrict__ bb,
    const float* __restrict__ Rg, const float* __restrict__ tg,
    const int* __restrict__ col, float* __restrict__ Redge, float* __restrict__ eattr){
  int e = blockIdx.x*64 + threadIdx.x;
  if (e >= EE) return;
  int i = e/KK;
  int jn = col[e];
  float Ri[9], Rj[9];
  #pragma unroll
  for (int a=0;a<9;a++){ Ri[a]=Rg[(size_t)i*9+a]; Rj[a]=Rg[(size_t)jn*9+a]; }
  float dt0 = tg[(size_t)jn*3+0]-tg[(size_t)i*3+0];
  float dt1 = tg[(size_t)jn*3+1]-tg[(size_t)i*3+1];
  float dt2 = tg[(size_t)jn*3+2]-tg[(size_t)i*3+2];
  float Re[9];
  #pragma unroll
  for (int a=0;a<3;a++){
    #pragma unroll
    for (int c=0;c<3;c++)
      Re[a*3+c] = Ri[0+a]*Rj[0+c] + Ri[3+a]*Rj[3+c] + Ri[6+a]*Rj[6+c];
  }
  float te0 = Ri[0]*dt0 + Ri[3]*dt1 + Ri[6]*dt2;
  float te1 = Ri[1]*dt0 + Ri[4]*dt1 + Ri[7]*dt2;
  float te2 = Ri[2]*dt0 + Ri[5]*dt1 + Ri[8]*dt2;
  float xx=Re[0], xy=Re[1], xz=Re[2], yx=Re[3], yy=Re[4], yz=Re[5], zx=Re[6], zy=Re[7], zz=Re[8];
  float km[4][4];
  km[0][0]=(xx+yy+zz)/3.0f; km[0][1]=(zy-yz)/3.0f;    km[0][2]=(xz-zx)/3.0f;    km[0][3]=(yx-xy)/3.0f;
  km[1][0]=km[0][1];        km[1][1]=(xx-yy-zz)/3.0f; km[1][2]=(xy+yx)/3.0f;    km[1][3]=(xz+zx)/3.0f;
  km[2][0]=km[0][2];        km[2][1]=km[1][2];        km[2][2]=(yy-xx-zz)/3.0f; km[2][3]=(yz+zy)/3.0f;
  km[3][0]=km[0][3];        km[3][1]=km[1][3];        km[3][2]=km[2][3];        km[3][3]=(zz-xx-yy)/3.0f;
  float q[4];
  sym4_quat_f32(km, q);
  float* ea = eattr + (size_t)e*EAP;
  ea[0]=q[0]; ea[1]=q[1]; ea[2]=q[2]; ea[3]=q[3];
  ea[4]=te0;  ea[5]=te1;  ea[6]=te2;
  int cd = i - jn; if (cd < 0) cd = -cd;
  ea[7] = logf((float)cd + 1.0f);
  ea[8] = logf(sqrtf(te0*te0+te1*te1+te2*te2) + 1e-8f);
  const float* bi = bb + (size_t)i*9;
  const float* bj = bb + (size_t)jn*9;
  int idx = 9;
  #pragma unroll
  for (int a=0;a<3;a++){
    float ax=bi[a*3+0], ay=bi[a*3+1], az=bi[a*3+2];
    #pragma unroll
    for (int b2=0;b2<3;b2++){
      float dx=ax-bj[b2*3+0], dy=ay-bj[b2*3+1], dz=az-bj[b2*3+2];
      float dd = sqrtf(fmaxf(dx*dx+dy*dy+dz*dz, 1e-12f));
      #pragma unroll
      for (int kb=0;kb<16;kb++){
        float muv = 1.3333334f*(float)kb;
        float df = dd - muv;
        ea[idx] = expf(-0.5f*df*df);
        idx++;
      }
    }
  }
  ea[153]=0.0f; ea[154]=0.0f; ea[155]=0.0f;
  #pragma unroll
  for (int a=0;a<9;a++) Redge[(size_t)e*9+a] = Re[a];
}

// Fused h1 + h2 + LN + vu per node-block. Per-acc addend order identical to R10;
// LDS reads vectorized (float4 -> ds_read_b128); single 30-wide qq pass; k-group 8.
__global__ __launch_bounds__(256, 3) void fused_kernel(
    const float* __restrict__ emb_in, const float* __restrict__ v_in,
    const float* __restrict__ Redge, const float* __restrict__ eattr,
    const int* __restrict__ col,
    const float* __restrict__ W1, const float* __restrict__ b1,
    const float* __restrict__ W2, const float* __restrict__ b2,
    const float* __restrict__ W3, const float* __restrict__ b3,
    const float* __restrict__ vW,
    const float* __restrict__ lng, const float* __restrict__ lnb,
    float* __restrict__ emb_out, float* __restrict__ vu_out){
  int n = blockIdx.x, j = threadIdx.x;
  size_t e0 = (size_t)n*KK;
  __shared__ float s_big[KK*EMB];     // 30720 B: s_emb (phase B), s_h1 (phase C)
  __shared__ float s_eau[KK*EAP];     // 18720 B: eattr (phase B); sbuf/rbuf (phase C)
  __shared__ float s_vjr[KK][16];     // 1920 B
  __shared__ float s_xi [EMB];        // 1024 B
  __shared__ float s_vi [16];         // 64 B
  float* sbuf = s_eau;                // phase C alias
  float* rbuf = s_eau + 256;          // phase C alias

  // ---- staging (coalesced) ----
  #pragma unroll
  for (int e=0;e<KK;e++){
    int cj = col[e0+e];
    s_big[e*EMB + j] = emb_in[(size_t)cj*EMB + j];
  }
  s_xi[j] = emb_in[(size_t)n*EMB + j];
  if (j < V3) s_vi[j] = v_in[(size_t)n*V3 + j];
  for (int idx=j; idx<KK*EAP; idx+=256){
    s_eau[idx] = eattr[e0*EAP + idx];
  }
  for (int idx=j; idx<KK*16; idx+=256){
    int e = idx>>4, r = idx&15;
    if (r < V3){
      int m = r/3, ii = r - m*3;
      int cj = col[e0+e];
      const float* Rp = Redge + (e0+e)*9;
      const float* vp = v_in + (size_t)cj*V3 + m*3;
      s_vjr[e][r] = Rp[ii*3+0]*vp[0] + Rp[ii*3+1]*vp[1] + Rp[ii*3+2]*vp[2];
    }
  }
  __syncthreads();

  // ---- phase B: h1 ----
  float csh = b1[j];
  {
    for (int k=0;k<EMB;k+=4){
      float w0=W1[(size_t)(k+0)*EMB+j], w1=W1[(size_t)(k+1)*EMB+j], w2=W1[(size_t)(k+2)*EMB+j], w3=W1[(size_t)(k+3)*EMB+j];
      float4 xv = *(const float4*)&s_xi[k];
      csh += xv.x*w0 + xv.y*w1 + xv.z*w2 + xv.w*w3;
    }
    #pragma unroll
    for (int r=0;r<V3;r++) csh += s_vi[r]*(W1[(size_t)(512+r)*EMB+j] + W1[(size_t)(542+r)*EMB+j]);
  }
  float acc[KK];
  #pragma unroll
  for (int e=0;e<KK;e++) acc[e] = csh;
  // x_j part: W1 rows 256..511 — k-group 8, full 30-wide qq
  for (int k=0;k<EMB;k+=8){
    float w[8];
    #pragma unroll
    for (int u=0;u<8;u++) w[u] = W1[(size_t)(256+k+u)*EMB+j];
    #pragma unroll
    for (int qq=0;qq<KK;qq++){
      float4 x0 = *(const float4*)&s_big[qq*EMB + k];
      float4 x1 = *(const float4*)&s_big[qq*EMB + k+4];
      acc[qq] += x0.x*w[0] + x0.y*w[1] + x0.z*w[2] + x0.w*w[3];
      acc[qq] += x1.x*w[4] + x1.y*w[5] + x1.z*w[6] + x1.w*w[7];
    }
  }
  // vj_rot part
  {
    float wv[V3];
    #pragma unroll
    for (int r=0;r<V3;r++) wv[r] = W1[(size_t)(527+r)*EMB+j] - W1[(size_t)(542+r)*EMB+j];
    #pragma unroll
    for (int e=0;e<KK;e++){
      float a = acc[e];
      #pragma unroll
      for (int r=0;r<V3;r++) a += s_vjr[e][r]*wv[r];
      acc[e] = a;
    }
  }
  // edge-attr part: rows 557..708 (152 = 19*8), then row 709
  for (int k=0;k<152;k+=8){
    float w[8];
    #pragma unroll
    for (int u=0;u<8;u++) w[u] = W1[(size_t)(557+k+u)*EMB+j];
    #pragma unroll
    for (int qq=0;qq<KK;qq++){
      float4 a0 = *(const float4*)&s_eau[qq*EAP + k];
      float4 a1 = *(const float4*)&s_eau[qq*EAP + k+4];
      acc[qq] += a0.x*w[0] + a0.y*w[1] + a0.z*w[2] + a0.w*w[3];
      acc[qq] += a1.x*w[4] + a1.y*w[5] + a1.z*w[6] + a1.w*w[7];
    }
  }
  {
    float wl = W1[(size_t)709*EMB+j];
    #pragma unroll
    for (int qq=0;qq<KK;qq++) acc[qq] += s_eau[qq*EAP + 152]*wl;
  }
  // h1 -> LDS (reuse s_big)
  __syncthreads();
  #pragma unroll
  for (int e=0;e<KK;e++) s_big[e*EMB + j] = gelu_f(acc[e]);
  __syncthreads();

  // ---- phase C: h2 ----
  float acc2[KK];
  #pragma unroll
  for (int e=0;e<KK;e++) acc2[e] = b2[j];
  for (int k=0;k<EMB;k+=8){
    float w[8];
    #pragma unroll
    for (int u=0;u<8;u++) w[u] = W2[(size_t)(k+u)*EMB+j];
    #pragma unroll
    for (int qq=0;qq<KK;qq++){
      float4 h0 = *(const float4*)&s_big[qq*EMB + k];
      float4 h1v = *(const float4*)&s_big[qq*EMB + k+4];
      acc2[qq] += h0.x*w[0] + h0.y*w[1] + h0.z*w[2] + h0.w*w[3];
      acc2[qq] += h1v.x*w[4] + h1v.y*w[5] + h1v.z*w[6] + h1v.w*w[7];
    }
  }
  float s = 0.0f;
  #pragma unroll
  for (int e=0;e<KK;e++) s += gelu_f(acc2[e]);
  __syncthreads();
  sbuf[j] = s;
  __syncthreads();
  float ag = 0.0f;
  for (int k=0;k<EMB;k+=4){
    float4 s4 = *(const float4*)&sbuf[k];
    ag += s4.x*W3[(size_t)(k+0)*EMB+j] + s4.y*W3[(size_t)(k+1)*EMB+j]
        + s4.z*W3[(size_t)(k+2)*EMB+j] + s4.w*W3[(size_t)(k+3)*EMB+j];
  }
  ag = ag*(1.0f/30.0f) + b3[j];
  float u = s_xi[j] + ag;
  float mu = bsumf(u, rbuf)*(1.0f/EMB);
  float dl = u - mu;
  float var = bsumf(dl*dl, rbuf)*(1.0f/EMB);
  float rs = 1.0f/sqrtf(var + 1e-5f);
  float y = lng[j]*dl*rs + lnb[j];
  emb_out[(size_t)n*EMB+j] = y;
  __syncthreads();
  sbuf[j] = y;
  __syncthreads();
  // ---- vu ----
  if (j < V3){
    float a = s_vi[j];
    for (int k=0;k<EMB;k++){
      a += sbuf[k]*vW[k*V3+j];
    }
    #pragma unroll
    for (int r=0;r<V3;r++) a += s_vi[r]*vW[(EMB+r)*V3+j];
    vu_out[(size_t)n*V3+j] = a;
  }
}

// Pure QR per graph (f32 sgeqr2/sorg2r, raw LAPACK signs) — untouched.
__global__ __launch_bounds__(256) void qr_kernel(
    const float* __restrict__ vu_in, float* __restrict__ vout){
  int g = blockIdx.x, t = threadIdx.x;
  __shared__ float A[QRM*QRN];
  __shared__ float meanv[V3];
  __shared__ float taus[QRN];
  __shared__ float sh[2];
  int n = g*LSZ + t;
  #pragma unroll
  for (int j=0;j<V3;j++) A[t*V3+j] = vu_in[(size_t)n*V3 + j];
  __syncthreads();
  if (t < V3){
    float s = 0.0f;
    for (int l0=0;l0<LSZ;l0++) s += A[l0*V3+t];
    meanv[t] = s/(float)LSZ;
  }
  __syncthreads();
  #pragma unroll
  for (int j=0;j<V3;j++) A[t*V3+j] -= meanv[j];
  __syncthreads();
  // ---- sgeqr2 ----
  for (int i=0;i<QRN;i++){
    if (t == 0){
      float s0=0,s1=0,s2=0,s3=0;
      int r=i+1;
      for (; r+3<QRM; r+=4){
        float x0=A[r*QRN+i], x1=A[(r+1)*QRN+i], x2=A[(r+2)*QRN+i], x3=A[(r+3)*QRN+i];
        s0+=x0*x0; s1+=x1*x1; s2+=x2*x2; s3+=x3*x3;
      }
      for (; r<QRM; r++){ float x=A[r*QRN+i]; s0+=x*x; }
      float xn2 = (s0+s1)+(s2+s3);
      float alpha = A[i*QRN+i];
      float taui = 0.0f, sc = 1.0f;
      if (xn2 != 0.0f){
        float beta = -s_sign(slapy2(alpha, sqrtf(xn2)), alpha);
        taui = (beta - alpha)/beta;
        sc = 1.0f/(alpha - beta);
      }
      taus[i] = taui; sh[0] = sc;
    }
    __syncthreads();
    {
      float sc = sh[0];
      for (int r=i+1+t; r<QRM; r+=256) A[r*QRN+i] *= sc;
    }
    __syncthreads();
    for (int j=i+1;j<QRN;j++){
      if (t == 0){
        float s0=A[i*QRN+j], s1=0,s2=0,s3=0;
        int r=i+1;
        for (; r+3<QRM; r+=4){
          s0 += A[r*QRN+i]*A[r*QRN+j];
          s1 += A[(r+1)*QRN+i]*A[(r+1)*QRN+j];
          s2 += A[(r+2)*QRN+i]*A[(r+2)*QRN+j];
          s3 += A[(r+3)*QRN+i]*A[(r+3)*QRN+j];
        }
        for (; r<QRM; r++) s0 += A[r*QRN+i]*A[r*QRN+j];
        sh[0] = taus[i]*((s0+s1)+(s2+s3));
      }
      __syncthreads();
      {
        float w = sh[0];
        for (int r=i+t; r<QRM; r+=256){
          float vr = (r==i) ? 1.0f : A[r*QRN+i];
          A[r*QRN+j] -= w*vr;
        }
      }
      __syncthreads();
    }
  }
  // ---- sorg2r ----
  for (int i=QRN-1;i>=0;i--){
    for (int j=i+1;j<QRN;j++){
      if (t == 0){
        float s0=A[i*QRN+j], s1=0,s2=0,s3=0;
        int r=i+1;
        for (; r+3<QRM; r+=4){
          s0 += A[r*QRN+i]*A[r*QRN+j];
          s1 += A[(r+1)*QRN+i]*A[(r+1)*QRN+j];
          s2 += A[(r+2)*QRN+i]*A[(r+2)*QRN+j];
          s3 += A[(r+3)*QRN+i]*A[(r+3)*QRN+j];
        }
        for (; r<QRM; r++) s0 += A[r*QRN+i]*A[r*QRN+j];
        sh[0] = taus[i]*((s0+s1)+(s2+s3));
      }
      __syncthreads();
      {
        float w = sh[0];
        for (int r=i+t; r<QRM; r+=256){
          float vr = (r==i) ? 1.0f : A[r*QRN+i];
          A[r*QRN+j] -= w*vr;
        }
      }
      __syncthreads();
    }
    {
      float taui = taus[i];
      for (int r=i+1+t; r<QRM; r+=256) A[r*QRN+i] *= -taui;
    }
    __syncthreads();
    if (t == 0) A[i*QRN+i] = 1.0f - taus[i];
    if (t < i) A[t*QRN+i] = 0.0f;
    __syncthreads();
  }
  for (int idx=t; idx<QRM*QRN; idx+=256)
    vout[(size_t)g*LSZ*V3 + idx] = 16.0f*A[idx];
}

__global__ __launch_bounds__(256) void final_kernel(const float* __restrict__ embf,
    const float* __restrict__ vf, const float* __restrict__ Rg, float* __restrict__ out){
  int n = blockIdx.x, t = threadIdx.x;
  out[(size_t)n*EMB + t] = embf[(size_t)n*EMB + t];
  if (t < V3){
    int m = t/3, ii = t - m*3;
    const float* Rp = Rg + (size_t)n*9;
    const float* vp = vf + (size_t)n*V3 + m*3;
    float val = Rp[ii*3+0]*vp[0] + Rp[ii*3+1]*vp[1] + Rp[ii*3+2]*vp[2];
    out[(size_t)NN*EMB + (size_t)n*V3 + t] = val;
  }
}

// ---------------- host ----------------
extern "C" void kernel_launch(void* const* d_in, const int* in_sizes, int n_in,
                              void* d_out, int out_size, void* d_ws, size_t ws_size,
                              hipStream_t stream){
  (void)in_sizes; (void)n_in; (void)out_size; (void)ws_size;
  const float* x       = (const float*)d_in[0];
  const float* bb      = (const float*)d_in[1];
  const float* in_ln_g = (const float*)d_in[2];
  const float* in_ln_b = (const float*)d_in[3];
  const float* in_W    = (const float*)d_in[4];
  const float* in_b    = (const float*)d_in[5];
  const float* msg_W1  = (const float*)d_in[6];
  const float* msg_b1  = (const float*)d_in[7];
  const float* msg_W2  = (const float*)d_in[8];
  const float* msg_b2  = (const float*)d_in[9];
  const float* msg_W3  = (const float*)d_in[10];
  const float* msg_b3  = (const float*)d_in[11];
  const float* vect_W  = (const float*)d_in[12];
  const float* ln_g    = (const float*)d_in[13];
  const float* ln_b    = (const float*)d_in[14];
  const int*   col     = (const int*)d_in[16];

  char* p = (char*)d_ws;
  auto alloc = [&](size_t bytes)->void*{ void* r = (void*)p; p += (bytes + 255) & ~(size_t)255; return r; };
  float*  Rg    = (float*) alloc((size_t)NN*9*4);
  float*  tg    = (float*) alloc((size_t)NN*3*4);
  float*  xln   = (float*) alloc((size_t)NN*IND*4);
  float*  eA    = (float*) alloc((size_t)NN*EMB*4);
  float*  eB    = (float*) alloc((size_t)NN*EMB*4);
  float*  vA    = (float*) alloc((size_t)NN*V3*4);
  float*  vB    = (float*) alloc((size_t)NN*V3*4);
  float*  vu    = (float*) alloc((size_t)NN*V3*4);
  float*  Redge = (float*) alloc((size_t)EE*9*4);
  float*  eattr = (float*) alloc((size_t)EE*EAP*4);

  const int NV = NN*V3;
  fill_kernel<<<(NV+255)/256, 256, 0, stream>>>(vA, NV, 0.0f);
  rigid_kernel<<<(NN+63)/64, 64, 0, stream>>>(bb, Rg, tg);
  ln_kernel<<<NN, 256, 0, stream>>>(x, in_ln_g, in_ln_b, xln);
  emb0_kernel<<<NN/8, 256, 0, stream>>>(xln, in_W, in_b, eA);
  edge_kernel<<<(EE+63)/64, 64, 0, stream>>>(bb, Rg, tg, col, Redge, eattr);

  float* ein = eA; float* eout = eB; float* vin = vA; float* vout = vB;
  for (int l=0; l<3; ++l){
    fused_kernel<<<NN, 256, 0, stream>>>(ein, vin, Redge, eattr, col,
        msg_W1 + (size_t)l*710*EMB, msg_b1 + (size_t)l*EMB,
        msg_W2 + (size_t)l*EMB*EMB, msg_b2 + (size_t)l*EMB,
        msg_W3 + (size_t)l*EMB*EMB, msg_b3 + (size_t)l*EMB,
        vect_W + (size_t)l*(EMB+V3)*V3,
        ln_g + (size_t)l*EMB, ln_b + (size_t)l*EMB, eout, vu);
    qr_kernel<<<NG, 256, 0, stream>>>(vu, vout);
    float* tmp = ein; ein = eout; eout = tmp;
    tmp = vin; vin = vout; vout = tmp;
  }
  final_kernel<<<NN, 256, 0, stream>>>(ein, vin, Rg, (float*)d_out);
}

// Round 12
// 2026.905 us; speedup vs baseline: 1.1895x; 1.1895x over previous
//
#include <hip/hip_runtime.h>
#include <hip/hip_bf16.h>

#define NG   8
#define LSZ  256
#define NN   2048
#define KK   30
#define EE   61440
#define IND  1280
#define EMB  256
#define V3   15
#define EAP  156
#define QRM  768
#define QRN  5

#define F32_EPS    5.9604645e-08f
#define F32_EPS2   3.5527137e-15f
#define F32_SAFMIN 1.17549435e-38f

typedef __bf16 bf16x8 __attribute__((ext_vector_type(8)));
typedef float  f32x4  __attribute__((ext_vector_type(4)));
typedef short  s16x8  __attribute__((ext_vector_type(8)));

__device__ __forceinline__ float bsumf(float v, float* rbuf){
  int t = threadIdx.x;
  __syncthreads();
  rbuf[t] = v;
  __syncthreads();
  for (int s=128; s>0; s>>=1){
    if (t < s) rbuf[t] += rbuf[t+s];
    __syncthreads();
  }
  float r = rbuf[0];
  __syncthreads();
  return r;
}
__device__ __forceinline__ float gelu_f(float x){
  return 0.5f*x*(1.0f + erff(x*0.70710678f));
}
__device__ __forceinline__ float s_sign(float a, float b){ return (b >= 0.0f) ? fabsf(a) : -fabsf(a); }
__device__ __forceinline__ float slapy2(float x, float y){
  float xa = fabsf(x), ya = fabsf(y);
  float w = fmaxf(xa, ya), z = fminf(xa, ya);
  if (z == 0.0f) return w;
  float t = z/w;
  return w*sqrtf(1.0f + t*t);
}
// RNE f32 -> bf16 bits
__device__ __forceinline__ unsigned short bf16_rne(float v){
  unsigned int u = __float_as_uint(v);
  u = u + 0x7FFFu + ((u>>16)&1u);
  return (unsigned short)(u>>16);
}
// LAPACK >=3.10 slartg (f32)
__device__ void slartg(float f, float g, float& c, float& s, float& r){
  const float safmin = F32_SAFMIN;
  const float safmax = 8.5070592e+37f;
  const float rtmin  = 1.0842022e-19f;
  const float rtmax  = 6.5243586e+18f;
  float f1 = fabsf(f), g1 = fabsf(g);
  if (g == 0.0f){ c = 1.0f; s = 0.0f; r = f; }
  else if (f == 0.0f){ c = 0.0f; s = (g >= 0.0f ? 1.0f : -1.0f); r = g1; }
  else {
    if (f1 > rtmin && f1 < rtmax && g1 > rtmin && g1 < rtmax){
      float d = sqrtf(f*f + g*g);
      c = f1/d;
      r = (f >= 0.0f ? d : -d);
      s = g/r;
    } else {
      float u = fminf(safmax, fmaxf(safmin, fmaxf(f1,g1)));
      float fs = f/u, gs = g/u;
      float d = sqrtf(fs*fs + gs*gs);
      c = fabsf(fs)/d;
      r = (f >= 0.0f ? d : -d);
      s = gs/r;
      r = r*u;
    }
  }
}
__device__ void slaev2(float a, float b, float c, float& rt1, float& rt2, float& cs1, float& sn1){
  float sm = a + c, df = a - c, adf = fabsf(df), tb = b + b, ab = fabsf(tb);
  float acmx, acmn;
  if (fabsf(a) > fabsf(c)) { acmx=a; acmn=c; } else { acmx=c; acmn=a; }
  float rt;
  if (adf > ab){ float t = ab/adf; rt = adf*sqrtf(1.0f+t*t); }
  else if (adf < ab){ float t = adf/ab; rt = ab*sqrtf(1.0f+t*t); }
  else rt = ab*sqrtf(2.0f);
  int sgn1;
  if (sm < 0.0f){ rt1 = 0.5f*(sm-rt); sgn1 = -1; rt2 = (acmx/rt1)*acmn - (b/rt1)*b; }
  else if (sm > 0.0f){ rt1 = 0.5f*(sm+rt); sgn1 = 1; rt2 = (acmx/rt1)*acmn - (b/rt1)*b; }
  else { rt1 = 0.5f*rt; rt2 = -0.5f*rt; sgn1 = 1; }
  float cs; int sgn2;
  if (df >= 0.0f){ cs = df + rt; sgn2 = 1; } else { cs = df - rt; sgn2 = -1; }
  float acs = fabsf(cs);
  if (acs > ab){
    float ct = -tb/cs; sn1 = 1.0f/sqrtf(1.0f+ct*ct); cs1 = ct*sn1;
  } else {
    if (ab == 0.0f){ cs1 = 1.0f; sn1 = 0.0f; }
    else { float tn = -cs/tb; cs1 = 1.0f/sqrtf(1.0f+tn*tn); sn1 = tn*cs1; }
  }
  if (sgn1 == sgn2){ float tn = cs1; cs1 = -sn1; sn1 = tn; }
}

// f32 ssytd2('L') + ssteqr('I') for 4x4; returns eigvec of largest eigenvalue.
__device__ void sym4_quat_f32(float (&a)[4][4], float* q){
  float d[4], e[3];
  float tau0 = 0.0f, tau1 = 0.0f;
  float v31 = 0.0f, v41 = 0.0f, v42 = 0.0f;
  {
    float alpha = a[1][0];
    float x1 = a[2][0], x2 = a[3][0];
    float xnorm = sqrtf(x1*x1 + x2*x2);
    if (xnorm == 0.0f){ tau0 = 0.0f; e[0] = alpha; }
    else {
      float beta = -s_sign(slapy2(alpha, xnorm), alpha);
      tau0 = (beta - alpha)/beta;
      float sc = 1.0f/(alpha - beta);
      x1 *= sc; x2 *= sc;
      e[0] = beta;
      float p0 = tau0*(a[1][1] + a[2][1]*x1 + a[3][1]*x2);
      float p1 = tau0*(a[2][1] + a[2][2]*x1 + a[3][2]*x2);
      float p2 = tau0*(a[3][1] + a[3][2]*x1 + a[3][3]*x2);
      float al = -0.5f*tau0*(p0 + p1*x1 + p2*x2);
      p0 += al; p1 += al*x1; p2 += al*x2;
      a[1][1] -= 2.0f*p0;
      a[2][1] -= x1*p0 + p1;
      a[3][1] -= x2*p0 + p2;
      a[2][2] -= 2.0f*x1*p1;
      a[3][2] -= x2*p1 + p2*x1;
      a[3][3] -= 2.0f*x2*p2;
    }
    v31 = x1; v41 = x2;
  }
  {
    float alpha = a[2][1];
    float x1 = a[3][1];
    float xnorm = fabsf(x1);
    if (xnorm == 0.0f){ tau1 = 0.0f; e[1] = alpha; }
    else {
      float beta = -s_sign(slapy2(alpha, xnorm), alpha);
      tau1 = (beta - alpha)/beta;
      x1 *= 1.0f/(alpha - beta);
      e[1] = beta;
      float p0 = tau1*(a[2][2] + a[3][2]*x1);
      float p1 = tau1*(a[3][2] + a[3][3]*x1);
      float al = -0.5f*tau1*(p0 + p1*x1);
      p0 += al; p1 += al*x1;
      a[2][2] -= 2.0f*p0;
      a[3][2] -= x1*p0 + p1;
      a[3][3] -= 2.0f*x1*p1;
    }
    v42 = x1;
  }
  e[2] = a[3][2];
  d[0]=a[0][0]; d[1]=a[1][1]; d[2]=a[2][2]; d[3]=a[3][3];
  float z[4][4] = {{1,0,0,0},{0,1,0,0},{0,0,1,0},{0,0,0,1}};
  const float eps = F32_EPS;
  const float eps2 = F32_EPS2;
  const float safmin = F32_SAFMIN;
  int jtot = 0;
  const int nmaxit = 120;
  int l1 = 0;
  bool fail = false;
  while (!fail){
    if (l1 > 3) break;
    if (l1 > 0) e[l1-1] = 0.0f;
    int lend = 3;
    for (int mm = l1; mm <= 2; ++mm){
      float tst = fabsf(e[mm]);
      if (tst == 0.0f){ lend = mm; break; }
      if (tst <= (sqrtf(fabsf(d[mm]))*sqrtf(fabsf(d[mm+1])))*eps){ e[mm] = 0.0f; lend = mm; break; }
    }
    int l = l1;
    int lsv = l, lendsv = lend;
    l1 = lend + 1;
    if (lend == l) continue;
    float anorm = fabsf(d[l]);
    for (int ii=l+1; ii<=lend; ++ii) anorm = fmaxf(anorm, fabsf(d[ii]));
    for (int ii=l; ii<lend; ++ii)    anorm = fmaxf(anorm, fabsf(e[ii]));
    if (anorm == 0.0f) continue;
    if (fabsf(d[lend]) < fabsf(d[l])){ lend = lsv; l = lendsv; }
    if (lend > l){
      for (;;){
        int m = lend;
        if (l != lend){
          for (int mm=l; mm<=lend-1; ++mm){
            float tst = e[mm]*e[mm];
            if (tst <= (eps2*fabsf(d[mm]))*fabsf(d[mm+1]) + safmin){ m = mm; break; }
          }
        }
        if (m < lend) e[m] = 0.0f;
        float p = d[l];
        if (m == l){
          d[l] = p; ++l;
          if (l <= lend) continue;
          break;
        }
        if (m == l+1){
          float rt1, rt2, c, s;
          slaev2(d[l], e[l], d[l+1], rt1, rt2, c, s);
          #pragma unroll
          for (int r2=0;r2<4;r2++){
            float t_ = z[r2][l+1];
            z[r2][l+1] = c*t_ - s*z[r2][l];
            z[r2][l]   = s*t_ + c*z[r2][l];
          }
          d[l]=rt1; d[l+1]=rt2; e[l]=0.0f;
          l += 2;
          if (l <= lend) continue;
          break;
        }
        if (jtot == nmaxit){ fail = true; break; }
        ++jtot;
        float g = (d[l+1]-p)/(2.0f*e[l]);
        float r_ = slapy2(g, 1.0f);
        g = d[m] - p + e[l]/(g + s_sign(r_, g));
        float s = 1.0f, c = 1.0f;
        p = 0.0f;
        float csv[3], snv[3];
        for (int i=m-1; i>=l; --i){
          float f = s*e[i], b = c*e[i];
          slartg(g, f, c, s, r_);
          if (i != m-1) e[i+1] = r_;
          g = d[i+1] - p;
          r_ = (d[i]-g)*s + 2.0f*c*b;
          p = s*r_;
          d[i+1] = g + p;
          g = c*r_ - b;
          csv[i] = c; snv[i] = -s;
        }
        for (int i=m-1; i>=l; --i){
          float cc = csv[i], ss = snv[i];
          #pragma unroll
          for (int r2=0;r2<4;r2++){
            float t_ = z[r2][i+1];
            z[r2][i+1] = cc*t_ - ss*z[r2][i];
            z[r2][i]   = ss*t_ + cc*z[r2][i];
          }
        }
        d[l] -= p; e[l] = g;
      }
    } else {
      for (;;){
        int m = lend;
        if (l != lend){
          for (int mm=l; mm>=lend+1; --mm){
            float tst = e[mm-1]*e[mm-1];
            if (tst <= (eps2*fabsf(d[mm]))*fabsf(d[mm-1]) + safmin){ m = mm; break; }
          }
        }
        if (m > lend) e[m-1] = 0.0f;
        float p = d[l];
        if (m == l){
          d[l] = p; --l;
          if (l >= lend) continue;
          break;
        }
        if (m == l-1){
          float rt1, rt2, c, s;
          slaev2(d[l-1], e[l-1], d[l], rt1, rt2, c, s);
          #pragma unroll
          for (int r2=0;r2<4;r2++){
            float t_ = z[r2][l];
            z[r2][l]   = c*t_ - s*z[r2][l-1];
            z[r2][l-1] = s*t_ + c*z[r2][l-1];
          }
          d[l-1]=rt1; d[l]=rt2; e[l-1]=0.0f;
          l -= 2;
          if (l >= lend) continue;
          break;
        }
        if (jtot == nmaxit){ fail = true; break; }
        ++jtot;
        float g = (d[l-1]-p)/(2.0f*e[l-1]);
        float r_ = slapy2(g, 1.0f);
        g = d[m] - p + e[l-1]/(g + s_sign(r_, g));
        float s = 1.0f, c = 1.0f;
        p = 0.0f;
        float csv[3], snv[3];
        for (int i=m; i<=l-1; ++i){
          float f = s*e[i], b = c*e[i];
          slartg(g, f, c, s, r_);
          if (i != m) e[i-1] = r_;
          g = d[i] - p;
          r_ = (d[i+1]-g)*s + 2.0f*c*b;
          p = s*r_;
          d[i] = g + p;
          g = c*r_ - b;
          csv[i] = c; snv[i] = s;
        }
        for (int i=m; i<=l-1; ++i){
          float cc = csv[i], ss = snv[i];
          #pragma unroll
          for (int r2=0;r2<4;r2++){
            float t_ = z[r2][i+1];
            z[r2][i+1] = cc*t_ - ss*z[r2][i];
            z[r2][i]   = ss*t_ + cc*z[r2][i];
          }
        }
        d[l] -= p; e[l-1] = g;
      }
    }
  }
  for (int ii=1; ii<4; ++ii){
    int i0 = ii-1, k0 = i0;
    float p = d[i0];
    for (int j2=ii; j2<4; ++j2) if (d[j2] < p){ k0 = j2; p = d[j2]; }
    if (k0 != i0){
      d[k0] = d[i0]; d[i0] = p;
      #pragma unroll
      for (int r2=0;r2<4;r2++){ float t_ = z[r2][i0]; z[r2][i0] = z[r2][k0]; z[r2][k0] = t_; }
    }
  }
  float w0 = z[0][3], w1 = z[1][3], w2 = z[2][3], w3 = z[3][3];
  if (tau1 != 0.0f){
    float dv = w2 + v42*w3;
    w2 -= tau1*dv;
    w3 -= tau1*dv*v42;
  }
  if (tau0 != 0.0f){
    float dv = w1 + v31*w2 + v41*w3;
    w1 -= tau0*dv;
    w2 -= tau0*dv*v31;
    w3 -= tau0*dv*v41;
  }
  q[0]=w0; q[1]=w1; q[2]=w2; q[3]=w3;
}

// ---------------- kernels ----------------
__global__ void fill_kernel(float* __restrict__ p, int nelem, float val){
  int i = blockIdx.x*blockDim.x + threadIdx.x;
  if (i < nelem) p[i] = val;
}

// Pre-split W2 (3 layers) into transposed bf16 hi/lo: out[l][j][k]
__global__ __launch_bounds__(256) void wsplit_kernel(const float* __restrict__ W2,
    unsigned short* __restrict__ hi, unsigned short* __restrict__ lo){
  int idx = blockIdx.x*256 + threadIdx.x;   // 3*65536 total
  int l = idx >> 16; int rem = idx & 65535; int k = rem >> 8; int j = rem & 255;
  float v = W2[(size_t)l*65536 + (size_t)k*256 + j];
  unsigned short hb = bf16_rne(v);
  float hf = __uint_as_float(((unsigned int)hb)<<16);
  unsigned short lb = bf16_rne(v - hf);
  size_t o = (size_t)l*65536 + (size_t)j*256 + k;
  hi[o] = hb; lo[o] = lb;
}

__global__ void rigid_kernel(const float* __restrict__ bb, float* __restrict__ Rg, float* __restrict__ tg){
  int n = blockIdx.x*blockDim.x + threadIdx.x;
  if (n >= NN) return;
  const float* p = bb + (size_t)n*9;
  float nx=p[0],ny=p[1],nz=p[2], cax=p[3],cay=p[4],caz=p[5], cx=p[6],cy=p[7],cz=p[8];
  float e1x=cx-cax, e1y=cy-cay, e1z=cz-caz;
  float n1 = sqrtf(e1x*e1x+e1y*e1y+e1z*e1z);
  e1x/=n1; e1y/=n1; e1z/=n1;
  float ux=nx-cax, uy=ny-cay, uz=nz-caz;
  float du = ux*e1x+uy*e1y+uz*e1z;
  float e2x=ux-du*e1x, e2y=uy-du*e1y, e2z=uz-du*e1z;
  float n2 = sqrtf(e2x*e2x+e2y*e2y+e2z*e2z);
  e2x/=n2; e2y/=n2; e2z/=n2;
  float e3x=e1y*e2z-e1z*e2y, e3y=e1z*e2x-e1x*e2z, e3z=e1x*e2y-e1y*e2x;
  float* R = Rg + (size_t)n*9;
  R[0]=e1x; R[1]=e2x; R[2]=e3x;
  R[3]=e1y; R[4]=e2y; R[5]=e3y;
  R[6]=e1z; R[7]=e2z; R[8]=e3z;
  tg[(size_t)n*3+0]=cax; tg[(size_t)n*3+1]=cay; tg[(size_t)n*3+2]=caz;
}

__global__ __launch_bounds__(256) void ln_kernel(const float* __restrict__ x,
    const float* __restrict__ g, const float* __restrict__ b, float* __restrict__ xln){
  int n = blockIdx.x, t = threadIdx.x;
  __shared__ float rbuf[256];
  float v[5];
  float s = 0.0f;
  #pragma unroll
  for (int i=0;i<5;i++){ v[i] = x[(size_t)n*IND + t + i*256]; s += v[i]; }
  float mu = bsumf(s, rbuf)*(1.0f/IND);
  float pv = 0.0f;
  #pragma unroll
  for (int i=0;i<5;i++){ float dd = v[i]-mu; pv += dd*dd; }
  float var = bsumf(pv, rbuf)*(1.0f/IND);
  float rs = 1.0f/sqrtf(var + 1e-5f);
  #pragma unroll
  for (int i=0;i<5;i++){
    int k = t + i*256;
    xln[(size_t)n*IND + k] = g[k]*((v[i]-mu)*rs) + b[k];
  }
}

// emb0 with LDS staging (R10 form).
__global__ __launch_bounds__(256) void emb0_kernel(const float* __restrict__ xln,
    const float* __restrict__ W, const float* __restrict__ bias, float* __restrict__ emb){
  int n0 = blockIdx.x*8, j = threadIdx.x;
  __shared__ float s_x[8][IND];   // 40 KB
  for (int idx=j; idx<8*IND; idx+=256){
    int i = idx/IND, k = idx - i*IND;
    s_x[i][k] = xln[(size_t)(n0+i)*IND + k];
  }
  __syncthreads();
  float acc[8];
  #pragma unroll
  for (int i=0;i<8;i++) acc[i] = bias[j];
  for (int k=0;k<IND;k+=4){
    float w0=W[(size_t)(k+0)*EMB+j], w1=W[(size_t)(k+1)*EMB+j], w2=W[(size_t)(k+2)*EMB+j], w3=W[(size_t)(k+3)*EMB+j];
    #pragma unroll
    for (int i=0;i<8;i++){
      const float* xp = &s_x[i][k];
      acc[i] += xp[0]*w0 + xp[1]*w1 + xp[2]*w2 + xp[3]*w3;
    }
  }
  #pragma unroll
  for (int i=0;i<8;i++) emb[(size_t)(n0+i)*EMB + j] = acc[i];
}

__global__ __launch_bounds__(64) void edge_kernel(const float* __restrict__ bb,
    const float* __restrict__ Rg, const float* __restrict__ tg,
    const int* __restrict__ col, float* __restrict__ Redge, float* __restrict__ eattr){
  int e = blockIdx.x*64 + threadIdx.x;
  if (e >= EE) return;
  int i = e/KK;
  int jn = col[e];
  float Ri[9], Rj[9];
  #pragma unroll
  for (int a=0;a<9;a++){ Ri[a]=Rg[(size_t)i*9+a]; Rj[a]=Rg[(size_t)jn*9+a]; }
  float dt0 = tg[(size_t)jn*3+0]-tg[(size_t)i*3+0];
  float dt1 = tg[(size_t)jn*3+1]-tg[(size_t)i*3+1];
  float dt2 = tg[(size_t)jn*3+2]-tg[(size_t)i*3+2];
  float Re[9];
  #pragma unroll
  for (int a=0;a<3;a++){
    #pragma unroll
    for (int c=0;c<3;c++)
      Re[a*3+c] = Ri[0+a]*Rj[0+c] + Ri[3+a]*Rj[3+c] + Ri[6+a]*Rj[6+c];
  }
  float te0 = Ri[0]*dt0 + Ri[3]*dt1 + Ri[6]*dt2;
  float te1 = Ri[1]*dt0 + Ri[4]*dt1 + Ri[7]*dt2;
  float te2 = Ri[2]*dt0 + Ri[5]*dt1 + Ri[8]*dt2;
  float xx=Re[0], xy=Re[1], xz=Re[2], yx=Re[3], yy=Re[4], yz=Re[5], zx=Re[6], zy=Re[7], zz=Re[8];
  float km[4][4];
  km[0][0]=(xx+yy+zz)/3.0f; km[0][1]=(zy-yz)/3.0f;    km[0][2]=(xz-zx)/3.0f;    km[0][3]=(yx-xy)/3.0f;
  km[1][0]=km[0][1];        km[1][1]=(xx-yy-zz)/3.0f; km[1][2]=(xy+yx)/3.0f;    km[1][3]=(xz+zx)/3.0f;
  km[2][0]=km[0][2];        km[2][1]=km[1][2];        km[2][2]=(yy-xx-zz)/3.0f; km[2][3]=(yz+zy)/3.0f;
  km[3][0]=km[0][3];        km[3][1]=km[1][3];        km[3][2]=km[2][3];        km[3][3]=(zz-xx-yy)/3.0f;
  float q[4];
  sym4_quat_f32(km, q);
  float* ea = eattr + (size_t)e*EAP;
  ea[0]=q[0]; ea[1]=q[1]; ea[2]=q[2]; ea[3]=q[3];
  ea[4]=te0;  ea[5]=te1;  ea[6]=te2;
  int cd = i - jn; if (cd < 0) cd = -cd;
  ea[7] = logf((float)cd + 1.0f);
  ea[8] = logf(sqrtf(te0*te0+te1*te1+te2*te2) + 1e-8f);
  const float* bi = bb + (size_t)i*9;
  const float* bj = bb + (size_t)jn*9;
  int idx = 9;
  #pragma unroll
  for (int a=0;a<3;a++){
    float ax=bi[a*3+0], ay=bi[a*3+1], az=bi[a*3+2];
    #pragma unroll
    for (int b2=0;b2<3;b2++){
      float dx=ax-bj[b2*3+0], dy=ay-bj[b2*3+1], dz=az-bj[b2*3+2];
      float dd = sqrtf(fmaxf(dx*dx+dy*dy+dz*dz, 1e-12f));
      #pragma unroll
      for (int kb=0;kb<16;kb++){
        float muv = 1.3333334f*(float)kb;
        float df = dd - muv;
        ea[idx] = expf(-0.5f*df*df);
        idx++;
      }
    }
  }
  ea[153]=0.0f; ea[154]=0.0f; ea[155]=0.0f;
  #pragma unroll
  for (int a=0;a<9;a++) Redge[(size_t)e*9+a] = Re[a];
}

// Fused: phase B = R10 VALU h1; phase C = MFMA bf16x2-split h2; epilogue LN/vu as R10.
#define H1K 264   // padded bf16 row stride for A operand
__global__ __launch_bounds__(256, 3) void fused_kernel(
    const float* __restrict__ emb_in, const float* __restrict__ v_in,
    const float* __restrict__ Redge, const float* __restrict__ eattr,
    const int* __restrict__ col,
    const float* __restrict__ W1, const float* __restrict__ b1,
    const unsigned short* __restrict__ W2Thi, const unsigned short* __restrict__ W2Tlo,
    const float* __restrict__ b2,
    const float* __restrict__ W3, const float* __restrict__ b3,
    const float* __restrict__ vW,
    const float* __restrict__ lng, const float* __restrict__ lnb,
    float* __restrict__ emb_out, float* __restrict__ vu_out){
  int n = blockIdx.x, j = threadIdx.x;
  size_t e0 = (size_t)n*KK;
  __shared__ __align__(16) char smem[49440];   // phase B: s_big(30720)+s_eau(18720); phase C: h1 splits + sbuf/rbuf
  __shared__ float s_vjr[KK][16];
  __shared__ float s_xi [EMB];
  __shared__ float s_vi [16];
  float* s_big = (float*)smem;                   // [KK*EMB]
  float* s_eau = (float*)(smem + 30720);         // [KK*EAP]
  unsigned short* h1hi = (unsigned short*)smem;            // [32][H1K]
  unsigned short* h1lo = h1hi + 32*H1K;                    // [32][H1K]  (ends at 33792 B)
  float* sbuf = (float*)(smem + 33792);          // [256]
  float* rbuf = (float*)(smem + 34816);          // [256]

  // ---- staging (coalesced) ----
  #pragma unroll
  for (int e=0;e<KK;e++){
    int cj = col[e0+e];
    s_big[e*EMB + j] = emb_in[(size_t)cj*EMB + j];
  }
  s_xi[j] = emb_in[(size_t)n*EMB + j];
  if (j < V3) s_vi[j] = v_in[(size_t)n*V3 + j];
  for (int idx=j; idx<KK*EAP; idx+=256){
    s_eau[idx] = eattr[e0*EAP + idx];
  }
  for (int idx=j; idx<KK*16; idx+=256){
    int e = idx>>4, r = idx&15;
    if (r < V3){
      int m = r/3, ii = r - m*3;
      int cj = col[e0+e];
      const float* Rp = Redge + (e0+e)*9;
      const float* vp = v_in + (size_t)cj*V3 + m*3;
      s_vjr[e][r] = Rp[ii*3+0]*vp[0] + Rp[ii*3+1]*vp[1] + Rp[ii*3+2]*vp[2];
    }
  }
  __syncthreads();

  // ---- phase B: h1 (R10 form) ----
  float csh = b1[j];
  {
    for (int k=0;k<EMB;k+=4){
      float w0=W1[(size_t)(k+0)*EMB+j], w1=W1[(size_t)(k+1)*EMB+j], w2=W1[(size_t)(k+2)*EMB+j], w3=W1[(size_t)(k+3)*EMB+j];
      csh += s_xi[k+0]*w0 + s_xi[k+1]*w1 + s_xi[k+2]*w2 + s_xi[k+3]*w3;
    }
    #pragma unroll
    for (int r=0;r<V3;r++) csh += s_vi[r]*(W1[(size_t)(512+r)*EMB+j] + W1[(size_t)(542+r)*EMB+j]);
  }
  float acc[KK];
  #pragma unroll
  for (int e=0;e<KK;e++) acc[e] = csh;
  #pragma unroll
  for (int eg=0; eg<KK; eg+=15){
    for (int k=0;k<EMB;k+=4){
      float w0=W1[(size_t)(256+k)*EMB+j], w1=W1[(size_t)(257+k)*EMB+j], w2=W1[(size_t)(258+k)*EMB+j], w3=W1[(size_t)(259+k)*EMB+j];
      #pragma unroll
      for (int qq=0;qq<15;qq++){
        const float* xp = &s_big[(eg+qq)*EMB + k];
        acc[eg+qq] += xp[0]*w0 + xp[1]*w1 + xp[2]*w2 + xp[3]*w3;
      }
    }
  }
  {
    float wv[V3];
    #pragma unroll
    for (int r=0;r<V3;r++) wv[r] = W1[(size_t)(527+r)*EMB+j] - W1[(size_t)(542+r)*EMB+j];
    #pragma unroll
    for (int e=0;e<KK;e++){
      float a = acc[e];
      #pragma unroll
      for (int r=0;r<V3;r++) a += s_vjr[e][r]*wv[r];
      acc[e] = a;
    }
  }
  #pragma unroll
  for (int eg=0; eg<KK; eg+=15){
    for (int k=0;k<152;k+=4){
      float w0=W1[(size_t)(557+k)*EMB+j], w1=W1[(size_t)(558+k)*EMB+j], w2=W1[(size_t)(559+k)*EMB+j], w3=W1[(size_t)(560+k)*EMB+j];
      #pragma unroll
      for (int qq=0;qq<15;qq++){
        const float* ap = &s_eau[(eg+qq)*EAP + k];
        acc[eg+qq] += ap[0]*w0 + ap[1]*w1 + ap[2]*w2 + ap[3]*w3;
      }
    }
    float wl = W1[(size_t)709*EMB+j];
    #pragma unroll
    for (int qq=0;qq<15;qq++) acc[eg+qq] += s_eau[(eg+qq)*EAP + 152]*wl;
  }
  // ---- h1 -> bf16 hi/lo LDS (overwrites s_big/s_eau after barrier) ----
  __syncthreads();
  #pragma unroll
  for (int e=0;e<KK;e++){
    float g = gelu_f(acc[e]);
    unsigned short hb = bf16_rne(g);
    float hf = __uint_as_float(((unsigned int)hb)<<16);
    unsigned short lb = bf16_rne(g - hf);
    h1hi[e*H1K + j] = hb;
    h1lo[e*H1K + j] = lb;
  }
  h1hi[30*H1K + j] = 0; h1hi[31*H1K + j] = 0;
  h1lo[30*H1K + j] = 0; h1lo[31*H1K + j] = 0;
  __syncthreads();

  // ---- phase C: h2 via MFMA (bf16x2 split, 3 products) ----
  int l = j & 63, w = j >> 6;
  f32x4 cacc[2][4];
  #pragma unroll
  for (int mt=0;mt<2;mt++)
    #pragma unroll
    for (int nt=0;nt<4;nt++)
      #pragma unroll
      for (int rg=0;rg<4;rg++) cacc[mt][nt][rg] = 0.0f;
  for (int kt=0;kt<8;kt++){
    int k0 = kt*32 + (l>>4)*8;
    bf16x8 aH[2], aL[2];
    #pragma unroll
    for (int mt=0;mt<2;mt++){
      int row = mt*16 + (l&15);
      aH[mt] = __builtin_bit_cast(bf16x8, *(const s16x8*)&h1hi[row*H1K + k0]);
      aL[mt] = __builtin_bit_cast(bf16x8, *(const s16x8*)&h1lo[row*H1K + k0]);
    }
    #pragma unroll
    for (int nt=0;nt<4;nt++){
      int colj = w*64 + nt*16 + (l&15);
      bf16x8 Bh = __builtin_bit_cast(bf16x8, *(const s16x8*)&W2Thi[(size_t)colj*256 + k0]);
      bf16x8 Bl = __builtin_bit_cast(bf16x8, *(const s16x8*)&W2Tlo[(size_t)colj*256 + k0]);
      #pragma unroll
      for (int mt=0;mt<2;mt++){
        cacc[mt][nt] = __builtin_amdgcn_mfma_f32_16x16x32_bf16(aH[mt], Bh, cacc[mt][nt], 0,0,0);
        cacc[mt][nt] = __builtin_amdgcn_mfma_f32_16x16x32_bf16(aH[mt], Bl, cacc[mt][nt], 0,0,0);
        cacc[mt][nt] = __builtin_amdgcn_mfma_f32_16x16x32_bf16(aL[mt], Bh, cacc[mt][nt], 0,0,0);
      }
    }
  }
  // gelu + sum over edges (rows), cross-row-group reduce, into sbuf
  {
    float p[4];
    #pragma unroll
    for (int nt=0;nt<4;nt++){
      float b2v = b2[w*64 + nt*16 + (l&15)];
      float pp = 0.0f;
      #pragma unroll
      for (int mt=0;mt<2;mt++){
        #pragma unroll
        for (int rg=0;rg<4;rg++){
          int row = mt*16 + ((l>>4)&3)*4 + rg;
          if (row < KK) pp += gelu_f(cacc[mt][nt][rg] + b2v);
        }
      }
      pp += __shfl_xor(pp, 16);
      pp += __shfl_xor(pp, 32);
      p[nt] = pp;
    }
    if (l < 16){
      #pragma unroll
      for (int nt=0;nt<4;nt++) sbuf[w*64 + nt*16 + l] = p[nt];
    }
  }
  __syncthreads();
  // ---- epilogue: W3 dot, LN, vu (identical structure to R10) ----
  float ag = 0.0f;
  for (int k=0;k<EMB;k+=4){
    float4 s4 = *(const float4*)&sbuf[k];
    ag += s4.x*W3[(size_t)(k+0)*EMB+j] + s4.y*W3[(size_t)(k+1)*EMB+j]
        + s4.z*W3[(size_t)(k+2)*EMB+j] + s4.w*W3[(size_t)(k+3)*EMB+j];
  }
  ag = ag*(1.0f/30.0f) + b3[j];
  float u = s_xi[j] + ag;
  float mu = bsumf(u, rbuf)*(1.0f/EMB);
  float dl = u - mu;
  float var = bsumf(dl*dl, rbuf)*(1.0f/EMB);
  float rs = 1.0f/sqrtf(var + 1e-5f);
  float y = lng[j]*dl*rs + lnb[j];
  emb_out[(size_t)n*EMB+j] = y;
  __syncthreads();
  sbuf[j] = y;
  __syncthreads();
  if (j < V3){
    float a = s_vi[j];
    for (int k=0;k<EMB;k++){
      a += sbuf[k]*vW[k*V3+j];
    }
    #pragma unroll
    for (int r=0;r<V3;r++) a += s_vi[r]*vW[(EMB+r)*V3+j];
    vu_out[(size_t)n*V3+j] = a;
  }
}

// Pure QR per graph (f32 sgeqr2/sorg2r, raw LAPACK signs) — untouched.
__global__ __launch_bounds__(256) void qr_kernel(
    const float* __restrict__ vu_in, float* __restrict__ vout){
  int g = blockIdx.x, t = threadIdx.x;
  __shared__ float A[QRM*QRN];
  __shared__ float meanv[V3];
  __shared__ float taus[QRN];
  __shared__ float sh[2];
  int n = g*LSZ + t;
  #pragma unroll
  for (int j=0;j<V3;j++) A[t*V3+j] = vu_in[(size_t)n*V3 + j];
  __syncthreads();
  if (t < V3){
    float s = 0.0f;
    for (int l0=0;l0<LSZ;l0++) s += A[l0*V3+t];
    meanv[t] = s/(float)LSZ;
  }
  __syncthreads();
  #pragma unroll
  for (int j=0;j<V3;j++) A[t*V3+j] -= meanv[j];
  __syncthreads();
  // ---- sgeqr2 ----
  for (int i=0;i<QRN;i++){
    if (t == 0){
      float s0=0,s1=0,s2=0,s3=0;
      int r=i+1;
      for (; r+3<QRM; r+=4){
        float x0=A[r*QRN+i], x1=A[(r+1)*QRN+i], x2=A[(r+2)*QRN+i], x3=A[(r+3)*QRN+i];
        s0+=x0*x0; s1+=x1*x1; s2+=x2*x2; s3+=x3*x3;
      }
      for (; r<QRM; r++){ float x=A[r*QRN+i]; s0+=x*x; }
      float xn2 = (s0+s1)+(s2+s3);
      float alpha = A[i*QRN+i];
      float taui = 0.0f, sc = 1.0f;
      if (xn2 != 0.0f){
        float beta = -s_sign(slapy2(alpha, sqrtf(xn2)), alpha);
        taui = (beta - alpha)/beta;
        sc = 1.0f/(alpha - beta);
      }
      taus[i] = taui; sh[0] = sc;
    }
    __syncthreads();
    {
      float sc = sh[0];
      for (int r=i+1+t; r<QRM; r+=256) A[r*QRN+i] *= sc;
    }
    __syncthreads();
    for (int j=i+1;j<QRN;j++){
      if (t == 0){
        float s0=A[i*QRN+j], s1=0,s2=0,s3=0;
        int r=i+1;
        for (; r+3<QRM; r+=4){
          s0 += A[r*QRN+i]*A[r*QRN+j];
          s1 += A[(r+1)*QRN+i]*A[(r+1)*QRN+j];
          s2 += A[(r+2)*QRN+i]*A[(r+2)*QRN+j];
          s3 += A[(r+3)*QRN+i]*A[(r+3)*QRN+j];
        }
        for (; r<QRM; r++) s0 += A[r*QRN+i]*A[r*QRN+j];
        sh[0] = taus[i]*((s0+s1)+(s2+s3));
      }
      __syncthreads();
      {
        float w = sh[0];
        for (int r=i+t; r<QRM; r+=256){
          float vr = (r==i) ? 1.0f : A[r*QRN+i];
          A[r*QRN+j] -= w*vr;
        }
      }
      __syncthreads();
    }
  }
  // ---- sorg2r ----
  for (int i=QRN-1;i>=0;i--){
    for (int j=i+1;j<QRN;j++){
      if (t == 0){
        float s0=A[i*QRN+j], s1=0,s2=0,s3=0;
        int r=i+1;
        for (; r+3<QRM; r+=4){
          s0 += A[r*QRN+i]*A[r*QRN+j];
          s1 += A[(r+1)*QRN+i]*A[(r+1)*QRN+j];
          s2 += A[(r+2)*QRN+i]*A[(r+2)*QRN+j];
          s3 += A[(r+3)*QRN+i]*A[(r+3)*QRN+j];
        }
        for (; r<QRM; r++) s0 += A[r*QRN+i]*A[r*QRN+j];
        sh[0] = taus[i]*((s0+s1)+(s2+s3));
      }
      __syncthreads();
      {
        float w = sh[0];
        for (int r=i+t; r<QRM; r+=256){
          float vr = (r==i) ? 1.0f : A[r*QRN+i];
          A[r*QRN+j] -= w*vr;
        }
      }
      __syncthreads();
    }
    {
      float taui = taus[i];
      for (int r=i+1+t; r<QRM; r+=256) A[r*QRN+i] *= -taui;
    }
    __syncthreads();
    if (t == 0) A[i*QRN+i] = 1.0f - taus[i];
    if (t < i) A[t*QRN+i] = 0.0f;
    __syncthreads();
  }
  for (int idx=t; idx<QRM*QRN; idx+=256)
    vout[(size_t)g*LSZ*V3 + idx] = 16.0f*A[idx];
}

__global__ __launch_bounds__(256) void final_kernel(const float* __restrict__ embf,
    const float* __restrict__ vf, const float* __restrict__ Rg, float* __restrict__ out){
  int n = blockIdx.x, t = threadIdx.x;
  out[(size_t)n*EMB + t] = embf[(size_t)n*EMB + t];
  if (t < V3){
    int m = t/3, ii = t - m*3;
    const float* Rp = Rg + (size_t)n*9;
    const float* vp = vf + (size_t)n*V3 + m*3;
    float val = Rp[ii*3+0]*vp[0] + Rp[ii*3+1]*vp[1] + Rp[ii*3+2]*vp[2];
    out[(size_t)NN*EMB + (size_t)n*V3 + t] = val;
  }
}

// ---------------- host ----------------
extern "C" void kernel_launch(void* const* d_in, const int* in_sizes, int n_in,
                              void* d_out, int out_size, void* d_ws, size_t ws_size,
                              hipStream_t stream){
  (void)in_sizes; (void)n_in; (void)out_size; (void)ws_size;
  const float* x       = (const float*)d_in[0];
  const float* bb      = (const float*)d_in[1];
  const float* in_ln_g = (const float*)d_in[2];
  const float* in_ln_b = (const float*)d_in[3];
  const float* in_W    = (const float*)d_in[4];
  const float* in_b    = (const float*)d_in[5];
  const float* msg_W1  = (const float*)d_in[6];
  const float* msg_b1  = (const float*)d_in[7];
  const float* msg_W2  = (const float*)d_in[8];
  const float* msg_b2  = (const float*)d_in[9];
  const float* msg_W3  = (const float*)d_in[10];
  const float* msg_b3  = (const float*)d_in[11];
  const float* vect_W  = (const float*)d_in[12];
  const float* ln_g    = (const float*)d_in[13];
  const float* ln_b    = (const float*)d_in[14];
  const int*   col     = (const int*)d_in[16];

  char* p = (char*)d_ws;
  auto alloc = [&](size_t bytes)->void*{ void* r = (void*)p; p += (bytes + 255) & ~(size_t)255; return r; };
  float*  Rg    = (float*) alloc((size_t)NN*9*4);
  float*  tg    = (float*) alloc((size_t)NN*3*4);
  float*  xln   = (float*) alloc((size_t)NN*IND*4);
  float*  eA    = (float*) alloc((size_t)NN*EMB*4);
  float*  eB    = (float*) alloc((size_t)NN*EMB*4);
  float*  vA    = (float*) alloc((size_t)NN*V3*4);
  float*  vB    = (float*) alloc((size_t)NN*V3*4);
  float*  vu    = (float*) alloc((size_t)NN*V3*4);
  float*  Redge = (float*) alloc((size_t)EE*9*4);
  float*  eattr = (float*) alloc((size_t)EE*EAP*4);
  unsigned short* W2Thi = (unsigned short*)alloc((size_t)3*65536*2);
  unsigned short* W2Tlo = (unsigned short*)alloc((size_t)3*65536*2);

  const int NV = NN*V3;
  fill_kernel<<<(NV+255)/256, 256, 0, stream>>>(vA, NV, 0.0f);
  wsplit_kernel<<<768, 256, 0, stream>>>(msg_W2, W2Thi, W2Tlo);
  rigid_kernel<<<(NN+63)/64, 64, 0, stream>>>(bb, Rg, tg);
  ln_kernel<<<NN, 256, 0, stream>>>(x, in_ln_g, in_ln_b, xln);
  emb0_kernel<<<NN/8, 256, 0, stream>>>(xln, in_W, in_b, eA);
  edge_kernel<<<(EE+63)/64, 64, 0, stream>>>(bb, Rg, tg, col, Redge, eattr);

  float* ein = eA; float* eout = eB; float* vin = vA; float* vout = vB;
  for (int l=0; l<3; ++l){
    fused_kernel<<<NN, 256, 0, stream>>>(ein, vin, Redge, eattr, col,
        msg_W1 + (size_t)l*710*EMB, msg_b1 + (size_t)l*EMB,
        W2Thi + (size_t)l*65536, W2Tlo + (size_t)l*65536,
        msg_b2 + (size_t)l*EMB,
        msg_W3 + (size_t)l*EMB*EMB, msg_b3 + (size_t)l*EMB,
        vect_W + (size_t)l*(EMB+V3)*V3,
        ln_g + (size_t)l*EMB, ln_b + (size_t)l*EMB, eout, vu);
    qr_kernel<<<NG, 256, 0, stream>>>(vu, vout);
    float* tmp = ein; ein = eout; eout = tmp;
    tmp = vin; vin = vout; vout = tmp;
  }
  final_kernel<<<NN, 256, 0, stream>>>(ein, vin, Rg, (float*)d_out);
}

// Round 13
// 1799.901 us; speedup vs baseline: 1.3395x; 1.1261x over previous
//
#include <hip/hip_runtime.h>
#include <hip/hip_bf16.h>

#define NG   8
#define LSZ  256
#define NN   2048
#define KK   30
#define EE   61440
#define IND  1280
#define EMB  256
#define V3   15
#define EAP  156
#define QRM  768
#define QRN  5

#define F32_EPS    5.9604645e-08f
#define F32_EPS2   3.5527137e-15f
#define F32_SAFMIN 1.17549435e-38f

typedef __bf16 bf16x8 __attribute__((ext_vector_type(8)));
typedef float  f32x4  __attribute__((ext_vector_type(4)));
typedef short  s16x8  __attribute__((ext_vector_type(8)));

#define AK  456   // A stride (shorts), phase B (16B-aligned rows: 912B)
#define WK  448   // W1eff K extent
#define H1K 264   // h1 stride (shorts), phase C

__device__ __forceinline__ float bsumf(float v, float* rbuf){
  int t = threadIdx.x;
  __syncthreads();
  rbuf[t] = v;
  __syncthreads();
  for (int s=128; s>0; s>>=1){
    if (t < s) rbuf[t] += rbuf[t+s];
    __syncthreads();
  }
  float r = rbuf[0];
  __syncthreads();
  return r;
}
__device__ __forceinline__ float gelu_f(float x){
  return 0.5f*x*(1.0f + erff(x*0.70710678f));
}
__device__ __forceinline__ float s_sign(float a, float b){ return (b >= 0.0f) ? fabsf(a) : -fabsf(a); }
__device__ __forceinline__ float slapy2(float x, float y){
  float xa = fabsf(x), ya = fabsf(y);
  float w = fmaxf(xa, ya), z = fminf(xa, ya);
  if (z == 0.0f) return w;
  float t = z/w;
  return w*sqrtf(1.0f + t*t);
}
// RNE f32 -> bf16 bits
__device__ __forceinline__ unsigned short bf16_rne(float v){
  unsigned int u = __float_as_uint(v);
  u = u + 0x7FFFu + ((u>>16)&1u);
  return (unsigned short)(u>>16);
}
// LAPACK >=3.10 slartg (f32)
__device__ void slartg(float f, float g, float& c, float& s, float& r){
  const float safmin = F32_SAFMIN;
  const float safmax = 8.5070592e+37f;
  const float rtmin  = 1.0842022e-19f;
  const float rtmax  = 6.5243586e+18f;
  float f1 = fabsf(f), g1 = fabsf(g);
  if (g == 0.0f){ c = 1.0f; s = 0.0f; r = f; }
  else if (f == 0.0f){ c = 0.0f; s = (g >= 0.0f ? 1.0f : -1.0f); r = g1; }
  else {
    if (f1 > rtmin && f1 < rtmax && g1 > rtmin && g1 < rtmax){
      float d = sqrtf(f*f + g*g);
      c = f1/d;
      r = (f >= 0.0f ? d : -d);
      s = g/r;
    } else {
      float u = fminf(safmax, fmaxf(safmin, fmaxf(f1,g1)));
      float fs = f/u, gs = g/u;
      float d = sqrtf(fs*fs + gs*gs);
      c = fabsf(fs)/d;
      r = (f >= 0.0f ? d : -d);
      s = gs/r;
      r = r*u;
    }
  }
}
__device__ void slaev2(float a, float b, float c, float& rt1, float& rt2, float& cs1, float& sn1){
  float sm = a + c, df = a - c, adf = fabsf(df), tb = b + b, ab = fabsf(tb);
  float acmx, acmn;
  if (fabsf(a) > fabsf(c)) { acmx=a; acmn=c; } else { acmx=c; acmn=a; }
  float rt;
  if (adf > ab){ float t = ab/adf; rt = adf*sqrtf(1.0f+t*t); }
  else if (adf < ab){ float t = adf/ab; rt = ab*sqrtf(1.0f+t*t); }
  else rt = ab*sqrtf(2.0f);
  int sgn1;
  if (sm < 0.0f){ rt1 = 0.5f*(sm-rt); sgn1 = -1; rt2 = (acmx/rt1)*acmn - (b/rt1)*b; }
  else if (sm > 0.0f){ rt1 = 0.5f*(sm+rt); sgn1 = 1; rt2 = (acmx/rt1)*acmn - (b/rt1)*b; }
  else { rt1 = 0.5f*rt; rt2 = -0.5f*rt; sgn1 = 1; }
  float cs; int sgn2;
  if (df >= 0.0f){ cs = df + rt; sgn2 = 1; } else { cs = df - rt; sgn2 = -1; }
  float acs = fabsf(cs);
  if (acs > ab){
    float ct = -tb/cs; sn1 = 1.0f/sqrtf(1.0f+ct*ct); cs1 = ct*sn1;
  } else {
    if (ab == 0.0f){ cs1 = 1.0f; sn1 = 0.0f; }
    else { float tn = -cs/tb; cs1 = 1.0f/sqrtf(1.0f+tn*tn); sn1 = tn*cs1; }
  }
  if (sgn1 == sgn2){ float tn = cs1; cs1 = -sn1; sn1 = tn; }
}

// f32 ssytd2('L') + ssteqr('I') for 4x4; returns eigvec of largest eigenvalue.
__device__ void sym4_quat_f32(float (&a)[4][4], float* q){
  float d[4], e[3];
  float tau0 = 0.0f, tau1 = 0.0f;
  float v31 = 0.0f, v41 = 0.0f, v42 = 0.0f;
  {
    float alpha = a[1][0];
    float x1 = a[2][0], x2 = a[3][0];
    float xnorm = sqrtf(x1*x1 + x2*x2);
    if (xnorm == 0.0f){ tau0 = 0.0f; e[0] = alpha; }
    else {
      float beta = -s_sign(slapy2(alpha, xnorm), alpha);
      tau0 = (beta - alpha)/beta;
      float sc = 1.0f/(alpha - beta);
      x1 *= sc; x2 *= sc;
      e[0] = beta;
      float p0 = tau0*(a[1][1] + a[2][1]*x1 + a[3][1]*x2);
      float p1 = tau0*(a[2][1] + a[2][2]*x1 + a[3][2]*x2);
      float p2 = tau0*(a[3][1] + a[3][2]*x1 + a[3][3]*x2);
      float al = -0.5f*tau0*(p0 + p1*x1 + p2*x2);
      p0 += al; p1 += al*x1; p2 += al*x2;
      a[1][1] -= 2.0f*p0;
      a[2][1] -= x1*p0 + p1;
      a[3][1] -= x2*p0 + p2;
      a[2][2] -= 2.0f*x1*p1;
      a[3][2] -= x2*p1 + p2*x1;
      a[3][3] -= 2.0f*x2*p2;
    }
    v31 = x1; v41 = x2;
  }
  {
    float alpha = a[2][1];
    float x1 = a[3][1];
    float xnorm = fabsf(x1);
    if (xnorm == 0.0f){ tau1 = 0.0f; e[1] = alpha; }
    else {
      float beta = -s_sign(slapy2(alpha, xnorm), alpha);
      tau1 = (beta - alpha)/beta;
      x1 *= 1.0f/(alpha - beta);
      e[1] = beta;
      float p0 = tau1*(a[2][2] + a[3][2]*x1);
      float p1 = tau1*(a[3][2] + a[3][3]*x1);
      float al = -0.5f*tau1*(p0 + p1*x1);
      p0 += al; p1 += al*x1;
      a[2][2] -= 2.0f*p0;
      a[3][2] -= x1*p0 + p1;
      a[3][3] -= 2.0f*x1*p1;
    }
    v42 = x1;
  }
  e[2] = a[3][2];
  d[0]=a[0][0]; d[1]=a[1][1]; d[2]=a[2][2]; d[3]=a[3][3];
  float z[4][4] = {{1,0,0,0},{0,1,0,0},{0,0,1,0},{0,0,0,1}};
  const float eps = F32_EPS;
  const float eps2 = F32_EPS2;
  const float safmin = F32_SAFMIN;
  int jtot = 0;
  const int nmaxit = 120;
  int l1 = 0;
  bool fail = false;
  while (!fail){
    if (l1 > 3) break;
    if (l1 > 0) e[l1-1] = 0.0f;
    int lend = 3;
    for (int mm = l1; mm <= 2; ++mm){
      float tst = fabsf(e[mm]);
      if (tst == 0.0f){ lend = mm; break; }
      if (tst <= (sqrtf(fabsf(d[mm]))*sqrtf(fabsf(d[mm+1])))*eps){ e[mm] = 0.0f; lend = mm; break; }
    }
    int l = l1;
    int lsv = l, lendsv = lend;
    l1 = lend + 1;
    if (lend == l) continue;
    float anorm = fabsf(d[l]);
    for (int ii=l+1; ii<=lend; ++ii) anorm = fmaxf(anorm, fabsf(d[ii]));
    for (int ii=l; ii<lend; ++ii)    anorm = fmaxf(anorm, fabsf(e[ii]));
    if (anorm == 0.0f) continue;
    if (fabsf(d[lend]) < fabsf(d[l])){ lend = lsv; l = lendsv; }
    if (lend > l){
      for (;;){
        int m = lend;
        if (l != lend){
          for (int mm=l; mm<=lend-1; ++mm){
            float tst = e[mm]*e[mm];
            if (tst <= (eps2*fabsf(d[mm]))*fabsf(d[mm+1]) + safmin){ m = mm; break; }
          }
        }
        if (m < lend) e[m] = 0.0f;
        float p = d[l];
        if (m == l){
          d[l] = p; ++l;
          if (l <= lend) continue;
          break;
        }
        if (m == l+1){
          float rt1, rt2, c, s;
          slaev2(d[l], e[l], d[l+1], rt1, rt2, c, s);
          #pragma unroll
          for (int r2=0;r2<4;r2++){
            float t_ = z[r2][l+1];
            z[r2][l+1] = c*t_ - s*z[r2][l];
            z[r2][l]   = s*t_ + c*z[r2][l];
          }
          d[l]=rt1; d[l+1]=rt2; e[l]=0.0f;
          l += 2;
          if (l <= lend) continue;
          break;
        }
        if (jtot == nmaxit){ fail = true; break; }
        ++jtot;
        float g = (d[l+1]-p)/(2.0f*e[l]);
        float r_ = slapy2(g, 1.0f);
        g = d[m] - p + e[l]/(g + s_sign(r_, g));
        float s = 1.0f, c = 1.0f;
        p = 0.0f;
        float csv[3], snv[3];
        for (int i=m-1; i>=l; --i){
          float f = s*e[i], b = c*e[i];
          slartg(g, f, c, s, r_);
          if (i != m-1) e[i+1] = r_;
          g = d[i+1] - p;
          r_ = (d[i]-g)*s + 2.0f*c*b;
          p = s*r_;
          d[i+1] = g + p;
          g = c*r_ - b;
          csv[i] = c; snv[i] = -s;
        }
        for (int i=m-1; i>=l; --i){
          float cc = csv[i], ss = snv[i];
          #pragma unroll
          for (int r2=0;r2<4;r2++){
            float t_ = z[r2][i+1];
            z[r2][i+1] = cc*t_ - ss*z[r2][i];
            z[r2][i]   = ss*t_ + cc*z[r2][i];
          }
        }
        d[l] -= p; e[l] = g;
      }
    } else {
      for (;;){
        int m = lend;
        if (l != lend){
          for (int mm=l; mm>=lend+1; --mm){
            float tst = e[mm-1]*e[mm-1];
            if (tst <= (eps2*fabsf(d[mm]))*fabsf(d[mm-1]) + safmin){ m = mm; break; }
          }
        }
        if (m > lend) e[m-1] = 0.0f;
        float p = d[l];
        if (m == l){
          d[l] = p; --l;
          if (l >= lend) continue;
          break;
        }
        if (m == l-1){
          float rt1, rt2, c, s;
          slaev2(d[l-1], e[l-1], d[l], rt1, rt2, c, s);
          #pragma unroll
          for (int r2=0;r2<4;r2++){
            float t_ = z[r2][l];
            z[r2][l]   = c*t_ - s*z[r2][l-1];
            z[r2][l-1] = s*t_ + c*z[r2][l-1];
          }
          d[l-1]=rt1; d[l]=rt2; e[l-1]=0.0f;
          l -= 2;
          if (l >= lend) continue;
          break;
        }
        if (jtot == nmaxit){ fail = true; break; }
        ++jtot;
        float g = (d[l-1]-p)/(2.0f*e[l-1]);
        float r_ = slapy2(g, 1.0f);
        g = d[m] - p + e[l-1]/(g + s_sign(r_, g));
        float s = 1.0f, c = 1.0f;
        p = 0.0f;
        float csv[3], snv[3];
        for (int i=m; i<=l-1; ++i){
          float f = s*e[i], b = c*e[i];
          slartg(g, f, c, s, r_);
          if (i != m) e[i-1] = r_;
          g = d[i] - p;
          r_ = (d[i+1]-g)*s + 2.0f*c*b;
          p = s*r_;
          d[i] = g + p;
          g = c*r_ - b;
          csv[i] = c; snv[i] = s;
        }
        for (int i=m; i<=l-1; ++i){
          float cc = csv[i], ss = snv[i];
          #pragma unroll
          for (int r2=0;r2<4;r2++){
            float t_ = z[r2][i+1];
            z[r2][i+1] = cc*t_ - ss*z[r2][i];
            z[r2][i]   = ss*t_ + cc*z[r2][i];
          }
        }
        d[l] -= p; e[l-1] = g;
      }
    }
  }
  for (int ii=1; ii<4; ++ii){
    int i0 = ii-1, k0 = i0;
    float p = d[i0];
    for (int j2=ii; j2<4; ++j2) if (d[j2] < p){ k0 = j2; p = d[j2]; }
    if (k0 != i0){
      d[k0] = d[i0]; d[i0] = p;
      #pragma unroll
      for (int r2=0;r2<4;r2++){ float t_ = z[r2][i0]; z[r2][i0] = z[r2][k0]; z[r2][k0] = t_; }
    }
  }
  float w0 = z[0][3], w1 = z[1][3], w2 = z[2][3], w3 = z[3][3];
  if (tau1 != 0.0f){
    float dv = w2 + v42*w3;
    w2 -= tau1*dv;
    w3 -= tau1*dv*v42;
  }
  if (tau0 != 0.0f){
    float dv = w1 + v31*w2 + v41*w3;
    w1 -= tau0*dv;
    w2 -= tau0*dv*v31;
    w3 -= tau0*dv*v41;
  }
  q[0]=w0; q[1]=w1; q[2]=w2; q[3]=w3;
}

// ---------------- kernels ----------------
__global__ void fill_kernel(float* __restrict__ p, int nelem, float val){
  int i = blockIdx.x*blockDim.x + threadIdx.x;
  if (i < nelem) p[i] = val;
}

// Pre-split W2 (3 layers) into transposed bf16 hi/lo: out[l][j][k]
__global__ __launch_bounds__(256) void wsplit2_kernel(const float* __restrict__ W2,
    unsigned short* __restrict__ hi, unsigned short* __restrict__ lo){
  int idx = blockIdx.x*256 + threadIdx.x;
  int l = idx >> 16; int rem = idx & 65535; int k = rem >> 8; int j = rem & 255;
  float v = W2[(size_t)l*65536 + (size_t)k*256 + j];
  unsigned short hb = bf16_rne(v);
  float hf = __uint_as_float(((unsigned int)hb)<<16);
  unsigned short lb = bf16_rne(v - hf);
  size_t o = (size_t)l*65536 + (size_t)j*256 + k;
  hi[o] = hb; lo[o] = lb;
}

// Build W1eff^T (3 layers): [l][j][k], k<448:
//   k<256        -> W1[256+k][j]
//   256<=k<416   -> kk=k-256: kk<153 ? W1[557+kk][j] : 0
//   416<=k<432   -> r=k-416:  r<15 ? W1[527+r][j]-W1[542+r][j] : 0
//   else 0
__global__ __launch_bounds__(256) void wsplit1_kernel(const float* __restrict__ W1,
    unsigned short* __restrict__ hi, unsigned short* __restrict__ lo){
  int idx = blockIdx.x*256 + threadIdx.x;
  if (idx >= 3*256*WK) return;
  int l = idx / (256*WK); int rem = idx - l*(256*WK);
  int j = rem / WK; int k = rem - j*WK;
  const float* Wl = W1 + (size_t)l*710*EMB;
  float v = 0.0f;
  if (k < 256) v = Wl[(size_t)(256+k)*EMB + j];
  else if (k < 416){ int kk = k-256; if (kk < 153) v = Wl[(size_t)(557+kk)*EMB + j]; }
  else if (k < 432){ int r = k-416; if (r < 15) v = Wl[(size_t)(527+r)*EMB + j] - Wl[(size_t)(542+r)*EMB + j]; }
  unsigned short hb = bf16_rne(v);
  float hf = __uint_as_float(((unsigned int)hb)<<16);
  unsigned short lb = bf16_rne(v - hf);
  size_t o = (size_t)l*(256*WK) + (size_t)j*WK + k;
  hi[o] = hb; lo[o] = lb;
}

__global__ void rigid_kernel(const float* __restrict__ bb, float* __restrict__ Rg, float* __restrict__ tg){
  int n = blockIdx.x*blockDim.x + threadIdx.x;
  if (n >= NN) return;
  const float* p = bb + (size_t)n*9;
  float nx=p[0],ny=p[1],nz=p[2], cax=p[3],cay=p[4],caz=p[5], cx=p[6],cy=p[7],cz=p[8];
  float e1x=cx-cax, e1y=cy-cay, e1z=cz-caz;
  float n1 = sqrtf(e1x*e1x+e1y*e1y+e1z*e1z);
  e1x/=n1; e1y/=n1; e1z/=n1;
  float ux=nx-cax, uy=ny-cay, uz=nz-caz;
  float du = ux*e1x+uy*e1y+uz*e1z;
  float e2x=ux-du*e1x, e2y=uy-du*e1y, e2z=uz-du*e1z;
  float n2 = sqrtf(e2x*e2x+e2y*e2y+e2z*e2z);
  e2x/=n2; e2y/=n2; e2z/=n2;
  float e3x=e1y*e2z-e1z*e2y, e3y=e1z*e2x-e1x*e2z, e3z=e1x*e2y-e1y*e2x;
  float* R = Rg + (size_t)n*9;
  R[0]=e1x; R[1]=e2x; R[2]=e3x;
  R[3]=e1y; R[4]=e2y; R[5]=e3y;
  R[6]=e1z; R[7]=e2z; R[8]=e3z;
  tg[(size_t)n*3+0]=cax; tg[(size_t)n*3+1]=cay; tg[(size_t)n*3+2]=caz;
}

__global__ __launch_bounds__(256) void ln_kernel(const float* __restrict__ x,
    const float* __restrict__ g, const float* __restrict__ b, float* __restrict__ xln){
  int n = blockIdx.x, t = threadIdx.x;
  __shared__ float rbuf[256];
  float v[5];
  float s = 0.0f;
  #pragma unroll
  for (int i=0;i<5;i++){ v[i] = x[(size_t)n*IND + t + i*256]; s += v[i]; }
  float mu = bsumf(s, rbuf)*(1.0f/IND);
  float pv = 0.0f;
  #pragma unroll
  for (int i=0;i<5;i++){ float dd = v[i]-mu; pv += dd*dd; }
  float var = bsumf(pv, rbuf)*(1.0f/IND);
  float rs = 1.0f/sqrtf(var + 1e-5f);
  #pragma unroll
  for (int i=0;i<5;i++){
    int k = t + i*256;
    xln[(size_t)n*IND + k] = g[k]*((v[i]-mu)*rs) + b[k];
  }
}

// emb0 with LDS staging (R10 form).
__global__ __launch_bounds__(256) void emb0_kernel(const float* __restrict__ xln,
    const float* __restrict__ W, const float* __restrict__ bias, float* __restrict__ emb){
  int n0 = blockIdx.x*8, j = threadIdx.x;
  __shared__ float s_x[8][IND];   // 40 KB
  for (int idx=j; idx<8*IND; idx+=256){
    int i = idx/IND, k = idx - i*IND;
    s_x[i][k] = xln[(size_t)(n0+i)*IND + k];
  }
  __syncthreads();
  float acc[8];
  #pragma unroll
  for (int i=0;i<8;i++) acc[i] = bias[j];
  for (int k=0;k<IND;k+=4){
    float w0=W[(size_t)(k+0)*EMB+j], w1=W[(size_t)(k+1)*EMB+j], w2=W[(size_t)(k+2)*EMB+j], w3=W[(size_t)(k+3)*EMB+j];
    #pragma unroll
    for (int i=0;i<8;i++){
      const float* xp = &s_x[i][k];
      acc[i] += xp[0]*w0 + xp[1]*w1 + xp[2]*w2 + xp[3]*w3;
    }
  }
  #pragma unroll
  for (int i=0;i<8;i++) emb[(size_t)(n0+i)*EMB + j] = acc[i];
}

__global__ __launch_bounds__(64) void edge_kernel(const float* __restrict__ bb,
    const float* __restrict__ Rg, const float* __restrict__ tg,
    const int* __restrict__ col, float* __restrict__ Redge, float* __restrict__ eattr){
  int e = blockIdx.x*64 + threadIdx.x;
  if (e >= EE) return;
  int i = e/KK;
  int jn = col[e];
  float Ri[9], Rj[9];
  #pragma unroll
  for (int a=0;a<9;a++){ Ri[a]=Rg[(size_t)i*9+a]; Rj[a]=Rg[(size_t)jn*9+a]; }
  float dt0 = tg[(size_t)jn*3+0]-tg[(size_t)i*3+0];
  float dt1 = tg[(size_t)jn*3+1]-tg[(size_t)i*3+1];
  float dt2 = tg[(size_t)jn*3+2]-tg[(size_t)i*3+2];
  float Re[9];
  #pragma unroll
  for (int a=0;a<3;a++){
    #pragma unroll
    for (int c=0;c<3;c++)
      Re[a*3+c] = Ri[0+a]*Rj[0+c] + Ri[3+a]*Rj[3+c] + Ri[6+a]*Rj[6+c];
  }
  float te0 = Ri[0]*dt0 + Ri[3]*dt1 + Ri[6]*dt2;
  float te1 = Ri[1]*dt0 + Ri[4]*dt1 + Ri[7]*dt2;
  float te2 = Ri[2]*dt0 + Ri[5]*dt1 + Ri[8]*dt2;
  float xx=Re[0], xy=Re[1], xz=Re[2], yx=Re[3], yy=Re[4], yz=Re[5], zx=Re[6], zy=Re[7], zz=Re[8];
  float km[4][4];
  km[0][0]=(xx+yy+zz)/3.0f; km[0][1]=(zy-yz)/3.0f;    km[0][2]=(xz-zx)/3.0f;    km[0][3]=(yx-xy)/3.0f;
  km[1][0]=km[0][1];        km[1][1]=(xx-yy-zz)/3.0f; km[1][2]=(xy+yx)/3.0f;    km[1][3]=(xz+zx)/3.0f;
  km[2][0]=km[0][2];        km[2][1]=km[1][2];        km[2][2]=(yy-xx-zz)/3.0f; km[2][3]=(yz+zy)/3.0f;
  km[3][0]=km[0][3];        km[3][1]=km[1][3];        km[3][2]=km[2][3];        km[3][3]=(zz-xx-yy)/3.0f;
  float q[4];
  sym4_quat_f32(km, q);
  float* ea = eattr + (size_t)e*EAP;
  ea[0]=q[0]; ea[1]=q[1]; ea[2]=q[2]; ea[3]=q[3];
  ea[4]=te0;  ea[5]=te1;  ea[6]=te2;
  int cd = i - jn; if (cd < 0) cd = -cd;
  ea[7] = logf((float)cd + 1.0f);
  ea[8] = logf(sqrtf(te0*te0+te1*te1+te2*te2) + 1e-8f);
  const float* bi = bb + (size_t)i*9;
  const float* bj = bb + (size_t)jn*9;
  int idx = 9;
  #pragma unroll
  for (int a=0;a<3;a++){
    float ax=bi[a*3+0], ay=bi[a*3+1], az=bi[a*3+2];
    #pragma unroll
    for (int b2=0;b2<3;b2++){
      float dx=ax-bj[b2*3+0], dy=ay-bj[b2*3+1], dz=az-bj[b2*3+2];
      float dd = sqrtf(fmaxf(dx*dx+dy*dy+dz*dz, 1e-12f));
      #pragma unroll
      for (int kb=0;kb<16;kb++){
        float muv = 1.3333334f*(float)kb;
        float df = dd - muv;
        ea[idx] = expf(-0.5f*df*df);
        idx++;
      }
    }
  }
  ea[153]=0.0f; ea[154]=0.0f; ea[155]=0.0f;
  #pragma unroll
  for (int a=0;a<9;a++) Redge[(size_t)e*9+a] = Re[a];
}

// Fused: phase B AND phase C via MFMA bf16x2-split. csh exact f32. LN/vu epilogue as R12.
__global__ __launch_bounds__(256, 4) void fused_kernel(
    const float* __restrict__ emb_in, const float* __restrict__ v_in,
    const float* __restrict__ Redge, const float* __restrict__ eattr,
    const int* __restrict__ col,
    const float* __restrict__ W1, const float* __restrict__ b1,
    const unsigned short* __restrict__ W1Thi, const unsigned short* __restrict__ W1Tlo,
    const unsigned short* __restrict__ W2Thi, const unsigned short* __restrict__ W2Tlo,
    const float* __restrict__ b2,
    const float* __restrict__ W3, const float* __restrict__ b3,
    const float* __restrict__ vW,
    const float* __restrict__ lng, const float* __restrict__ lnb,
    float* __restrict__ emb_out, float* __restrict__ vu_out){
  int n = blockIdx.x, j = threadIdx.x;
  size_t e0 = (size_t)n*KK;
  __shared__ __align__(16) char smem[36864];
  __shared__ float s_xi[EMB];
  __shared__ float s_vi[16];
  unsigned short* Abuf = (unsigned short*)smem;    // [32][AK] phase B (29184 B)
  unsigned short* h1hi = (unsigned short*)smem;    // [32][H1K] phase C
  unsigned short* h1lo = h1hi + 32*H1K;            // ends at 33792
  float* cshb = (float*)(smem + 33792);            // [256]
  float* sbuf = (float*)(smem + 34816);            // [256]
  float* rbuf = (float*)(smem + 35840);            // [256]

  s_xi[j] = emb_in[(size_t)n*EMB + j];
  if (j < 16) s_vi[j] = (j < V3) ? v_in[(size_t)n*V3 + j] : 0.0f;

  // ---- stage A (half = 0:hi, 1:lo) ----
  auto stageA = [&](int half){
    #pragma unroll 1
    for (int e=0;e<KK;e++){
      int cj = col[e0+e];
      float v = emb_in[(size_t)cj*EMB + j];
      unsigned short hb = bf16_rne(v);
      unsigned short out = hb;
      if (half){ float hf = __uint_as_float(((unsigned int)hb)<<16); out = bf16_rne(v - hf); }
      Abuf[e*AK + j] = out;
    }
    for (int idx=j; idx<KK*160; idx+=256){
      int e = idx/160, kk = idx - e*160;
      float v = (kk < 156) ? eattr[(e0+e)*EAP + kk] : 0.0f;
      unsigned short hb = bf16_rne(v);
      unsigned short out = hb;
      if (half){ float hf = __uint_as_float(((unsigned int)hb)<<16); out = bf16_rne(v - hf); }
      Abuf[e*AK + 256 + kk] = out;
    }
    for (int idx=j; idx<KK*32; idx+=256){
      int e = idx>>5, r = idx&31;
      float v = 0.0f;
      if (r < V3){
        int m = r/3, ii = r - m*3;
        int cj = col[e0+e];
        const float* Rp = Redge + (e0+e)*9;
        const float* vp = v_in + (size_t)cj*V3 + m*3;
        v = Rp[ii*3+0]*vp[0] + Rp[ii*3+1]*vp[1] + Rp[ii*3+2]*vp[2];
      }
      unsigned short hb = bf16_rne(v);
      unsigned short out = hb;
      if (half){ float hf = __uint_as_float(((unsigned int)hb)<<16); out = bf16_rne(v - hf); }
      Abuf[e*AK + 416 + r] = out;
    }
    for (int idx=j; idx<2*WK; idx+=256){
      int rr = 30 + idx/WK, c = idx%WK;
      Abuf[rr*AK + c] = 0;
    }
  };

  stageA(0);
  __syncthreads();

  // csh (exact f32): b1 + x_i.W1[0:256] + v_i terms; store for fragment epilogue
  {
    float csh = b1[j];
    for (int k=0;k<EMB;k+=4){
      float w0=W1[(size_t)(k+0)*EMB+j], w1=W1[(size_t)(k+1)*EMB+j], w2=W1[(size_t)(k+2)*EMB+j], w3=W1[(size_t)(k+3)*EMB+j];
      csh += s_xi[k+0]*w0 + s_xi[k+1]*w1 + s_xi[k+2]*w2 + s_xi[k+3]*w3;
    }
    #pragma unroll
    for (int r=0;r<V3;r++) csh += s_vi[r]*(W1[(size_t)(512+r)*EMB+j] + W1[(size_t)(542+r)*EMB+j]);
    cshb[j] = csh;
  }

  int l = j & 63, w = j >> 6;
  f32x4 cacc[2][4];
  #pragma unroll
  for (int mt=0;mt<2;mt++)
    #pragma unroll
    for (int nt=0;nt<4;nt++)
      #pragma unroll
      for (int rg=0;rg<4;rg++) cacc[mt][nt][rg] = 0.0f;

  // pass 1: aH x (Bh, Bl)
  for (int kt=0;kt<14;kt++){
    int k0 = kt*32 + (l>>4)*8;
    bf16x8 aH[2];
    #pragma unroll
    for (int mt=0;mt<2;mt++){
      int row = mt*16 + (l&15);
      aH[mt] = __builtin_bit_cast(bf16x8, *(const s16x8*)&Abuf[row*AK + k0]);
    }
    #pragma unroll
    for (int nt=0;nt<4;nt++){
      int colj = w*64 + nt*16 + (l&15);
      bf16x8 Bh = __builtin_bit_cast(bf16x8, *(const s16x8*)&W1Thi[(size_t)colj*WK + k0]);
      bf16x8 Bl = __builtin_bit_cast(bf16x8, *(const s16x8*)&W1Tlo[(size_t)colj*WK + k0]);
      #pragma unroll
      for (int mt=0;mt<2;mt++){
        cacc[mt][nt] = __builtin_amdgcn_mfma_f32_16x16x32_bf16(aH[mt], Bh, cacc[mt][nt], 0,0,0);
        cacc[mt][nt] = __builtin_amdgcn_mfma_f32_16x16x32_bf16(aH[mt], Bl, cacc[mt][nt], 0,0,0);
      }
    }
  }
  __syncthreads();
  stageA(1);
  __syncthreads();
  // pass 2: aL x Bh
  for (int kt=0;kt<14;kt++){
    int k0 = kt*32 + (l>>4)*8;
    bf16x8 aL[2];
    #pragma unroll
    for (int mt=0;mt<2;mt++){
      int row = mt*16 + (l&15);
      aL[mt] = __builtin_bit_cast(bf16x8, *(const s16x8*)&Abuf[row*AK + k0]);
    }
    #pragma unroll
    for (int nt=0;nt<4;nt++){
      int colj = w*64 + nt*16 + (l&15);
      bf16x8 Bh = __builtin_bit_cast(bf16x8, *(const s16x8*)&W1Thi[(size_t)colj*WK + k0]);
      #pragma unroll
      for (int mt=0;mt<2;mt++)
        cacc[mt][nt] = __builtin_amdgcn_mfma_f32_16x16x32_bf16(aL[mt], Bh, cacc[mt][nt], 0,0,0);
    }
  }
  __syncthreads();
  // epilogue phase B: h1 = gelu(acc + csh[col]); split -> h1hi/h1lo (overwrites Abuf)
  #pragma unroll
  for (int mt=0;mt<2;mt++){
    #pragma unroll
    for (int nt=0;nt<4;nt++){
      int colj = w*64 + nt*16 + (l&15);
      float cshv = cshb[colj];
      #pragma unroll
      for (int rg=0;rg<4;rg++){
        int row = mt*16 + ((l>>4)&3)*4 + rg;
        float val = 0.0f;
        if (row < KK) val = gelu_f(cacc[mt][nt][rg] + cshv);
        unsigned short hb = bf16_rne(val);
        float hf = __uint_as_float(((unsigned int)hb)<<16);
        unsigned short lb = bf16_rne(val - hf);
        h1hi[row*H1K + colj] = hb;
        h1lo[row*H1K + colj] = lb;
      }
    }
  }
  __syncthreads();

  // ---- phase C: h2 via MFMA (R12-validated) ----
  f32x4 dacc[2][4];
  #pragma unroll
  for (int mt=0;mt<2;mt++)
    #pragma unroll
    for (int nt=0;nt<4;nt++)
      #pragma unroll
      for (int rg=0;rg<4;rg++) dacc[mt][nt][rg] = 0.0f;
  for (int kt=0;kt<8;kt++){
    int k0 = kt*32 + (l>>4)*8;
    bf16x8 aH[2], aL[2];
    #pragma unroll
    for (int mt=0;mt<2;mt++){
      int row = mt*16 + (l&15);
      aH[mt] = __builtin_bit_cast(bf16x8, *(const s16x8*)&h1hi[row*H1K + k0]);
      aL[mt] = __builtin_bit_cast(bf16x8, *(const s16x8*)&h1lo[row*H1K + k0]);
    }
    #pragma unroll
    for (int nt=0;nt<4;nt++){
      int colj = w*64 + nt*16 + (l&15);
      bf16x8 Bh = __builtin_bit_cast(bf16x8, *(const s16x8*)&W2Thi[(size_t)colj*256 + k0]);
      bf16x8 Bl = __builtin_bit_cast(bf16x8, *(const s16x8*)&W2Tlo[(size_t)colj*256 + k0]);
      #pragma unroll
      for (int mt=0;mt<2;mt++){
        dacc[mt][nt] = __builtin_amdgcn_mfma_f32_16x16x32_bf16(aH[mt], Bh, dacc[mt][nt], 0,0,0);
        dacc[mt][nt] = __builtin_amdgcn_mfma_f32_16x16x32_bf16(aH[mt], Bl, dacc[mt][nt], 0,0,0);
        dacc[mt][nt] = __builtin_amdgcn_mfma_f32_16x16x32_bf16(aL[mt], Bh, dacc[mt][nt], 0,0,0);
      }
    }
  }
  {
    float p[4];
    #pragma unroll
    for (int nt=0;nt<4;nt++){
      float b2v = b2[w*64 + nt*16 + (l&15)];
      float pp = 0.0f;
      #pragma unroll
      for (int mt=0;mt<2;mt++){
        #pragma unroll
        for (int rg=0;rg<4;rg++){
          int row = mt*16 + ((l>>4)&3)*4 + rg;
          if (row < KK) pp += gelu_f(dacc[mt][nt][rg] + b2v);
        }
      }
      pp += __shfl_xor(pp, 16);
      pp += __shfl_xor(pp, 32);
      p[nt] = pp;
    }
    if (l < 16){
      #pragma unroll
      for (int nt=0;nt<4;nt++) sbuf[w*64 + nt*16 + l] = p[nt];
    }
  }
  __syncthreads();
  // ---- epilogue: W3 dot, LN, vu ----
  float ag = 0.0f;
  for (int k=0;k<EMB;k+=4){
    float4 s4 = *(const float4*)&sbuf[k];
    ag += s4.x*W3[(size_t)(k+0)*EMB+j] + s4.y*W3[(size_t)(k+1)*EMB+j]
        + s4.z*W3[(size_t)(k+2)*EMB+j] + s4.w*W3[(size_t)(k+3)*EMB+j];
  }
  ag = ag*(1.0f/30.0f) + b3[j];
  float u = s_xi[j] + ag;
  float mu = bsumf(u, rbuf)*(1.0f/EMB);
  float dl = u - mu;
  float var = bsumf(dl*dl, rbuf)*(1.0f/EMB);
  float rs = 1.0f/sqrtf(var + 1e-5f);
  float y = lng[j]*dl*rs + lnb[j];
  emb_out[(size_t)n*EMB+j] = y;
  __syncthreads();
  sbuf[j] = y;
  __syncthreads();
  if (j < V3){
    float a = s_vi[j];
    for (int k=0;k<EMB;k++){
      a += sbuf[k]*vW[k*V3+j];
    }
    #pragma unroll
    for (int r=0;r<V3;r++) a += s_vi[r]*vW[(EMB+r)*V3+j];
    vu_out[(size_t)n*V3+j] = a;
  }
}

// Pure QR per graph (f32 sgeqr2/sorg2r, raw LAPACK signs) — untouched.
__global__ __launch_bounds__(256) void qr_kernel(
    const float* __restrict__ vu_in, float* __restrict__ vout){
  int g = blockIdx.x, t = threadIdx.x;
  __shared__ float A[QRM*QRN];
  __shared__ float meanv[V3];
  __shared__ float taus[QRN];
  __shared__ float sh[2];
  int n = g*LSZ + t;
  #pragma unroll
  for (int j=0;j<V3;j++) A[t*V3+j] = vu_in[(size_t)n*V3 + j];
  __syncthreads();
  if (t < V3){
    float s = 0.0f;
    for (int l0=0;l0<LSZ;l0++) s += A[l0*V3+t];
    meanv[t] = s/(float)LSZ;
  }
  __syncthreads();
  #pragma unroll
  for (int j=0;j<V3;j++) A[t*V3+j] -= meanv[j];
  __syncthreads();
  // ---- sgeqr2 ----
  for (int i=0;i<QRN;i++){
    if (t == 0){
      float s0=0,s1=0,s2=0,s3=0;
      int r=i+1;
      for (; r+3<QRM; r+=4){
        float x0=A[r*QRN+i], x1=A[(r+1)*QRN+i], x2=A[(r+2)*QRN+i], x3=A[(r+3)*QRN+i];
        s0+=x0*x0; s1+=x1*x1; s2+=x2*x2; s3+=x3*x3;
      }
      for (; r<QRM; r++){ float x=A[r*QRN+i]; s0+=x*x; }
      float xn2 = (s0+s1)+(s2+s3);
      float alpha = A[i*QRN+i];
      float taui = 0.0f, sc = 1.0f;
      if (xn2 != 0.0f){
        float beta = -s_sign(slapy2(alpha, sqrtf(xn2)), alpha);
        taui = (beta - alpha)/beta;
        sc = 1.0f/(alpha - beta);
      }
      taus[i] = taui; sh[0] = sc;
    }
    __syncthreads();
    {
      float sc = sh[0];
      for (int r=i+1+t; r<QRM; r+=256) A[r*QRN+i] *= sc;
    }
    __syncthreads();
    for (int j=i+1;j<QRN;j++){
      if (t == 0){
        float s0=A[i*QRN+j], s1=0,s2=0,s3=0;
        int r=i+1;
        for (; r+3<QRM; r+=4){
          s0 += A[r*QRN+i]*A[r*QRN+j];
          s1 += A[(r+1)*QRN+i]*A[(r+1)*QRN+j];
          s2 += A[(r+2)*QRN+i]*A[(r+2)*QRN+j];
          s3 += A[(r+3)*QRN+i]*A[(r+3)*QRN+j];
        }
        for (; r<QRM; r++) s0 += A[r*QRN+i]*A[r*QRN+j];
        sh[0] = taus[i]*((s0+s1)+(s2+s3));
      }
      __syncthreads();
      {
        float w = sh[0];
        for (int r=i+t; r<QRM; r+=256){
          float vr = (r==i) ? 1.0f : A[r*QRN+i];
          A[r*QRN+j] -= w*vr;
        }
      }
      __syncthreads();
    }
  }
  // ---- sorg2r ----
  for (int i=QRN-1;i>=0;i--){
    for (int j=i+1;j<QRN;j++){
      if (t == 0){
        float s0=A[i*QRN+j], s1=0,s2=0,s3=0;
        int r=i+1;
        for (; r+3<QRM; r+=4){
          s0 += A[r*QRN+i]*A[r*QRN+j];
          s1 += A[(r+1)*QRN+i]*A[(r+1)*QRN+j];
          s2 += A[(r+2)*QRN+i]*A[(r+2)*QRN+j];
          s3 += A[(r+3)*QRN+i]*A[(r+3)*QRN+j];
        }
        for (; r<QRM; r++) s0 += A[r*QRN+i]*A[r*QRN+j];
        sh[0] = taus[i]*((s0+s1)+(s2+s3));
      }
      __syncthreads();
      {
        float w = sh[0];
        for (int r=i+t; r<QRM; r+=256){
          float vr = (r==i) ? 1.0f : A[r*QRN+i];
          A[r*QRN+j] -= w*vr;
        }
      }
      __syncthreads();
    }
    {
      float taui = taus[i];
      for (int r=i+1+t; r<QRM; r+=256) A[r*QRN+i] *= -taui;
    }
    __syncthreads();
    if (t == 0) A[i*QRN+i] = 1.0f - taus[i];
    if (t < i) A[t*QRN+i] = 0.0f;
    __syncthreads();
  }
  for (int idx=t; idx<QRM*QRN; idx+=256)
    vout[(size_t)g*LSZ*V3 + idx] = 16.0f*A[idx];
}

__global__ __launch_bounds__(256) void final_kernel(const float* __restrict__ embf,
    const float* __restrict__ vf, const float* __restrict__ Rg, float* __restrict__ out){
  int n = blockIdx.x, t = threadIdx.x;
  out[(size_t)n*EMB + t] = embf[(size_t)n*EMB + t];
  if (t < V3){
    int m = t/3, ii = t - m*3;
    const float* Rp = Rg + (size_t)n*9;
    const float* vp = vf + (size_t)n*V3 + m*3;
    float val = Rp[ii*3+0]*vp[0] + Rp[ii*3+1]*vp[1] + Rp[ii*3+2]*vp[2];
    out[(size_t)NN*EMB + (size_t)n*V3 + t] = val;
  }
}

// ---------------- host ----------------
extern "C" void kernel_launch(void* const* d_in, const int* in_sizes, int n_in,
                              void* d_out, int out_size, void* d_ws, size_t ws_size,
                              hipStream_t stream){
  (void)in_sizes; (void)n_in; (void)out_size; (void)ws_size;
  const float* x       = (const float*)d_in[0];
  const float* bb      = (const float*)d_in[1];
  const float* in_ln_g = (const float*)d_in[2];
  const float* in_ln_b = (const float*)d_in[3];
  const float* in_W    = (const float*)d_in[4];
  const float* in_b    = (const float*)d_in[5];
  const float* msg_W1  = (const float*)d_in[6];
  const float* msg_b1  = (const float*)d_in[7];
  const float* msg_W2  = (const float*)d_in[8];
  const float* msg_b2  = (const float*)d_in[9];
  const float* msg_W3  = (const float*)d_in[10];
  const float* msg_b3  = (const float*)d_in[11];
  const float* vect_W  = (const float*)d_in[12];
  const float* ln_g    = (const float*)d_in[13];
  const float* ln_b    = (const float*)d_in[14];
  const int*   col     = (const int*)d_in[16];

  char* p = (char*)d_ws;
  auto alloc = [&](size_t bytes)->void*{ void* r = (void*)p; p += (bytes + 255) & ~(size_t)255; return r; };
  float*  Rg    = (float*) alloc((size_t)NN*9*4);
  float*  tg    = (float*) alloc((size_t)NN*3*4);
  float*  xln   = (float*) alloc((size_t)NN*IND*4);
  float*  eA    = (float*) alloc((size_t)NN*EMB*4);
  float*  eB    = (float*) alloc((size_t)NN*EMB*4);
  float*  vA    = (float*) alloc((size_t)NN*V3*4);
  float*  vB    = (float*) alloc((size_t)NN*V3*4);
  float*  vu    = (float*) alloc((size_t)NN*V3*4);
  float*  Redge = (float*) alloc((size_t)EE*9*4);
  float*  eattr = (float*) alloc((size_t)EE*EAP*4);
  unsigned short* W2Thi = (unsigned short*)alloc((size_t)3*65536*2);
  unsigned short* W2Tlo = (unsigned short*)alloc((size_t)3*65536*2);
  unsigned short* W1Thi = (unsigned short*)alloc((size_t)3*256*WK*2);
  unsigned short* W1Tlo = (unsigned short*)alloc((size_t)3*256*WK*2);

  const int NV = NN*V3;
  fill_kernel<<<(NV+255)/256, 256, 0, stream>>>(vA, NV, 0.0f);
  wsplit2_kernel<<<768, 256, 0, stream>>>(msg_W2, W2Thi, W2Tlo);
  wsplit1_kernel<<<(3*256*WK+255)/256, 256, 0, stream>>>(msg_W1, W1Thi, W1Tlo);
  rigid_kernel<<<(NN+63)/64, 64, 0, stream>>>(bb, Rg, tg);
  ln_kernel<<<NN, 256, 0, stream>>>(x, in_ln_g, in_ln_b, xln);
  emb0_kernel<<<NN/8, 256, 0, stream>>>(xln, in_W, in_b, eA);
  edge_kernel<<<(EE+63)/64, 64, 0, stream>>>(bb, Rg, tg, col, Redge, eattr);

  float* ein = eA; float* eout = eB; float* vin = vA; float* vout = vB;
  for (int l=0; l<3; ++l){
    fused_kernel<<<NN, 256, 0, stream>>>(ein, vin, Redge, eattr, col,
        msg_W1 + (size_t)l*710*EMB, msg_b1 + (size_t)l*EMB,
        W1Thi + (size_t)l*256*WK, W1Tlo + (size_t)l*256*WK,
        W2Thi + (size_t)l*65536, W2Tlo + (size_t)l*65536,
        msg_b2 + (size_t)l*EMB,
        msg_W3 + (size_t)l*EMB*EMB, msg_b3 + (size_t)l*EMB,
        vect_W + (size_t)l*(EMB+V3)*V3,
        ln_g + (size_t)l*EMB, ln_b + (size_t)l*EMB, eout, vu);
    qr_kernel<<<NG, 256, 0, stream>>>(vu, vout);
    float* tmp = ein; ein = eout; eout = tmp;
    tmp = vin; vin = vout; vout = tmp;
  }
  final_kernel<<<NN, 256, 0, stream>>>(ein, vin, Rg, (float*)d_out);
}

// Round 14
// 1773.853 us; speedup vs baseline: 1.3591x; 1.0147x over previous
//
#include <hip/hip_runtime.h>
#include <hip/hip_bf16.h>

#define NG   8
#define LSZ  256
#define NN   2048
#define KK   30
#define EE   61440
#define IND  1280
#define EMB  256
#define V3   15
#define EAP  156
#define QRM  768
#define QRN  5

#define F32_EPS    5.9604645e-08f
#define F32_EPS2   3.5527137e-15f
#define F32_SAFMIN 1.17549435e-38f

typedef __bf16 bf16x8 __attribute__((ext_vector_type(8)));
typedef float  f32x4  __attribute__((ext_vector_type(4)));
typedef short  s16x8  __attribute__((ext_vector_type(8)));

#define AK  456   // A stride (shorts), phase B
#define WK  448   // W1eff K extent
#define H1K 264   // h1 stride (shorts), phase C
#define XK  264   // ln_emb0 chunk stride (shorts)

__device__ __forceinline__ float bsumf(float v, float* rbuf){
  int t = threadIdx.x;
  __syncthreads();
  rbuf[t] = v;
  __syncthreads();
  for (int s=128; s>0; s>>=1){
    if (t < s) rbuf[t] += rbuf[t+s];
    __syncthreads();
  }
  float r = rbuf[0];
  __syncthreads();
  return r;
}
__device__ __forceinline__ float gelu_f(float x){
  return 0.5f*x*(1.0f + erff(x*0.70710678f));
}
__device__ __forceinline__ float s_sign(float a, float b){ return (b >= 0.0f) ? fabsf(a) : -fabsf(a); }
__device__ __forceinline__ float slapy2(float x, float y){
  float xa = fabsf(x), ya = fabsf(y);
  float w = fmaxf(xa, ya), z = fminf(xa, ya);
  if (z == 0.0f) return w;
  float t = z/w;
  return w*sqrtf(1.0f + t*t);
}
// RNE f32 -> bf16 bits
__device__ __forceinline__ unsigned short bf16_rne(float v){
  unsigned int u = __float_as_uint(v);
  u = u + 0x7FFFu + ((u>>16)&1u);
  return (unsigned short)(u>>16);
}
// LAPACK >=3.10 slartg (f32)
__device__ void slartg(float f, float g, float& c, float& s, float& r){
  const float safmin = F32_SAFMIN;
  const float safmax = 8.5070592e+37f;
  const float rtmin  = 1.0842022e-19f;
  const float rtmax  = 6.5243586e+18f;
  float f1 = fabsf(f), g1 = fabsf(g);
  if (g == 0.0f){ c = 1.0f; s = 0.0f; r = f; }
  else if (f == 0.0f){ c = 0.0f; s = (g >= 0.0f ? 1.0f : -1.0f); r = g1; }
  else {
    if (f1 > rtmin && f1 < rtmax && g1 > rtmin && g1 < rtmax){
      float d = sqrtf(f*f + g*g);
      c = f1/d;
      r = (f >= 0.0f ? d : -d);
      s = g/r;
    } else {
      float u = fminf(safmax, fmaxf(safmin, fmaxf(f1,g1)));
      float fs = f/u, gs = g/u;
      float d = sqrtf(fs*fs + gs*gs);
      c = fabsf(fs)/d;
      r = (f >= 0.0f ? d : -d);
      s = gs/r;
      r = r*u;
    }
  }
}
__device__ void slaev2(float a, float b, float c, float& rt1, float& rt2, float& cs1, float& sn1){
  float sm = a + c, df = a - c, adf = fabsf(df), tb = b + b, ab = fabsf(tb);
  float acmx, acmn;
  if (fabsf(a) > fabsf(c)) { acmx=a; acmn=c; } else { acmx=c; acmn=a; }
  float rt;
  if (adf > ab){ float t = ab/adf; rt = adf*sqrtf(1.0f+t*t); }
  else if (adf < ab){ float t = adf/ab; rt = ab*sqrtf(1.0f+t*t); }
  else rt = ab*sqrtf(2.0f);
  int sgn1;
  if (sm < 0.0f){ rt1 = 0.5f*(sm-rt); sgn1 = -1; rt2 = (acmx/rt1)*acmn - (b/rt1)*b; }
  else if (sm > 0.0f){ rt1 = 0.5f*(sm+rt); sgn1 = 1; rt2 = (acmx/rt1)*acmn - (b/rt1)*b; }
  else { rt1 = 0.5f*rt; rt2 = -0.5f*rt; sgn1 = 1; }
  float cs; int sgn2;
  if (df >= 0.0f){ cs = df + rt; sgn2 = 1; } else { cs = df - rt; sgn2 = -1; }
  float acs = fabsf(cs);
  if (acs > ab){
    float ct = -tb/cs; sn1 = 1.0f/sqrtf(1.0f+ct*ct); cs1 = ct*sn1;
  } else {
    if (ab == 0.0f){ cs1 = 1.0f; sn1 = 0.0f; }
    else { float tn = -cs/tb; cs1 = 1.0f/sqrtf(1.0f+tn*tn); sn1 = tn*cs1; }
  }
  if (sgn1 == sgn2){ float tn = cs1; cs1 = -sn1; sn1 = tn; }
}

// f32 ssytd2('L') + ssteqr('I') for 4x4; returns eigvec of largest eigenvalue.
__device__ void sym4_quat_f32(float (&a)[4][4], float* q){
  float d[4], e[3];
  float tau0 = 0.0f, tau1 = 0.0f;
  float v31 = 0.0f, v41 = 0.0f, v42 = 0.0f;
  {
    float alpha = a[1][0];
    float x1 = a[2][0], x2 = a[3][0];
    float xnorm = sqrtf(x1*x1 + x2*x2);
    if (xnorm == 0.0f){ tau0 = 0.0f; e[0] = alpha; }
    else {
      float beta = -s_sign(slapy2(alpha, xnorm), alpha);
      tau0 = (beta - alpha)/beta;
      float sc = 1.0f/(alpha - beta);
      x1 *= sc; x2 *= sc;
      e[0] = beta;
      float p0 = tau0*(a[1][1] + a[2][1]*x1 + a[3][1]*x2);
      float p1 = tau0*(a[2][1] + a[2][2]*x1 + a[3][2]*x2);
      float p2 = tau0*(a[3][1] + a[3][2]*x1 + a[3][3]*x2);
      float al = -0.5f*tau0*(p0 + p1*x1 + p2*x2);
      p0 += al; p1 += al*x1; p2 += al*x2;
      a[1][1] -= 2.0f*p0;
      a[2][1] -= x1*p0 + p1;
      a[3][1] -= x2*p0 + p2;
      a[2][2] -= 2.0f*x1*p1;
      a[3][2] -= x2*p1 + p2*x1;
      a[3][3] -= 2.0f*x2*p2;
    }
    v31 = x1; v41 = x2;
  }
  {
    float alpha = a[2][1];
    float x1 = a[3][1];
    float xnorm = fabsf(x1);
    if (xnorm == 0.0f){ tau1 = 0.0f; e[1] = alpha; }
    else {
      float beta = -s_sign(slapy2(alpha, xnorm), alpha);
      tau1 = (beta - alpha)/beta;
      x1 *= 1.0f/(alpha - beta);
      e[1] = beta;
      float p0 = tau1*(a[2][2] + a[3][2]*x1);
      float p1 = tau1*(a[3][2] + a[3][3]*x1);
      float al = -0.5f*tau1*(p0 + p1*x1);
      p0 += al; p1 += al*x1;
      a[2][2] -= 2.0f*p0;
      a[3][2] -= x1*p0 + p1;
      a[3][3] -= 2.0f*x1*p1;
    }
    v42 = x1;
  }
  e[2] = a[3][2];
  d[0]=a[0][0]; d[1]=a[1][1]; d[2]=a[2][2]; d[3]=a[3][3];
  float z[4][4] = {{1,0,0,0},{0,1,0,0},{0,0,1,0},{0,0,0,1}};
  const float eps = F32_EPS;
  const float eps2 = F32_EPS2;
  const float safmin = F32_SAFMIN;
  int jtot = 0;
  const int nmaxit = 120;
  int l1 = 0;
  bool fail = false;
  while (!fail){
    if (l1 > 3) break;
    if (l1 > 0) e[l1-1] = 0.0f;
    int lend = 3;
    for (int mm = l1; mm <= 2; ++mm){
      float tst = fabsf(e[mm]);
      if (tst == 0.0f){ lend = mm; break; }
      if (tst <= (sqrtf(fabsf(d[mm]))*sqrtf(fabsf(d[mm+1])))*eps){ e[mm] = 0.0f; lend = mm; break; }
    }
    int l = l1;
    int lsv = l, lendsv = lend;
    l1 = lend + 1;
    if (lend == l) continue;
    float anorm = fabsf(d[l]);
    for (int ii=l+1; ii<=lend; ++ii) anorm = fmaxf(anorm, fabsf(d[ii]));
    for (int ii=l; ii<lend; ++ii)    anorm = fmaxf(anorm, fabsf(e[ii]));
    if (anorm == 0.0f) continue;
    if (fabsf(d[lend]) < fabsf(d[l])){ lend = lsv; l = lendsv; }
    if (lend > l){
      for (;;){
        int m = lend;
        if (l != lend){
          for (int mm=l; mm<=lend-1; ++mm){
            float tst = e[mm]*e[mm];
            if (tst <= (eps2*fabsf(d[mm]))*fabsf(d[mm+1]) + safmin){ m = mm; break; }
          }
        }
        if (m < lend) e[m] = 0.0f;
        float p = d[l];
        if (m == l){
          d[l] = p; ++l;
          if (l <= lend) continue;
          break;
        }
        if (m == l+1){
          float rt1, rt2, c, s;
          slaev2(d[l], e[l], d[l+1], rt1, rt2, c, s);
          #pragma unroll
          for (int r2=0;r2<4;r2++){
            float t_ = z[r2][l+1];
            z[r2][l+1] = c*t_ - s*z[r2][l];
            z[r2][l]   = s*t_ + c*z[r2][l];
          }
          d[l]=rt1; d[l+1]=rt2; e[l]=0.0f;
          l += 2;
          if (l <= lend) continue;
          break;
        }
        if (jtot == nmaxit){ fail = true; break; }
        ++jtot;
        float g = (d[l+1]-p)/(2.0f*e[l]);
        float r_ = slapy2(g, 1.0f);
        g = d[m] - p + e[l]/(g + s_sign(r_, g));
        float s = 1.0f, c = 1.0f;
        p = 0.0f;
        float csv[3], snv[3];
        for (int i=m-1; i>=l; --i){
          float f = s*e[i], b = c*e[i];
          slartg(g, f, c, s, r_);
          if (i != m-1) e[i+1] = r_;
          g = d[i+1] - p;
          r_ = (d[i]-g)*s + 2.0f*c*b;
          p = s*r_;
          d[i+1] = g + p;
          g = c*r_ - b;
          csv[i] = c; snv[i] = -s;
        }
        for (int i=m-1; i>=l; --i){
          float cc = csv[i], ss = snv[i];
          #pragma unroll
          for (int r2=0;r2<4;r2++){
            float t_ = z[r2][i+1];
            z[r2][i+1] = cc*t_ - ss*z[r2][i];
            z[r2][i]   = ss*t_ + cc*z[r2][i];
          }
        }
        d[l] -= p; e[l] = g;
      }
    } else {
      for (;;){
        int m = lend;
        if (l != lend){
          for (int mm=l; mm>=lend+1; --mm){
            float tst = e[mm-1]*e[mm-1];
            if (tst <= (eps2*fabsf(d[mm]))*fabsf(d[mm-1]) + safmin){ m = mm; break; }
          }
        }
        if (m > lend) e[m-1] = 0.0f;
        float p = d[l];
        if (m == l){
          d[l] = p; --l;
          if (l >= lend) continue;
          break;
        }
        if (m == l-1){
          float rt1, rt2, c, s;
          slaev2(d[l-1], e[l-1], d[l], rt1, rt2, c, s);
          #pragma unroll
          for (int r2=0;r2<4;r2++){
            float t_ = z[r2][l];
            z[r2][l]   = c*t_ - s*z[r2][l-1];
            z[r2][l-1] = s*t_ + c*z[r2][l-1];
          }
          d[l-1]=rt1; d[l]=rt2; e[l-1]=0.0f;
          l -= 2;
          if (l >= lend) continue;
          break;
        }
        if (jtot == nmaxit){ fail = true; break; }
        ++jtot;
        float g = (d[l-1]-p)/(2.0f*e[l-1]);
        float r_ = slapy2(g, 1.0f);
        g = d[m] - p + e[l-1]/(g + s_sign(r_, g));
        float s = 1.0f, c = 1.0f;
        p = 0.0f;
        float csv[3], snv[3];
        for (int i=m; i<=l-1; ++i){
          float f = s*e[i], b = c*e[i];
          slartg(g, f, c, s, r_);
          if (i != m) e[i-1] = r_;
          g = d[i] - p;
          r_ = (d[i+1]-g)*s + 2.0f*c*b;
          p = s*r_;
          d[i] = g + p;
          g = c*r_ - b;
          csv[i] = c; snv[i] = s;
        }
        for (int i=m; i<=l-1; ++i){
          float cc = csv[i], ss = snv[i];
          #pragma unroll
          for (int r2=0;r2<4;r2++){
            float t_ = z[r2][i+1];
            z[r2][i+1] = cc*t_ - ss*z[r2][i];
            z[r2][i]   = ss*t_ + cc*z[r2][i];
          }
        }
        d[l] -= p; e[l-1] = g;
      }
    }
  }
  for (int ii=1; ii<4; ++ii){
    int i0 = ii-1, k0 = i0;
    float p = d[i0];
    for (int j2=ii; j2<4; ++j2) if (d[j2] < p){ k0 = j2; p = d[j2]; }
    if (k0 != i0){
      d[k0] = d[i0]; d[i0] = p;
      #pragma unroll
      for (int r2=0;r2<4;r2++){ float t_ = z[r2][i0]; z[r2][i0] = z[r2][k0]; z[r2][k0] = t_; }
    }
  }
  float w0 = z[0][3], w1 = z[1][3], w2 = z[2][3], w3 = z[3][3];
  if (tau1 != 0.0f){
    float dv = w2 + v42*w3;
    w2 -= tau1*dv;
    w3 -= tau1*dv*v42;
  }
  if (tau0 != 0.0f){
    float dv = w1 + v31*w2 + v41*w3;
    w1 -= tau0*dv;
    w2 -= tau0*dv*v31;
    w3 -= tau0*dv*v41;
  }
  q[0]=w0; q[1]=w1; q[2]=w2; q[3]=w3;
}

// ---------------- kernels ----------------
__global__ void fill_kernel(float* __restrict__ p, int nelem, float val){
  int i = blockIdx.x*blockDim.x + threadIdx.x;
  if (i < nelem) p[i] = val;
}

// Pre-split W2 (3 layers) into transposed bf16 hi/lo: out[l][j][k]
__global__ __launch_bounds__(256) void wsplit2_kernel(const float* __restrict__ W2,
    unsigned short* __restrict__ hi, unsigned short* __restrict__ lo){
  int idx = blockIdx.x*256 + threadIdx.x;
  int l = idx >> 16; int rem = idx & 65535; int k = rem >> 8; int j = rem & 255;
  float v = W2[(size_t)l*65536 + (size_t)k*256 + j];
  unsigned short hb = bf16_rne(v);
  float hf = __uint_as_float(((unsigned int)hb)<<16);
  unsigned short lb = bf16_rne(v - hf);
  size_t o = (size_t)l*65536 + (size_t)j*256 + k;
  hi[o] = hb; lo[o] = lb;
}

// Build W1eff^T (3 layers): [l][j][k], k<448
__global__ __launch_bounds__(256) void wsplit1_kernel(const float* __restrict__ W1,
    unsigned short* __restrict__ hi, unsigned short* __restrict__ lo){
  int idx = blockIdx.x*256 + threadIdx.x;
  if (idx >= 3*256*WK) return;
  int l = idx / (256*WK); int rem = idx - l*(256*WK);
  int j = rem / WK; int k = rem - j*WK;
  const float* Wl = W1 + (size_t)l*710*EMB;
  float v = 0.0f;
  if (k < 256) v = Wl[(size_t)(256+k)*EMB + j];
  else if (k < 416){ int kk = k-256; if (kk < 153) v = Wl[(size_t)(557+kk)*EMB + j]; }
  else if (k < 432){ int r = k-416; if (r < 15) v = Wl[(size_t)(527+r)*EMB + j] - Wl[(size_t)(542+r)*EMB + j]; }
  unsigned short hb = bf16_rne(v);
  float hf = __uint_as_float(((unsigned int)hb)<<16);
  unsigned short lb = bf16_rne(v - hf);
  size_t o = (size_t)l*(256*WK) + (size_t)j*WK + k;
  hi[o] = hb; lo[o] = lb;
}

// Split in_W (1280x256) transposed: out[j][k]
__global__ __launch_bounds__(256) void wsplit0_kernel(const float* __restrict__ W0,
    unsigned short* __restrict__ hi, unsigned short* __restrict__ lo){
  int idx = blockIdx.x*256 + threadIdx.x;
  if (idx >= IND*EMB) return;
  int k = idx >> 8; int j = idx & 255;
  float v = W0[(size_t)k*EMB + j];
  unsigned short hb = bf16_rne(v);
  float hf = __uint_as_float(((unsigned int)hb)<<16);
  unsigned short lb = bf16_rne(v - hf);
  size_t o = (size_t)j*IND + k;
  hi[o] = hb; lo[o] = lb;
}

__global__ void rigid_kernel(const float* __restrict__ bb, float* __restrict__ Rg, float* __restrict__ tg){
  int n = blockIdx.x*blockDim.x + threadIdx.x;
  if (n >= NN) return;
  const float* p = bb + (size_t)n*9;
  float nx=p[0],ny=p[1],nz=p[2], cax=p[3],cay=p[4],caz=p[5], cx=p[6],cy=p[7],cz=p[8];
  float e1x=cx-cax, e1y=cy-cay, e1z=cz-caz;
  float n1 = sqrtf(e1x*e1x+e1y*e1y+e1z*e1z);
  e1x/=n1; e1y/=n1; e1z/=n1;
  float ux=nx-cax, uy=ny-cay, uz=nz-caz;
  float du = ux*e1x+uy*e1y+uz*e1z;
  float e2x=ux-du*e1x, e2y=uy-du*e1y, e2z=uz-du*e1z;
  float n2 = sqrtf(e2x*e2x+e2y*e2y+e2z*e2z);
  e2x/=n2; e2y/=n2; e2z/=n2;
  float e3x=e1y*e2z-e1z*e2y, e3y=e1z*e2x-e1x*e2z, e3z=e1x*e2y-e1y*e2x;
  float* R = Rg + (size_t)n*9;
  R[0]=e1x; R[1]=e2x; R[2]=e3x;
  R[3]=e1y; R[4]=e2y; R[5]=e3y;
  R[6]=e1z; R[7]=e2z; R[8]=e3z;
  tg[(size_t)n*3+0]=cax; tg[(size_t)n*3+1]=cay; tg[(size_t)n*3+2]=caz;
}

// Fused LN + emb0 via MFMA. 16 nodes/block, wave-local LN stats (shfl).
__global__ __launch_bounds__(256) void ln_emb0_kernel(const float* __restrict__ x,
    const float* __restrict__ lg, const float* __restrict__ lb,
    const unsigned short* __restrict__ W0Thi, const unsigned short* __restrict__ W0Tlo,
    const float* __restrict__ bias, float* __restrict__ emb){
  int n0 = blockIdx.x*16, j = threadIdx.x;
  int l = j & 63, w = j >> 6;
  __shared__ __align__(16) unsigned short chi[16*XK];
  __shared__ __align__(16) unsigned short clo[16*XK];
  __shared__ float smu[16], srs[16];
  // LN stats: wave w handles rows w, 4+w, 8+w, 12+w (order = value-noise only)
  for (int rr=0; rr<4; rr++){
    int r = rr*4 + w;
    float vals[20];
    float s = 0.0f;
    #pragma unroll
    for (int u=0;u<20;u++){ vals[u] = x[(size_t)(n0+r)*IND + u*64 + l]; s += vals[u]; }
    #pragma unroll
    for (int o=32;o>0;o>>=1) s += __shfl_xor(s, o);
    float mu = s*(1.0f/IND);
    float pv = 0.0f;
    #pragma unroll
    for (int u=0;u<20;u++){ float dd = vals[u]-mu; pv += dd*dd; }
    #pragma unroll
    for (int o=32;o>0;o>>=1) pv += __shfl_xor(pv, o);
    float rs = 1.0f/sqrtf(pv*(1.0f/IND) + 1e-5f);
    if (l == 0){ smu[r] = mu; srs[r] = rs; }
  }
  __syncthreads();
  f32x4 acc[4];
  #pragma unroll
  for (int nt=0;nt<4;nt++)
    #pragma unroll
    for (int rg=0;rg<4;rg++) acc[nt][rg] = 0.0f;
  for (int ch=0; ch<5; ch++){
    for (int idx=j; idx<16*256; idx+=256){
      int r = idx>>8, k = idx&255;
      int kk = ch*256 + k;
      float v = lg[kk]*((x[(size_t)(n0+r)*IND + kk]-smu[r])*srs[r]) + lb[kk];
      unsigned short hb = bf16_rne(v);
      float hf = __uint_as_float(((unsigned int)hb)<<16);
      chi[r*XK+k] = hb;
      clo[r*XK+k] = bf16_rne(v - hf);
    }
    __syncthreads();
    for (int kt=0;kt<8;kt++){
      int k0 = kt*32 + (l>>4)*8;
      int row = l&15;
      bf16x8 aH = __builtin_bit_cast(bf16x8, *(const s16x8*)&chi[row*XK + k0]);
      bf16x8 aL = __builtin_bit_cast(bf16x8, *(const s16x8*)&clo[row*XK + k0]);
      #pragma unroll
      for (int nt=0;nt<4;nt++){
        int colj = w*64 + nt*16 + (l&15);
        size_t wb = (size_t)colj*IND + ch*256 + k0;
        bf16x8 Bh = __builtin_bit_cast(bf16x8, *(const s16x8*)&W0Thi[wb]);
        bf16x8 Bl = __builtin_bit_cast(bf16x8, *(const s16x8*)&W0Tlo[wb]);
        acc[nt] = __builtin_amdgcn_mfma_f32_16x16x32_bf16(aH, Bh, acc[nt], 0,0,0);
        acc[nt] = __builtin_amdgcn_mfma_f32_16x16x32_bf16(aH, Bl, acc[nt], 0,0,0);
        acc[nt] = __builtin_amdgcn_mfma_f32_16x16x32_bf16(aL, Bh, acc[nt], 0,0,0);
      }
    }
    __syncthreads();
  }
  #pragma unroll
  for (int nt=0;nt<4;nt++){
    int colj = w*64 + nt*16 + (l&15);
    float bv = bias[colj];
    #pragma unroll
    for (int rg=0;rg<4;rg++){
      int row = (l>>4)*4 + rg;
      emb[(size_t)(n0+row)*EMB + colj] = acc[nt][rg] + bv;
    }
  }
}

__global__ __launch_bounds__(64) void edge_kernel(const float* __restrict__ bb,
    const float* __restrict__ Rg, const float* __restrict__ tg,
    const int* __restrict__ col, float* __restrict__ Redge, float* __restrict__ eattr){
  int e = blockIdx.x*64 + threadIdx.x;
  if (e >= EE) return;
  int i = e/KK;
  int jn = col[e];
  float Ri[9], Rj[9];
  #pragma unroll
  for (int a=0;a<9;a++){ Ri[a]=Rg[(size_t)i*9+a]; Rj[a]=Rg[(size_t)jn*9+a]; }
  float dt0 = tg[(size_t)jn*3+0]-tg[(size_t)i*3+0];
  float dt1 = tg[(size_t)jn*3+1]-tg[(size_t)i*3+1];
  float dt2 = tg[(size_t)jn*3+2]-tg[(size_t)i*3+2];
  float Re[9];
  #pragma unroll
  for (int a=0;a<3;a++){
    #pragma unroll
    for (int c=0;c<3;c++)
      Re[a*3+c] = Ri[0+a]*Rj[0+c] + Ri[3+a]*Rj[3+c] + Ri[6+a]*Rj[6+c];
  }
  float te0 = Ri[0]*dt0 + Ri[3]*dt1 + Ri[6]*dt2;
  float te1 = Ri[1]*dt0 + Ri[4]*dt1 + Ri[7]*dt2;
  float te2 = Ri[2]*dt0 + Ri[5]*dt1 + Ri[8]*dt2;
  float xx=Re[0], xy=Re[1], xz=Re[2], yx=Re[3], yy=Re[4], yz=Re[5], zx=Re[6], zy=Re[7], zz=Re[8];
  float km[4][4];
  km[0][0]=(xx+yy+zz)/3.0f; km[0][1]=(zy-yz)/3.0f;    km[0][2]=(xz-zx)/3.0f;    km[0][3]=(yx-xy)/3.0f;
  km[1][0]=km[0][1];        km[1][1]=(xx-yy-zz)/3.0f; km[1][2]=(xy+yx)/3.0f;    km[1][3]=(xz+zx)/3.0f;
  km[2][0]=km[0][2];        km[2][1]=km[1][2];        km[2][2]=(yy-xx-zz)/3.0f; km[2][3]=(yz+zy)/3.0f;
  km[3][0]=km[0][3];        km[3][1]=km[1][3];        km[3][2]=km[2][3];        km[3][3]=(zz-xx-yy)/3.0f;
  float q[4];
  sym4_quat_f32(km, q);
  float* ea = eattr + (size_t)e*EAP;
  ea[0]=q[0]; ea[1]=q[1]; ea[2]=q[2]; ea[3]=q[3];
  ea[4]=te0;  ea[5]=te1;  ea[6]=te2;
  int cd = i - jn; if (cd < 0) cd = -cd;
  ea[7] = logf((float)cd + 1.0f);
  ea[8] = logf(sqrtf(te0*te0+te1*te1+te2*te2) + 1e-8f);
  const float* bi = bb + (size_t)i*9;
  const float* bj = bb + (size_t)jn*9;
  int idx = 9;
  #pragma unroll
  for (int a=0;a<3;a++){
    float ax=bi[a*3+0], ay=bi[a*3+1], az=bi[a*3+2];
    #pragma unroll
    for (int b2=0;b2<3;b2++){
      float dx=ax-bj[b2*3+0], dy=ay-bj[b2*3+1], dz=az-bj[b2*3+2];
      float dd = sqrtf(fmaxf(dx*dx+dy*dy+dz*dz, 1e-12f));
      #pragma unroll
      for (int kb=0;kb<16;kb++){
        float muv = 1.3333334f*(float)kb;
        float df = dd - muv;
        ea[idx] = expf(-0.5f*df*df);
        idx++;
      }
    }
  }
  ea[153]=0.0f; ea[154]=0.0f; ea[155]=0.0f;
  #pragma unroll
  for (int a=0;a<9;a++) Redge[(size_t)e*9+a] = Re[a];
}

// Fused: phase B AND phase C via MFMA bf16x2-split; emb gather reg-cached across passes.
__global__ __launch_bounds__(256, 4) void fused_kernel(
    const float* __restrict__ emb_in, const float* __restrict__ v_in,
    const float* __restrict__ Redge, const float* __restrict__ eattr,
    const int* __restrict__ col,
    const float* __restrict__ W1, const float* __restrict__ b1,
    const unsigned short* __restrict__ W1Thi, const unsigned short* __restrict__ W1Tlo,
    const unsigned short* __restrict__ W2Thi, const unsigned short* __restrict__ W2Tlo,
    const float* __restrict__ b2,
    const float* __restrict__ W3, const float* __restrict__ b3,
    const float* __restrict__ vW,
    const float* __restrict__ lng, const float* __restrict__ lnb,
    float* __restrict__ emb_out, float* __restrict__ vu_out){
  int n = blockIdx.x, j = threadIdx.x;
  size_t e0 = (size_t)n*KK;
  __shared__ __align__(16) char smem[36864];
  __shared__ float s_xi[EMB];
  __shared__ float s_vi[16];
  unsigned short* Abuf = (unsigned short*)smem;    // [32][AK]
  unsigned short* h1hi = (unsigned short*)smem;    // [32][H1K]
  unsigned short* h1lo = h1hi + 32*H1K;
  float* cshb = (float*)(smem + 33792);
  float* sbuf = (float*)(smem + 34816);
  float* rbuf = (float*)(smem + 35840);

  s_xi[j] = emb_in[(size_t)n*EMB + j];
  if (j < 16) s_vi[j] = (j < V3) ? v_in[(size_t)n*V3 + j] : 0.0f;

  float femb[KK];   // reg-cache of gathered emb values
  // ---- stage A pass 0 (hi) ----
  #pragma unroll 1
  for (int e=0;e<KK;e++){
    int cj = col[e0+e];
    float v = emb_in[(size_t)cj*EMB + j];
    femb[e] = v;
    Abuf[e*AK + j] = bf16_rne(v);
  }
  for (int idx=j; idx<KK*160; idx+=256){
    int e = idx/160, kk = idx - e*160;
    float v = (kk < 156) ? eattr[(e0+e)*EAP + kk] : 0.0f;
    Abuf[e*AK + 256 + kk] = bf16_rne(v);
  }
  for (int idx=j; idx<KK*32; idx+=256){
    int e = idx>>5, r = idx&31;
    float v = 0.0f;
    if (r < V3){
      int m = r/3, ii = r - m*3;
      int cj = col[e0+e];
      const float* Rp = Redge + (e0+e)*9;
      const float* vp = v_in + (size_t)cj*V3 + m*3;
      v = Rp[ii*3+0]*vp[0] + Rp[ii*3+1]*vp[1] + Rp[ii*3+2]*vp[2];
    }
    Abuf[e*AK + 416 + r] = bf16_rne(v);
  }
  for (int idx=j; idx<2*WK; idx+=256){
    int rr = 30 + idx/WK, c = idx%WK;
    Abuf[rr*AK + c] = 0;
  }
  __syncthreads();

  // csh (exact f32)
  {
    float csh = b1[j];
    for (int k=0;k<EMB;k+=4){
      float w0=W1[(size_t)(k+0)*EMB+j], w1=W1[(size_t)(k+1)*EMB+j], w2=W1[(size_t)(k+2)*EMB+j], w3=W1[(size_t)(k+3)*EMB+j];
      csh += s_xi[k+0]*w0 + s_xi[k+1]*w1 + s_xi[k+2]*w2 + s_xi[k+3]*w3;
    }
    #pragma unroll
    for (int r=0;r<V3;r++) csh += s_vi[r]*(W1[(size_t)(512+r)*EMB+j] + W1[(size_t)(542+r)*EMB+j]);
    cshb[j] = csh;
  }

  int l = j & 63, w = j >> 6;
  f32x4 cacc[2][4];
  #pragma unroll
  for (int mt=0;mt<2;mt++)
    #pragma unroll
    for (int nt=0;nt<4;nt++)
      #pragma unroll
      for (int rg=0;rg<4;rg++) cacc[mt][nt][rg] = 0.0f;

  // pass 1: aH x (Bh, Bl)
  for (int kt=0;kt<14;kt++){
    int k0 = kt*32 + (l>>4)*8;
    bf16x8 aH[2];
    #pragma unroll
    for (int mt=0;mt<2;mt++){
      int row = mt*16 + (l&15);
      aH[mt] = __builtin_bit_cast(bf16x8, *(const s16x8*)&Abuf[row*AK + k0]);
    }
    #pragma unroll
    for (int nt=0;nt<4;nt++){
      int colj = w*64 + nt*16 + (l&15);
      bf16x8 Bh = __builtin_bit_cast(bf16x8, *(const s16x8*)&W1Thi[(size_t)colj*WK + k0]);
      bf16x8 Bl = __builtin_bit_cast(bf16x8, *(const s16x8*)&W1Tlo[(size_t)colj*WK + k0]);
      #pragma unroll
      for (int mt=0;mt<2;mt++){
        cacc[mt][nt] = __builtin_amdgcn_mfma_f32_16x16x32_bf16(aH[mt], Bh, cacc[mt][nt], 0,0,0);
        cacc[mt][nt] = __builtin_amdgcn_mfma_f32_16x16x32_bf16(aH[mt], Bl, cacc[mt][nt], 0,0,0);
      }
    }
  }
  __syncthreads();
  // ---- stage A pass 1 (lo) — emb from regs; eattr re-read; vjr recomputed ----
  #pragma unroll 1
  for (int e=0;e<KK;e++){
    float v = femb[e];
    unsigned short hb = bf16_rne(v);
    float hf = __uint_as_float(((unsigned int)hb)<<16);
    Abuf[e*AK + j] = bf16_rne(v - hf);
  }
  for (int idx=j; idx<KK*160; idx+=256){
    int e = idx/160, kk = idx - e*160;
    float v = (kk < 156) ? eattr[(e0+e)*EAP + kk] : 0.0f;
    unsigned short hb = bf16_rne(v);
    float hf = __uint_as_float(((unsigned int)hb)<<16);
    Abuf[e*AK + 256 + kk] = bf16_rne(v - hf);
  }
  for (int idx=j; idx<KK*32; idx+=256){
    int e = idx>>5, r = idx&31;
    float v = 0.0f;
    if (r < V3){
      int m = r/3, ii = r - m*3;
      int cj = col[e0+e];
      const float* Rp = Redge + (e0+e)*9;
      const float* vp = v_in + (size_t)cj*V3 + m*3;
      v = Rp[ii*3+0]*vp[0] + Rp[ii*3+1]*vp[1] + Rp[ii*3+2]*vp[2];
    }
    unsigned short hb = bf16_rne(v);
    float hf = __uint_as_float(((unsigned int)hb)<<16);
    Abuf[e*AK + 416 + r] = bf16_rne(v - hf);
  }
  for (int idx=j; idx<2*WK; idx+=256){
    int rr = 30 + idx/WK, c = idx%WK;
    Abuf[rr*AK + c] = 0;
  }
  __syncthreads();
  // pass 2: aL x Bh
  for (int kt=0;kt<14;kt++){
    int k0 = kt*32 + (l>>4)*8;
    bf16x8 aL[2];
    #pragma unroll
    for (int mt=0;mt<2;mt++){
      int row = mt*16 + (l&15);
      aL[mt] = __builtin_bit_cast(bf16x8, *(const s16x8*)&Abuf[row*AK + k0]);
    }
    #pragma unroll
    for (int nt=0;nt<4;nt++){
      int colj = w*64 + nt*16 + (l&15);
      bf16x8 Bh = __builtin_bit_cast(bf16x8, *(const s16x8*)&W1Thi[(size_t)colj*WK + k0]);
      #pragma unroll
      for (int mt=0;mt<2;mt++)
        cacc[mt][nt] = __builtin_amdgcn_mfma_f32_16x16x32_bf16(aL[mt], Bh, cacc[mt][nt], 0,0,0);
    }
  }
  __syncthreads();
  // epilogue phase B: h1 = gelu(acc + csh[col]); split -> h1hi/h1lo
  #pragma unroll
  for (int mt=0;mt<2;mt++){
    #pragma unroll
    for (int nt=0;nt<4;nt++){
      int colj = w*64 + nt*16 + (l&15);
      float cshv = cshb[colj];
      #pragma unroll
      for (int rg=0;rg<4;rg++){
        int row = mt*16 + ((l>>4)&3)*4 + rg;
        float val = 0.0f;
        if (row < KK) val = gelu_f(cacc[mt][nt][rg] + cshv);
        unsigned short hb = bf16_rne(val);
        float hf = __uint_as_float(((unsigned int)hb)<<16);
        unsigned short lb = bf16_rne(val - hf);
        h1hi[row*H1K + colj] = hb;
        h1lo[row*H1K + colj] = lb;
      }
    }
  }
  __syncthreads();

  // ---- phase C: h2 via MFMA ----
  f32x4 dacc[2][4];
  #pragma unroll
  for (int mt=0;mt<2;mt++)
    #pragma unroll
    for (int nt=0;nt<4;nt++)
      #pragma unroll
      for (int rg=0;rg<4;rg++) dacc[mt][nt][rg] = 0.0f;
  for (int kt=0;kt<8;kt++){
    int k0 = kt*32 + (l>>4)*8;
    bf16x8 aH[2], aL[2];
    #pragma unroll
    for (int mt=0;mt<2;mt++){
      int row = mt*16 + (l&15);
      aH[mt] = __builtin_bit_cast(bf16x8, *(const s16x8*)&h1hi[row*H1K + k0]);
      aL[mt] = __builtin_bit_cast(bf16x8, *(const s16x8*)&h1lo[row*H1K + k0]);
    }
    #pragma unroll
    for (int nt=0;nt<4;nt++){
      int colj = w*64 + nt*16 + (l&15);
      bf16x8 Bh = __builtin_bit_cast(bf16x8, *(const s16x8*)&W2Thi[(size_t)colj*256 + k0]);
      bf16x8 Bl = __builtin_bit_cast(bf16x8, *(const s16x8*)&W2Tlo[(size_t)colj*256 + k0]);
      #pragma unroll
      for (int mt=0;mt<2;mt++){
        dacc[mt][nt] = __builtin_amdgcn_mfma_f32_16x16x32_bf16(aH[mt], Bh, dacc[mt][nt], 0,0,0);
        dacc[mt][nt] = __builtin_amdgcn_mfma_f32_16x16x32_bf16(aH[mt], Bl, dacc[mt][nt], 0,0,0);
        dacc[mt][nt] = __builtin_amdgcn_mfma_f32_16x16x32_bf16(aL[mt], Bh, dacc[mt][nt], 0,0,0);
      }
    }
  }
  {
    float p[4];
    #pragma unroll
    for (int nt=0;nt<4;nt++){
      float b2v = b2[w*64 + nt*16 + (l&15)];
      float pp = 0.0f;
      #pragma unroll
      for (int mt=0;mt<2;mt++){
        #pragma unroll
        for (int rg=0;rg<4;rg++){
          int row = mt*16 + ((l>>4)&3)*4 + rg;
          if (row < KK) pp += gelu_f(dacc[mt][nt][rg] + b2v);
        }
      }
      pp += __shfl_xor(pp, 16);
      pp += __shfl_xor(pp, 32);
      p[nt] = pp;
    }
    if (l < 16){
      #pragma unroll
      for (int nt=0;nt<4;nt++) sbuf[w*64 + nt*16 + l] = p[nt];
    }
  }
  __syncthreads();
  // ---- epilogue: W3 dot, LN, vu ----
  float ag = 0.0f;
  for (int k=0;k<EMB;k+=4){
    float4 s4 = *(const float4*)&sbuf[k];
    ag += s4.x*W3[(size_t)(k+0)*EMB+j] + s4.y*W3[(size_t)(k+1)*EMB+j]
        + s4.z*W3[(size_t)(k+2)*EMB+j] + s4.w*W3[(size_t)(k+3)*EMB+j];
  }
  ag = ag*(1.0f/30.0f) + b3[j];
  float u = s_xi[j] + ag;
  float mu = bsumf(u, rbuf)*(1.0f/EMB);
  float dl = u - mu;
  float var = bsumf(dl*dl, rbuf)*(1.0f/EMB);
  float rs = 1.0f/sqrtf(var + 1e-5f);
  float y = lng[j]*dl*rs + lnb[j];
  emb_out[(size_t)n*EMB+j] = y;
  __syncthreads();
  sbuf[j] = y;
  __syncthreads();
  if (j < V3){
    float a = s_vi[j];
    for (int k=0;k<EMB;k++){
      a += sbuf[k]*vW[k*V3+j];
    }
    #pragma unroll
    for (int r=0;r<V3;r++) a += s_vi[r]*vW[(EMB+r)*V3+j];
    vu_out[(size_t)n*V3+j] = a;
  }
}

// Pure QR per graph (f32 sgeqr2/sorg2r, raw LAPACK signs) — untouched.
__global__ __launch_bounds__(256) void qr_kernel(
    const float* __restrict__ vu_in, float* __restrict__ vout){
  int g = blockIdx.x, t = threadIdx.x;
  __shared__ float A[QRM*QRN];
  __shared__ float meanv[V3];
  __shared__ float taus[QRN];
  __shared__ float sh[2];
  int n = g*LSZ + t;
  #pragma unroll
  for (int j=0;j<V3;j++) A[t*V3+j] = vu_in[(size_t)n*V3 + j];
  __syncthreads();
  if (t < V3){
    float s = 0.0f;
    for (int l0=0;l0<LSZ;l0++) s += A[l0*V3+t];
    meanv[t] = s/(float)LSZ;
  }
  __syncthreads();
  #pragma unroll
  for (int j=0;j<V3;j++) A[t*V3+j] -= meanv[j];
  __syncthreads();
  // ---- sgeqr2 ----
  for (int i=0;i<QRN;i++){
    if (t == 0){
      float s0=0,s1=0,s2=0,s3=0;
      int r=i+1;
      for (; r+3<QRM; r+=4){
        float x0=A[r*QRN+i], x1=A[(r+1)*QRN+i], x2=A[(r+2)*QRN+i], x3=A[(r+3)*QRN+i];
        s0+=x0*x0; s1+=x1*x1; s2+=x2*x2; s3+=x3*x3;
      }
      for (; r<QRM; r++){ float x=A[r*QRN+i]; s0+=x*x; }
      float xn2 = (s0+s1)+(s2+s3);
      float alpha = A[i*QRN+i];
      float taui = 0.0f, sc = 1.0f;
      if (xn2 != 0.0f){
        float beta = -s_sign(slapy2(alpha, sqrtf(xn2)), alpha);
        taui = (beta - alpha)/beta;
        sc = 1.0f/(alpha - beta);
      }
      taus[i] = taui; sh[0] = sc;
    }
    __syncthreads();
    {
      float sc = sh[0];
      for (int r=i+1+t; r<QRM; r+=256) A[r*QRN+i] *= sc;
    }
    __syncthreads();
    for (int j=i+1;j<QRN;j++){
      if (t == 0){
        float s0=A[i*QRN+j], s1=0,s2=0,s3=0;
        int r=i+1;
        for (; r+3<QRM; r+=4){
          s0 += A[r*QRN+i]*A[r*QRN+j];
          s1 += A[(r+1)*QRN+i]*A[(r+1)*QRN+j];
          s2 += A[(r+2)*QRN+i]*A[(r+2)*QRN+j];
          s3 += A[(r+3)*QRN+i]*A[(r+3)*QRN+j];
        }
        for (; r<QRM; r++) s0 += A[r*QRN+i]*A[r*QRN+j];
        sh[0] = taus[i]*((s0+s1)+(s2+s3));
      }
      __syncthreads();
      {
        float w = sh[0];
        for (int r=i+t; r<QRM; r+=256){
          float vr = (r==i) ? 1.0f : A[r*QRN+i];
          A[r*QRN+j] -= w*vr;
        }
      }
      __syncthreads();
    }
  }
  // ---- sorg2r ----
  for (int i=QRN-1;i>=0;i--){
    for (int j=i+1;j<QRN;j++){
      if (t == 0){
        float s0=A[i*QRN+j], s1=0,s2=0,s3=0;
        int r=i+1;
        for (; r+3<QRM; r+=4){
          s0 += A[r*QRN+i]*A[r*QRN+j];
          s1 += A[(r+1)*QRN+i]*A[(r+1)*QRN+j];
          s2 += A[(r+2)*QRN+i]*A[(r+2)*QRN+j];
          s3 += A[(r+3)*QRN+i]*A[(r+3)*QRN+j];
        }
        for (; r<QRM; r++) s0 += A[r*QRN+i]*A[r*QRN+j];
        sh[0] = taus[i]*((s0+s1)+(s2+s3));
      }
      __syncthreads();
      {
        float w = sh[0];
        for (int r=i+t; r<QRM; r+=256){
          float vr = (r==i) ? 1.0f : A[r*QRN+i];
          A[r*QRN+j] -= w*vr;
        }
      }
      __syncthreads();
    }
    {
      float taui = taus[i];
      for (int r=i+1+t; r<QRM; r+=256) A[r*QRN+i] *= -taui;
    }
    __syncthreads();
    if (t == 0) A[i*QRN+i] = 1.0f - taus[i];
    if (t < i) A[t*QRN+i] = 0.0f;
    __syncthreads();
  }
  for (int idx=t; idx<QRM*QRN; idx+=256)
    vout[(size_t)g*LSZ*V3 + idx] = 16.0f*A[idx];
}

__global__ __launch_bounds__(256) void final_kernel(const float* __restrict__ embf,
    const float* __restrict__ vf, const float* __restrict__ Rg, float* __restrict__ out){
  int n = blockIdx.x, t = threadIdx.x;
  out[(size_t)n*EMB + t] = embf[(size_t)n*EMB + t];
  if (t < V3){
    int m = t/3, ii = t - m*3;
    const float* Rp = Rg + (size_t)n*9;
    const float* vp = vf + (size_t)n*V3 + m*3;
    float val = Rp[ii*3+0]*vp[0] + Rp[ii*3+1]*vp[1] + Rp[ii*3+2]*vp[2];
    out[(size_t)NN*EMB + (size_t)n*V3 + t] = val;
  }
}

// ---------------- host ----------------
extern "C" void kernel_launch(void* const* d_in, const int* in_sizes, int n_in,
                              void* d_out, int out_size, void* d_ws, size_t ws_size,
                              hipStream_t stream){
  (void)in_sizes; (void)n_in; (void)out_size; (void)ws_size;
  const float* x       = (const float*)d_in[0];
  const float* bb      = (const float*)d_in[1];
  const float* in_ln_g = (const float*)d_in[2];
  const float* in_ln_b = (const float*)d_in[3];
  const float* in_W    = (const float*)d_in[4];
  const float* in_b    = (const float*)d_in[5];
  const float* msg_W1  = (const float*)d_in[6];
  const float* msg_b1  = (const float*)d_in[7];
  const float* msg_W2  = (const float*)d_in[8];
  const float* msg_b2  = (const float*)d_in[9];
  const float* msg_W3  = (const float*)d_in[10];
  const float* msg_b3  = (const float*)d_in[11];
  const float* vect_W  = (const float*)d_in[12];
  const float* ln_g    = (const float*)d_in[13];
  const float* ln_b    = (const float*)d_in[14];
  const int*   col     = (const int*)d_in[16];

  char* p = (char*)d_ws;
  auto alloc = [&](size_t bytes)->void*{ void* r = (void*)p; p += (bytes + 255) & ~(size_t)255; return r; };
  float*  Rg    = (float*) alloc((size_t)NN*9*4);
  float*  tg    = (float*) alloc((size_t)NN*3*4);
  float*  eA    = (float*) alloc((size_t)NN*EMB*4);
  float*  eB    = (float*) alloc((size_t)NN*EMB*4);
  float*  vA    = (float*) alloc((size_t)NN*V3*4);
  float*  vB    = (float*) alloc((size_t)NN*V3*4);
  float*  vu    = (float*) alloc((size_t)NN*V3*4);
  float*  Redge = (float*) alloc((size_t)EE*9*4);
  float*  eattr = (float*) alloc((size_t)EE*EAP*4);
  unsigned short* W2Thi = (unsigned short*)alloc((size_t)3*65536*2);
  unsigned short* W2Tlo = (unsigned short*)alloc((size_t)3*65536*2);
  unsigned short* W1Thi = (unsigned short*)alloc((size_t)3*256*WK*2);
  unsigned short* W1Tlo = (unsigned short*)alloc((size_t)3*256*WK*2);
  unsigned short* W0Thi = (unsigned short*)alloc((size_t)IND*EMB*2);
  unsigned short* W0Tlo = (unsigned short*)alloc((size_t)IND*EMB*2);

  const int NV = NN*V3;
  fill_kernel<<<(NV+255)/256, 256, 0, stream>>>(vA, NV, 0.0f);
  wsplit2_kernel<<<768, 256, 0, stream>>>(msg_W2, W2Thi, W2Tlo);
  wsplit1_kernel<<<(3*256*WK+255)/256, 256, 0, stream>>>(msg_W1, W1Thi, W1Tlo);
  wsplit0_kernel<<<(IND*EMB+255)/256, 256, 0, stream>>>(in_W, W0Thi, W0Tlo);
  rigid_kernel<<<(NN+63)/64, 64, 0, stream>>>(bb, Rg, tg);
  ln_emb0_kernel<<<NN/16, 256, 0, stream>>>(x, in_ln_g, in_ln_b, W0Thi, W0Tlo, in_b, eA);
  edge_kernel<<<(EE+63)/64, 64, 0, stream>>>(bb, Rg, tg, col, Redge, eattr);

  float* ein = eA; float* eout = eB; float* vin = vA; float* vout = vB;
  for (int l=0; l<3; ++l){
    fused_kernel<<<NN, 256, 0, stream>>>(ein, vin, Redge, eattr, col,
        msg_W1 + (size_t)l*710*EMB, msg_b1 + (size_t)l*EMB,
        W1Thi + (size_t)l*256*WK, W1Tlo + (size_t)l*256*WK,
        W2Thi + (size_t)l*65536, W2Tlo + (size_t)l*65536,
        msg_b2 + (size_t)l*EMB,
        msg_W3 + (size_t)l*EMB*EMB, msg_b3 + (size_t)l*EMB,
        vect_W + (size_t)l*(EMB+V3)*V3,
        ln_g + (size_t)l*EMB, ln_b + (size_t)l*EMB, eout, vu);
    qr_kernel<<<NG, 256, 0, stream>>>(vu, vout);
    float* tmp = ein; ein = eout; eout = tmp;
    tmp = vin; vin = vout; vout = tmp;
  }
  final_kernel<<<NN, 256, 0, stream>>>(ein, vin, Rg, (float*)d_out);
}

// Round 15
// 1166.182 us; speedup vs baseline: 2.0674x; 1.5211x over previous
//
#include <hip/hip_runtime.h>
#include <hip/hip_bf16.h>

#define NG   8
#define LSZ  256
#define NN   2048
#define KK   30
#define EE   61440
#define IND  1280
#define EMB  256
#define V3   15
#define EAP  156
#define QRM  768
#define QRN  5

#define F32_EPS    5.9604645e-08f
#define F32_EPS2   3.5527137e-15f
#define F32_SAFMIN 1.17549435e-38f

typedef __bf16 bf16x8 __attribute__((ext_vector_type(8)));
typedef float  f32x4  __attribute__((ext_vector_type(4)));
typedef short  s16x8  __attribute__((ext_vector_type(8)));

#define AK  456   // A stride (shorts), phase B
#define WK  448   // W1eff K extent
#define H1K 264   // h1 stride (shorts), phase C
#define XK  264   // ln_emb0 chunk stride (shorts)

__device__ __forceinline__ float bsumf(float v, float* rbuf){
  int t = threadIdx.x;
  __syncthreads();
  rbuf[t] = v;
  __syncthreads();
  for (int s=128; s>0; s>>=1){
    if (t < s) rbuf[t] += rbuf[t+s];
    __syncthreads();
  }
  float r = rbuf[0];
  __syncthreads();
  return r;
}
__device__ __forceinline__ float gelu_f(float x){
  return 0.5f*x*(1.0f + erff(x*0.70710678f));
}
__device__ __forceinline__ float s_sign(float a, float b){ return (b >= 0.0f) ? fabsf(a) : -fabsf(a); }
__device__ __forceinline__ float slapy2(float x, float y){
  float xa = fabsf(x), ya = fabsf(y);
  float w = fmaxf(xa, ya), z = fminf(xa, ya);
  if (z == 0.0f) return w;
  float t = z/w;
  return w*sqrtf(1.0f + t*t);
}
// RNE f32 -> bf16 bits
__device__ __forceinline__ unsigned short bf16_rne(float v){
  unsigned int u = __float_as_uint(v);
  u = u + 0x7FFFu + ((u>>16)&1u);
  return (unsigned short)(u>>16);
}
// LAPACK >=3.10 slartg (f32)
__device__ void slartg(float f, float g, float& c, float& s, float& r){
  const float safmin = F32_SAFMIN;
  const float safmax = 8.5070592e+37f;
  const float rtmin  = 1.0842022e-19f;
  const float rtmax  = 6.5243586e+18f;
  float f1 = fabsf(f), g1 = fabsf(g);
  if (g == 0.0f){ c = 1.0f; s = 0.0f; r = f; }
  else if (f == 0.0f){ c = 0.0f; s = (g >= 0.0f ? 1.0f : -1.0f); r = g1; }
  else {
    if (f1 > rtmin && f1 < rtmax && g1 > rtmin && g1 < rtmax){
      float d = sqrtf(f*f + g*g);
      c = f1/d;
      r = (f >= 0.0f ? d : -d);
      s = g/r;
    } else {
      float u = fminf(safmax, fmaxf(safmin, fmaxf(f1,g1)));
      float fs = f/u, gs = g/u;
      float d = sqrtf(fs*fs + gs*gs);
      c = fabsf(fs)/d;
      r = (f >= 0.0f ? d : -d);
      s = gs/r;
      r = r*u;
    }
  }
}
__device__ void slaev2(float a, float b, float c, float& rt1, float& rt2, float& cs1, float& sn1){
  float sm = a + c, df = a - c, adf = fabsf(df), tb = b + b, ab = fabsf(tb);
  float acmx, acmn;
  if (fabsf(a) > fabsf(c)) { acmx=a; acmn=c; } else { acmx=c; acmn=a; }
  float rt;
  if (adf > ab){ float t = ab/adf; rt = adf*sqrtf(1.0f+t*t); }
  else if (adf < ab){ float t = adf/ab; rt = ab*sqrtf(1.0f+t*t); }
  else rt = ab*sqrtf(2.0f);
  int sgn1;
  if (sm < 0.0f){ rt1 = 0.5f*(sm-rt); sgn1 = -1; rt2 = (acmx/rt1)*acmn - (b/rt1)*b; }
  else if (sm > 0.0f){ rt1 = 0.5f*(sm+rt); sgn1 = 1; rt2 = (acmx/rt1)*acmn - (b/rt1)*b; }
  else { rt1 = 0.5f*rt; rt2 = -0.5f*rt; sgn1 = 1; }
  float cs; int sgn2;
  if (df >= 0.0f){ cs = df + rt; sgn2 = 1; } else { cs = df - rt; sgn2 = -1; }
  float acs = fabsf(cs);
  if (acs > ab){
    float ct = -tb/cs; sn1 = 1.0f/sqrtf(1.0f+ct*ct); cs1 = ct*sn1;
  } else {
    if (ab == 0.0f){ cs1 = 1.0f; sn1 = 0.0f; }
    else { float tn = -cs/tb; cs1 = 1.0f/sqrtf(1.0f+tn*tn); sn1 = tn*cs1; }
  }
  if (sgn1 == sgn2){ float tn = cs1; cs1 = -sn1; sn1 = tn; }
}

// f32 ssytd2('L') + ssteqr('I') for 4x4; returns eigvec of largest eigenvalue.
__device__ void sym4_quat_f32(float (&a)[4][4], float* q){
  float d[4], e[3];
  float tau0 = 0.0f, tau1 = 0.0f;
  float v31 = 0.0f, v41 = 0.0f, v42 = 0.0f;
  {
    float alpha = a[1][0];
    float x1 = a[2][0], x2 = a[3][0];
    float xnorm = sqrtf(x1*x1 + x2*x2);
    if (xnorm == 0.0f){ tau0 = 0.0f; e[0] = alpha; }
    else {
      float beta = -s_sign(slapy2(alpha, xnorm), alpha);
      tau0 = (beta - alpha)/beta;
      float sc = 1.0f/(alpha - beta);
      x1 *= sc; x2 *= sc;
      e[0] = beta;
      float p0 = tau0*(a[1][1] + a[2][1]*x1 + a[3][1]*x2);
      float p1 = tau0*(a[2][1] + a[2][2]*x1 + a[3][2]*x2);
      float p2 = tau0*(a[3][1] + a[3][2]*x1 + a[3][3]*x2);
      float al = -0.5f*tau0*(p0 + p1*x1 + p2*x2);
      p0 += al; p1 += al*x1; p2 += al*x2;
      a[1][1] -= 2.0f*p0;
      a[2][1] -= x1*p0 + p1;
      a[3][1] -= x2*p0 + p2;
      a[2][2] -= 2.0f*x1*p1;
      a[3][2] -= x2*p1 + p2*x1;
      a[3][3] -= 2.0f*x2*p2;
    }
    v31 = x1; v41 = x2;
  }
  {
    float alpha = a[2][1];
    float x1 = a[3][1];
    float xnorm = fabsf(x1);
    if (xnorm == 0.0f){ tau1 = 0.0f; e[1] = alpha; }
    else {
      float beta = -s_sign(slapy2(alpha, xnorm), alpha);
      tau1 = (beta - alpha)/beta;
      x1 *= 1.0f/(alpha - beta);
      e[1] = beta;
      float p0 = tau1*(a[2][2] + a[3][2]*x1);
      float p1 = tau1*(a[3][2] + a[3][3]*x1);
      float al = -0.5f*tau1*(p0 + p1*x1);
      p0 += al; p1 += al*x1;
      a[2][2] -= 2.0f*p0;
      a[3][2] -= x1*p0 + p1;
      a[3][3] -= 2.0f*x1*p1;
    }
    v42 = x1;
  }
  e[2] = a[3][2];
  d[0]=a[0][0]; d[1]=a[1][1]; d[2]=a[2][2]; d[3]=a[3][3];
  float z[4][4] = {{1,0,0,0},{0,1,0,0},{0,0,1,0},{0,0,0,1}};
  const float eps = F32_EPS;
  const float eps2 = F32_EPS2;
  const float safmin = F32_SAFMIN;
  int jtot = 0;
  const int nmaxit = 120;
  int l1 = 0;
  bool fail = false;
  while (!fail){
    if (l1 > 3) break;
    if (l1 > 0) e[l1-1] = 0.0f;
    int lend = 3;
    for (int mm = l1; mm <= 2; ++mm){
      float tst = fabsf(e[mm]);
      if (tst == 0.0f){ lend = mm; break; }
      if (tst <= (sqrtf(fabsf(d[mm]))*sqrtf(fabsf(d[mm+1])))*eps){ e[mm] = 0.0f; lend = mm; break; }
    }
    int l = l1;
    int lsv = l, lendsv = lend;
    l1 = lend + 1;
    if (lend == l) continue;
    float anorm = fabsf(d[l]);
    for (int ii=l+1; ii<=lend; ++ii) anorm = fmaxf(anorm, fabsf(d[ii]));
    for (int ii=l; ii<lend; ++ii)    anorm = fmaxf(anorm, fabsf(e[ii]));
    if (anorm == 0.0f) continue;
    if (fabsf(d[lend]) < fabsf(d[l])){ lend = lsv; l = lendsv; }
    if (lend > l){
      for (;;){
        int m = lend;
        if (l != lend){
          for (int mm=l; mm<=lend-1; ++mm){
            float tst = e[mm]*e[mm];
            if (tst <= (eps2*fabsf(d[mm]))*fabsf(d[mm+1]) + safmin){ m = mm; break; }
          }
        }
        if (m < lend) e[m] = 0.0f;
        float p = d[l];
        if (m == l){
          d[l] = p; ++l;
          if (l <= lend) continue;
          break;
        }
        if (m == l+1){
          float rt1, rt2, c, s;
          slaev2(d[l], e[l], d[l+1], rt1, rt2, c, s);
          #pragma unroll
          for (int r2=0;r2<4;r2++){
            float t_ = z[r2][l+1];
            z[r2][l+1] = c*t_ - s*z[r2][l];
            z[r2][l]   = s*t_ + c*z[r2][l];
          }
          d[l]=rt1; d[l+1]=rt2; e[l]=0.0f;
          l += 2;
          if (l <= lend) continue;
          break;
        }
        if (jtot == nmaxit){ fail = true; break; }
        ++jtot;
        float g = (d[l+1]-p)/(2.0f*e[l]);
        float r_ = slapy2(g, 1.0f);
        g = d[m] - p + e[l]/(g + s_sign(r_, g));
        float s = 1.0f, c = 1.0f;
        p = 0.0f;
        float csv[3], snv[3];
        for (int i=m-1; i>=l; --i){
          float f = s*e[i], b = c*e[i];
          slartg(g, f, c, s, r_);
          if (i != m-1) e[i+1] = r_;
          g = d[i+1] - p;
          r_ = (d[i]-g)*s + 2.0f*c*b;
          p = s*r_;
          d[i+1] = g + p;
          g = c*r_ - b;
          csv[i] = c; snv[i] = -s;
        }
        for (int i=m-1; i>=l; --i){
          float cc = csv[i], ss = snv[i];
          #pragma unroll
          for (int r2=0;r2<4;r2++){
            float t_ = z[r2][i+1];
            z[r2][i+1] = cc*t_ - ss*z[r2][i];
            z[r2][i]   = ss*t_ + cc*z[r2][i];
          }
        }
        d[l] -= p; e[l] = g;
      }
    } else {
      for (;;){
        int m = lend;
        if (l != lend){
          for (int mm=l; mm>=lend+1; --mm){
            float tst = e[mm-1]*e[mm-1];
            if (tst <= (eps2*fabsf(d[mm]))*fabsf(d[mm-1]) + safmin){ m = mm; break; }
          }
        }
        if (m > lend) e[m-1] = 0.0f;
        float p = d[l];
        if (m == l){
          d[l] = p; --l;
          if (l >= lend) continue;
          break;
        }
        if (m == l-1){
          float rt1, rt2, c, s;
          slaev2(d[l-1], e[l-1], d[l], rt1, rt2, c, s);
          #pragma unroll
          for (int r2=0;r2<4;r2++){
            float t_ = z[r2][l];
            z[r2][l]   = c*t_ - s*z[r2][l-1];
            z[r2][l-1] = s*t_ + c*z[r2][l-1];
          }
          d[l-1]=rt1; d[l]=rt2; e[l-1]=0.0f;
          l -= 2;
          if (l >= lend) continue;
          break;
        }
        if (jtot == nmaxit){ fail = true; break; }
        ++jtot;
        float g = (d[l-1]-p)/(2.0f*e[l-1]);
        float r_ = slapy2(g, 1.0f);
        g = d[m] - p + e[l-1]/(g + s_sign(r_, g));
        float s = 1.0f, c = 1.0f;
        p = 0.0f;
        float csv[3], snv[3];
        for (int i=m; i<=l-1; ++i){
          float f = s*e[i], b = c*e[i];
          slartg(g, f, c, s, r_);
          if (i != m) e[i-1] = r_;
          g = d[i] - p;
          r_ = (d[i+1]-g)*s + 2.0f*c*b;
          p = s*r_;
          d[i] = g + p;
          g = c*r_ - b;
          csv[i] = c; snv[i] = s;
        }
        for (int i=m; i<=l-1; ++i){
          float cc = csv[i], ss = snv[i];
          #pragma unroll
          for (int r2=0;r2<4;r2++){
            float t_ = z[r2][i+1];
            z[r2][i+1] = cc*t_ - ss*z[r2][i];
            z[r2][i]   = ss*t_ + cc*z[r2][i];
          }
        }
        d[l] -= p; e[l-1] = g;
      }
    }
  }
  for (int ii=1; ii<4; ++ii){
    int i0 = ii-1, k0 = i0;
    float p = d[i0];
    for (int j2=ii; j2<4; ++j2) if (d[j2] < p){ k0 = j2; p = d[j2]; }
    if (k0 != i0){
      d[k0] = d[i0]; d[i0] = p;
      #pragma unroll
      for (int r2=0;r2<4;r2++){ float t_ = z[r2][i0]; z[r2][i0] = z[r2][k0]; z[r2][k0] = t_; }
    }
  }
  float w0 = z[0][3], w1 = z[1][3], w2 = z[2][3], w3 = z[3][3];
  if (tau1 != 0.0f){
    float dv = w2 + v42*w3;
    w2 -= tau1*dv;
    w3 -= tau1*dv*v42;
  }
  if (tau0 != 0.0f){
    float dv = w1 + v31*w2 + v41*w3;
    w1 -= tau0*dv;
    w2 -= tau0*dv*v31;
    w3 -= tau0*dv*v41;
  }
  q[0]=w0; q[1]=w1; q[2]=w2; q[3]=w3;
}

// ---------------- kernels ----------------
__global__ void fill_kernel(float* __restrict__ p, int nelem, float val){
  int i = blockIdx.x*blockDim.x + threadIdx.x;
  if (i < nelem) p[i] = val;
}

// Pre-split W2 (3 layers) into transposed bf16 hi/lo: out[l][j][k]
__global__ __launch_bounds__(256) void wsplit2_kernel(const float* __restrict__ W2,
    unsigned short* __restrict__ hi, unsigned short* __restrict__ lo){
  int idx = blockIdx.x*256 + threadIdx.x;
  int l = idx >> 16; int rem = idx & 65535; int k = rem >> 8; int j = rem & 255;
  float v = W2[(size_t)l*65536 + (size_t)k*256 + j];
  unsigned short hb = bf16_rne(v);
  float hf = __uint_as_float(((unsigned int)hb)<<16);
  unsigned short lb = bf16_rne(v - hf);
  size_t o = (size_t)l*65536 + (size_t)j*256 + k;
  hi[o] = hb; lo[o] = lb;
}

// Build W1eff^T (3 layers): [l][j][k], k<448
__global__ __launch_bounds__(256) void wsplit1_kernel(const float* __restrict__ W1,
    unsigned short* __restrict__ hi, unsigned short* __restrict__ lo){
  int idx = blockIdx.x*256 + threadIdx.x;
  if (idx >= 3*256*WK) return;
  int l = idx / (256*WK); int rem = idx - l*(256*WK);
  int j = rem / WK; int k = rem - j*WK;
  const float* Wl = W1 + (size_t)l*710*EMB;
  float v = 0.0f;
  if (k < 256) v = Wl[(size_t)(256+k)*EMB + j];
  else if (k < 416){ int kk = k-256; if (kk < 153) v = Wl[(size_t)(557+kk)*EMB + j]; }
  else if (k < 432){ int r = k-416; if (r < 15) v = Wl[(size_t)(527+r)*EMB + j] - Wl[(size_t)(542+r)*EMB + j]; }
  unsigned short hb = bf16_rne(v);
  float hf = __uint_as_float(((unsigned int)hb)<<16);
  unsigned short lb = bf16_rne(v - hf);
  size_t o = (size_t)l*(256*WK) + (size_t)j*WK + k;
  hi[o] = hb; lo[o] = lb;
}

// Split in_W (1280x256) transposed: out[j][k]
__global__ __launch_bounds__(256) void wsplit0_kernel(const float* __restrict__ W0,
    unsigned short* __restrict__ hi, unsigned short* __restrict__ lo){
  int idx = blockIdx.x*256 + threadIdx.x;
  if (idx >= IND*EMB) return;
  int k = idx >> 8; int j = idx & 255;
  float v = W0[(size_t)k*EMB + j];
  unsigned short hb = bf16_rne(v);
  float hf = __uint_as_float(((unsigned int)hb)<<16);
  unsigned short lb = bf16_rne(v - hf);
  size_t o = (size_t)j*IND + k;
  hi[o] = hb; lo[o] = lb;
}

__global__ void rigid_kernel(const float* __restrict__ bb, float* __restrict__ Rg, float* __restrict__ tg){
  int n = blockIdx.x*blockDim.x + threadIdx.x;
  if (n >= NN) return;
  const float* p = bb + (size_t)n*9;
  float nx=p[0],ny=p[1],nz=p[2], cax=p[3],cay=p[4],caz=p[5], cx=p[6],cy=p[7],cz=p[8];
  float e1x=cx-cax, e1y=cy-cay, e1z=cz-caz;
  float n1 = sqrtf(e1x*e1x+e1y*e1y+e1z*e1z);
  e1x/=n1; e1y/=n1; e1z/=n1;
  float ux=nx-cax, uy=ny-cay, uz=nz-caz;
  float du = ux*e1x+uy*e1y+uz*e1z;
  float e2x=ux-du*e1x, e2y=uy-du*e1y, e2z=uz-du*e1z;
  float n2 = sqrtf(e2x*e2x+e2y*e2y+e2z*e2z);
  e2x/=n2; e2y/=n2; e2z/=n2;
  float e3x=e1y*e2z-e1z*e2y, e3y=e1z*e2x-e1x*e2z, e3z=e1x*e2y-e1y*e2x;
  float* R = Rg + (size_t)n*9;
  R[0]=e1x; R[1]=e2x; R[2]=e3x;
  R[3]=e1y; R[4]=e2y; R[5]=e3y;
  R[6]=e1z; R[7]=e2z; R[8]=e3z;
  tg[(size_t)n*3+0]=cax; tg[(size_t)n*3+1]=cay; tg[(size_t)n*3+2]=caz;
}

// Fused LN + emb0 via MFMA. 16 nodes/block, wave-local LN stats (shfl).
__global__ __launch_bounds__(256) void ln_emb0_kernel(const float* __restrict__ x,
    const float* __restrict__ lg, const float* __restrict__ lb,
    const unsigned short* __restrict__ W0Thi, const unsigned short* __restrict__ W0Tlo,
    const float* __restrict__ bias, float* __restrict__ emb){
  int n0 = blockIdx.x*16, j = threadIdx.x;
  int l = j & 63, w = j >> 6;
  __shared__ __align__(16) unsigned short chi[16*XK];
  __shared__ __align__(16) unsigned short clo[16*XK];
  __shared__ float smu[16], srs[16];
  for (int rr=0; rr<4; rr++){
    int r = rr*4 + w;
    float vals[20];
    float s = 0.0f;
    #pragma unroll
    for (int u=0;u<20;u++){ vals[u] = x[(size_t)(n0+r)*IND + u*64 + l]; s += vals[u]; }
    #pragma unroll
    for (int o=32;o>0;o>>=1) s += __shfl_xor(s, o);
    float mu = s*(1.0f/IND);
    float pv = 0.0f;
    #pragma unroll
    for (int u=0;u<20;u++){ float dd = vals[u]-mu; pv += dd*dd; }
    #pragma unroll
    for (int o=32;o>0;o>>=1) pv += __shfl_xor(pv, o);
    float rs = 1.0f/sqrtf(pv*(1.0f/IND) + 1e-5f);
    if (l == 0){ smu[r] = mu; srs[r] = rs; }
  }
  __syncthreads();
  f32x4 acc[4];
  #pragma unroll
  for (int nt=0;nt<4;nt++)
    #pragma unroll
    for (int rg=0;rg<4;rg++) acc[nt][rg] = 0.0f;
  for (int ch=0; ch<5; ch++){
    for (int idx=j; idx<16*256; idx+=256){
      int r = idx>>8, k = idx&255;
      int kk = ch*256 + k;
      float v = lg[kk]*((x[(size_t)(n0+r)*IND + kk]-smu[r])*srs[r]) + lb[kk];
      unsigned short hb = bf16_rne(v);
      float hf = __uint_as_float(((unsigned int)hb)<<16);
      chi[r*XK+k] = hb;
      clo[r*XK+k] = bf16_rne(v - hf);
    }
    __syncthreads();
    for (int kt=0;kt<8;kt++){
      int k0 = kt*32 + (l>>4)*8;
      int row = l&15;
      bf16x8 aH = __builtin_bit_cast(bf16x8, *(const s16x8*)&chi[row*XK + k0]);
      bf16x8 aL = __builtin_bit_cast(bf16x8, *(const s16x8*)&clo[row*XK + k0]);
      #pragma unroll
      for (int nt=0;nt<4;nt++){
        int colj = w*64 + nt*16 + (l&15);
        size_t wb = (size_t)colj*IND + ch*256 + k0;
        bf16x8 Bh = __builtin_bit_cast(bf16x8, *(const s16x8*)&W0Thi[wb]);
        bf16x8 Bl = __builtin_bit_cast(bf16x8, *(const s16x8*)&W0Tlo[wb]);
        acc[nt] = __builtin_amdgcn_mfma_f32_16x16x32_bf16(aH, Bh, acc[nt], 0,0,0);
        acc[nt] = __builtin_amdgcn_mfma_f32_16x16x32_bf16(aH, Bl, acc[nt], 0,0,0);
        acc[nt] = __builtin_amdgcn_mfma_f32_16x16x32_bf16(aL, Bh, acc[nt], 0,0,0);
      }
    }
    __syncthreads();
  }
  #pragma unroll
  for (int nt=0;nt<4;nt++){
    int colj = w*64 + nt*16 + (l&15);
    float bv = bias[colj];
    #pragma unroll
    for (int rg=0;rg<4;rg++){
      int row = (l>>4)*4 + rg;
      emb[(size_t)(n0+row)*EMB + colj] = acc[nt][rg] + bv;
    }
  }
}

__global__ __launch_bounds__(64) void edge_kernel(const float* __restrict__ bb,
    const float* __restrict__ Rg, const float* __restrict__ tg,
    const int* __restrict__ col, float* __restrict__ Redge, float* __restrict__ eattr){
  int e = blockIdx.x*64 + threadIdx.x;
  if (e >= EE) return;
  int i = e/KK;
  int jn = col[e];
  float Ri[9], Rj[9];
  #pragma unroll
  for (int a=0;a<9;a++){ Ri[a]=Rg[(size_t)i*9+a]; Rj[a]=Rg[(size_t)jn*9+a]; }
  float dt0 = tg[(size_t)jn*3+0]-tg[(size_t)i*3+0];
  float dt1 = tg[(size_t)jn*3+1]-tg[(size_t)i*3+1];
  float dt2 = tg[(size_t)jn*3+2]-tg[(size_t)i*3+2];
  float Re[9];
  #pragma unroll
  for (int a=0;a<3;a++){
    #pragma unroll
    for (int c=0;c<3;c++)
      Re[a*3+c] = Ri[0+a]*Rj[0+c] + Ri[3+a]*Rj[3+c] + Ri[6+a]*Rj[6+c];
  }
  float te0 = Ri[0]*dt0 + Ri[3]*dt1 + Ri[6]*dt2;
  float te1 = Ri[1]*dt0 + Ri[4]*dt1 + Ri[7]*dt2;
  float te2 = Ri[2]*dt0 + Ri[5]*dt1 + Ri[8]*dt2;
  float xx=Re[0], xy=Re[1], xz=Re[2], yx=Re[3], yy=Re[4], yz=Re[5], zx=Re[6], zy=Re[7], zz=Re[8];
  float km[4][4];
  km[0][0]=(xx+yy+zz)/3.0f; km[0][1]=(zy-yz)/3.0f;    km[0][2]=(xz-zx)/3.0f;    km[0][3]=(yx-xy)/3.0f;
  km[1][0]=km[0][1];        km[1][1]=(xx-yy-zz)/3.0f; km[1][2]=(xy+yx)/3.0f;    km[1][3]=(xz+zx)/3.0f;
  km[2][0]=km[0][2];        km[2][1]=km[1][2];        km[2][2]=(yy-xx-zz)/3.0f; km[2][3]=(yz+zy)/3.0f;
  km[3][0]=km[0][3];        km[3][1]=km[1][3];        km[3][2]=km[2][3];        km[3][3]=(zz-xx-yy)/3.0f;
  float q[4];
  sym4_quat_f32(km, q);
  float* ea = eattr + (size_t)e*EAP;
  ea[0]=q[0]; ea[1]=q[1]; ea[2]=q[2]; ea[3]=q[3];
  ea[4]=te0;  ea[5]=te1;  ea[6]=te2;
  int cd = i - jn; if (cd < 0) cd = -cd;
  ea[7] = logf((float)cd + 1.0f);
  ea[8] = logf(sqrtf(te0*te0+te1*te1+te2*te2) + 1e-8f);
  const float* bi = bb + (size_t)i*9;
  const float* bj = bb + (size_t)jn*9;
  int idx = 9;
  #pragma unroll
  for (int a=0;a<3;a++){
    float ax=bi[a*3+0], ay=bi[a*3+1], az=bi[a*3+2];
    #pragma unroll
    for (int b2=0;b2<3;b2++){
      float dx=ax-bj[b2*3+0], dy=ay-bj[b2*3+1], dz=az-bj[b2*3+2];
      float dd = sqrtf(fmaxf(dx*dx+dy*dy+dz*dz, 1e-12f));
      #pragma unroll
      for (int kb=0;kb<16;kb++){
        float muv = 1.3333334f*(float)kb;
        float df = dd - muv;
        ea[idx] = expf(-0.5f*df*df);
        idx++;
      }
    }
  }
  ea[153]=0.0f; ea[154]=0.0f; ea[155]=0.0f;
  #pragma unroll
  for (int a=0;a<9;a++) Redge[(size_t)e*9+a] = Re[a];
}

// Fused: phase B AND phase C via MFMA bf16x2-split; emb/eattr/vjr reg-cached across passes.
__global__ __launch_bounds__(256, 4) void fused_kernel(
    const float* __restrict__ emb_in, const float* __restrict__ v_in,
    const float* __restrict__ Redge, const float* __restrict__ eattr,
    const int* __restrict__ col,
    const float* __restrict__ W1, const float* __restrict__ b1,
    const unsigned short* __restrict__ W1Thi, const unsigned short* __restrict__ W1Tlo,
    const unsigned short* __restrict__ W2Thi, const unsigned short* __restrict__ W2Tlo,
    const float* __restrict__ b2,
    const float* __restrict__ W3, const float* __restrict__ b3,
    const float* __restrict__ vW,
    const float* __restrict__ lng, const float* __restrict__ lnb,
    float* __restrict__ emb_out, float* __restrict__ vu_out){
  int n = blockIdx.x, j = threadIdx.x;
  size_t e0 = (size_t)n*KK;
  __shared__ __align__(16) char smem[36864];
  __shared__ float s_xi[EMB];
  __shared__ float s_vi[16];
  unsigned short* Abuf = (unsigned short*)smem;    // [32][AK]
  unsigned short* h1hi = (unsigned short*)smem;    // [32][H1K]
  unsigned short* h1lo = h1hi + 32*H1K;
  float* cshb = (float*)(smem + 33792);
  float* sbuf = (float*)(smem + 34816);
  float* rbuf = (float*)(smem + 35840);

  s_xi[j] = emb_in[(size_t)n*EMB + j];
  if (j < 16) s_vi[j] = (j < V3) ? v_in[(size_t)n*V3 + j] : 0.0f;

  float femb[KK];    // reg-cache: gathered emb
  float fea[19];     // reg-cache: eattr slice
  float fvj[4];      // reg-cache: vjr slice
  // ---- stage A pass 0 (hi) ----
  #pragma unroll 1
  for (int e=0;e<KK;e++){
    int cj = col[e0+e];
    float v = emb_in[(size_t)cj*EMB + j];
    femb[e] = v;
    Abuf[e*AK + j] = bf16_rne(v);
  }
  {
    int u = 0;
    for (int idx=j; idx<KK*160; idx+=256, ++u){
      int e = idx/160, kk = idx - e*160;
      float v = (kk < 156) ? eattr[(e0+e)*EAP + kk] : 0.0f;
      fea[u] = v;
      Abuf[e*AK + 256 + kk] = bf16_rne(v);
    }
  }
  {
    int u = 0;
    for (int idx=j; idx<KK*32; idx+=256, ++u){
      int e = idx>>5, r = idx&31;
      float v = 0.0f;
      if (r < V3){
        int m = r/3, ii = r - m*3;
        int cj = col[e0+e];
        const float* Rp = Redge + (e0+e)*9;
        const float* vp = v_in + (size_t)cj*V3 + m*3;
        v = Rp[ii*3+0]*vp[0] + Rp[ii*3+1]*vp[1] + Rp[ii*3+2]*vp[2];
      }
      fvj[u] = v;
      Abuf[e*AK + 416 + r] = bf16_rne(v);
    }
  }
  for (int idx=j; idx<2*WK; idx+=256){
    int rr = 30 + idx/WK, c = idx%WK;
    Abuf[rr*AK + c] = 0;
  }
  __syncthreads();

  // csh (exact f32)
  {
    float csh = b1[j];
    for (int k=0;k<EMB;k+=4){
      float w0=W1[(size_t)(k+0)*EMB+j], w1=W1[(size_t)(k+1)*EMB+j], w2=W1[(size_t)(k+2)*EMB+j], w3=W1[(size_t)(k+3)*EMB+j];
      csh += s_xi[k+0]*w0 + s_xi[k+1]*w1 + s_xi[k+2]*w2 + s_xi[k+3]*w3;
    }
    #pragma unroll
    for (int r=0;r<V3;r++) csh += s_vi[r]*(W1[(size_t)(512+r)*EMB+j] + W1[(size_t)(542+r)*EMB+j]);
    cshb[j] = csh;
  }

  int l = j & 63, w = j >> 6;
  f32x4 cacc[2][4];
  #pragma unroll
  for (int mt=0;mt<2;mt++)
    #pragma unroll
    for (int nt=0;nt<4;nt++)
      #pragma unroll
      for (int rg=0;rg<4;rg++) cacc[mt][nt][rg] = 0.0f;

  // pass 1: aH x (Bh, Bl)
  for (int kt=0;kt<14;kt++){
    int k0 = kt*32 + (l>>4)*8;
    bf16x8 aH[2];
    #pragma unroll
    for (int mt=0;mt<2;mt++){
      int row = mt*16 + (l&15);
      aH[mt] = __builtin_bit_cast(bf16x8, *(const s16x8*)&Abuf[row*AK + k0]);
    }
    #pragma unroll
    for (int nt=0;nt<4;nt++){
      int colj = w*64 + nt*16 + (l&15);
      bf16x8 Bh = __builtin_bit_cast(bf16x8, *(const s16x8*)&W1Thi[(size_t)colj*WK + k0]);
      bf16x8 Bl = __builtin_bit_cast(bf16x8, *(const s16x8*)&W1Tlo[(size_t)colj*WK + k0]);
      #pragma unroll
      for (int mt=0;mt<2;mt++){
        cacc[mt][nt] = __builtin_amdgcn_mfma_f32_16x16x32_bf16(aH[mt], Bh, cacc[mt][nt], 0,0,0);
        cacc[mt][nt] = __builtin_amdgcn_mfma_f32_16x16x32_bf16(aH[mt], Bl, cacc[mt][nt], 0,0,0);
      }
    }
  }
  __syncthreads();
  // ---- stage A pass 1 (lo) — all values from reg-caches ----
  #pragma unroll 1
  for (int e=0;e<KK;e++){
    float v = femb[e];
    unsigned short hb = bf16_rne(v);
    float hf = __uint_as_float(((unsigned int)hb)<<16);
    Abuf[e*AK + j] = bf16_rne(v - hf);
  }
  {
    int u = 0;
    for (int idx=j; idx<KK*160; idx+=256, ++u){
      int e = idx/160, kk = idx - e*160;
      float v = fea[u];
      unsigned short hb = bf16_rne(v);
      float hf = __uint_as_float(((unsigned int)hb)<<16);
      Abuf[e*AK + 256 + kk] = bf16_rne(v - hf);
    }
  }
  {
    int u = 0;
    for (int idx=j; idx<KK*32; idx+=256, ++u){
      int e = idx>>5, r = idx&31;
      float v = fvj[u];
      unsigned short hb = bf16_rne(v);
      float hf = __uint_as_float(((unsigned int)hb)<<16);
      Abuf[e*AK + 416 + r] = bf16_rne(v - hf);
    }
  }
  for (int idx=j; idx<2*WK; idx+=256){
    int rr = 30 + idx/WK, c = idx%WK;
    Abuf[rr*AK + c] = 0;
  }
  __syncthreads();
  // pass 2: aL x Bh
  for (int kt=0;kt<14;kt++){
    int k0 = kt*32 + (l>>4)*8;
    bf16x8 aL[2];
    #pragma unroll
    for (int mt=0;mt<2;mt++){
      int row = mt*16 + (l&15);
      aL[mt] = __builtin_bit_cast(bf16x8, *(const s16x8*)&Abuf[row*AK + k0]);
    }
    #pragma unroll
    for (int nt=0;nt<4;nt++){
      int colj = w*64 + nt*16 + (l&15);
      bf16x8 Bh = __builtin_bit_cast(bf16x8, *(const s16x8*)&W1Thi[(size_t)colj*WK + k0]);
      #pragma unroll
      for (int mt=0;mt<2;mt++)
        cacc[mt][nt] = __builtin_amdgcn_mfma_f32_16x16x32_bf16(aL[mt], Bh, cacc[mt][nt], 0,0,0);
    }
  }
  __syncthreads();
  // epilogue phase B: h1 = gelu(acc + csh[col]); split -> h1hi/h1lo
  #pragma unroll
  for (int mt=0;mt<2;mt++){
    #pragma unroll
    for (int nt=0;nt<4;nt++){
      int colj = w*64 + nt*16 + (l&15);
      float cshv = cshb[colj];
      #pragma unroll
      for (int rg=0;rg<4;rg++){
        int row = mt*16 + ((l>>4)&3)*4 + rg;
        float val = 0.0f;
        if (row < KK) val = gelu_f(cacc[mt][nt][rg] + cshv);
        unsigned short hb = bf16_rne(val);
        float hf = __uint_as_float(((unsigned int)hb)<<16);
        unsigned short lb = bf16_rne(val - hf);
        h1hi[row*H1K + colj] = hb;
        h1lo[row*H1K + colj] = lb;
      }
    }
  }
  __syncthreads();

  // ---- phase C: h2 via MFMA ----
  f32x4 dacc[2][4];
  #pragma unroll
  for (int mt=0;mt<2;mt++)
    #pragma unroll
    for (int nt=0;nt<4;nt++)
      #pragma unroll
      for (int rg=0;rg<4;rg++) dacc[mt][nt][rg] = 0.0f;
  for (int kt=0;kt<8;kt++){
    int k0 = kt*32 + (l>>4)*8;
    bf16x8 aH[2], aL[2];
    #pragma unroll
    for (int mt=0;mt<2;mt++){
      int row = mt*16 + (l&15);
      aH[mt] = __builtin_bit_cast(bf16x8, *(const s16x8*)&h1hi[row*H1K + k0]);
      aL[mt] = __builtin_bit_cast(bf16x8, *(const s16x8*)&h1lo[row*H1K + k0]);
    }
    #pragma unroll
    for (int nt=0;nt<4;nt++){
      int colj = w*64 + nt*16 + (l&15);
      bf16x8 Bh = __builtin_bit_cast(bf16x8, *(const s16x8*)&W2Thi[(size_t)colj*256 + k0]);
      bf16x8 Bl = __builtin_bit_cast(bf16x8, *(const s16x8*)&W2Tlo[(size_t)colj*256 + k0]);
      #pragma unroll
      for (int mt=0;mt<2;mt++){
        dacc[mt][nt] = __builtin_amdgcn_mfma_f32_16x16x32_bf16(aH[mt], Bh, dacc[mt][nt], 0,0,0);
        dacc[mt][nt] = __builtin_amdgcn_mfma_f32_16x16x32_bf16(aH[mt], Bl, dacc[mt][nt], 0,0,0);
        dacc[mt][nt] = __builtin_amdgcn_mfma_f32_16x16x32_bf16(aL[mt], Bh, dacc[mt][nt], 0,0,0);
      }
    }
  }
  {
    float p[4];
    #pragma unroll
    for (int nt=0;nt<4;nt++){
      float b2v = b2[w*64 + nt*16 + (l&15)];
      float pp = 0.0f;
      #pragma unroll
      for (int mt=0;mt<2;mt++){
        #pragma unroll
        for (int rg=0;rg<4;rg++){
          int row = mt*16 + ((l>>4)&3)*4 + rg;
          if (row < KK) pp += gelu_f(dacc[mt][nt][rg] + b2v);
        }
      }
      pp += __shfl_xor(pp, 16);
      pp += __shfl_xor(pp, 32);
      p[nt] = pp;
    }
    if (l < 16){
      #pragma unroll
      for (int nt=0;nt<4;nt++) sbuf[w*64 + nt*16 + l] = p[nt];
    }
  }
  __syncthreads();
  // ---- epilogue: W3 dot, LN, vu ----
  float ag = 0.0f;
  for (int k=0;k<EMB;k+=4){
    float4 s4 = *(const float4*)&sbuf[k];
    ag += s4.x*W3[(size_t)(k+0)*EMB+j] + s4.y*W3[(size_t)(k+1)*EMB+j]
        + s4.z*W3[(size_t)(k+2)*EMB+j] + s4.w*W3[(size_t)(k+3)*EMB+j];
  }
  ag = ag*(1.0f/30.0f) + b3[j];
  float u = s_xi[j] + ag;
  float mu = bsumf(u, rbuf)*(1.0f/EMB);
  float dl = u - mu;
  float var = bsumf(dl*dl, rbuf)*(1.0f/EMB);
  float rs = 1.0f/sqrtf(var + 1e-5f);
  float y = lng[j]*dl*rs + lnb[j];
  emb_out[(size_t)n*EMB+j] = y;
  __syncthreads();
  sbuf[j] = y;
  __syncthreads();
  if (j < V3){
    float a = s_vi[j];
    for (int k=0;k<EMB;k++){
      a += sbuf[k]*vW[k*V3+j];
    }
    #pragma unroll
    for (int r=0;r<V3;r++) a += s_vi[r]*vW[(EMB+r)*V3+j];
    vu_out[(size_t)n*V3+j] = a;
  }
}

// Pure QR per graph (f32 sgeqr2/sorg2r, raw LAPACK signs).
// Same formula sequence as R14; dot products now block-parallel (LDS tree).
__global__ __launch_bounds__(256) void qr_kernel(
    const float* __restrict__ vu_in, float* __restrict__ vout){
  int g = blockIdx.x, t = threadIdx.x;
  __shared__ float A[QRM*QRN];
  __shared__ float rbuf[256];
  __shared__ float meanv[V3];
  __shared__ float taus[QRN];
  int n = g*LSZ + t;
  #pragma unroll
  for (int j=0;j<V3;j++) A[t*V3+j] = vu_in[(size_t)n*V3 + j];
  __syncthreads();
  if (t < V3){
    float s = 0.0f;
    for (int l0=0;l0<LSZ;l0++) s += A[l0*V3+t];
    meanv[t] = s/(float)LSZ;
  }
  __syncthreads();
  #pragma unroll
  for (int j=0;j<V3;j++) A[t*V3+j] -= meanv[j];
  __syncthreads();
  // ---- sgeqr2 ----
  for (int i=0;i<QRN;i++){
    float ps = 0.0f;
    for (int r=i+1+t; r<QRM; r+=256){ float x = A[r*QRN+i]; ps += x*x; }
    float xn2 = bsumf(ps, rbuf);
    float alpha = A[i*QRN+i];           // unchanged by the scale below (row i untouched)
    float taui = 0.0f, sc = 1.0f;
    if (xn2 != 0.0f){
      float beta = -s_sign(slapy2(alpha, sqrtf(xn2)), alpha);
      taui = (beta - alpha)/beta;
      sc = 1.0f/(alpha - beta);
    }
    for (int r=i+1+t; r<QRM; r+=256) A[r*QRN+i] *= sc;
    if (t == 0) taus[i] = taui;
    __syncthreads();
    for (int j=i+1;j<QRN;j++){
      float pp = 0.0f;
      for (int r=i+t; r<QRM; r+=256){
        float vr = (r==i) ? 1.0f : A[r*QRN+i];
        pp += vr*A[r*QRN+j];
      }
      float wv = taui * bsumf(pp, rbuf);
      for (int r=i+t; r<QRM; r+=256){
        float vr = (r==i) ? 1.0f : A[r*QRN+i];
        A[r*QRN+j] -= wv*vr;
      }
      __syncthreads();
    }
  }
  // ---- sorg2r ----
  for (int i=QRN-1;i>=0;i--){
    float taui = taus[i];
    for (int j=i+1;j<QRN;j++){
      float pp = 0.0f;
      for (int r=i+t; r<QRM; r+=256){
        float vr = (r==i) ? 1.0f : A[r*QRN+i];
        pp += vr*A[r*QRN+j];
      }
      float wv = taui * bsumf(pp, rbuf);
      for (int r=i+t; r<QRM; r+=256){
        float vr = (r==i) ? 1.0f : A[r*QRN+i];
        A[r*QRN+j] -= wv*vr;
      }
      __syncthreads();
    }
    for (int r=i+1+t; r<QRM; r+=256) A[r*QRN+i] *= -taui;
    __syncthreads();
    if (t == 0) A[i*QRN+i] = 1.0f - taui;
    if (t < i) A[t*QRN+i] = 0.0f;
    __syncthreads();
  }
  for (int idx=t; idx<QRM*QRN; idx+=256)
    vout[(size_t)g*LSZ*V3 + idx] = 16.0f*A[idx];
}

__global__ __launch_bounds__(256) void final_kernel(const float* __restrict__ embf,
    const float* __restrict__ vf, const float* __restrict__ Rg, float* __restrict__ out){
  int n = blockIdx.x, t = threadIdx.x;
  out[(size_t)n*EMB + t] = embf[(size_t)n*EMB + t];
  if (t < V3){
    int m = t/3, ii = t - m*3;
    const float* Rp = Rg + (size_t)n*9;
    const float* vp = vf + (size_t)n*V3 + m*3;
    float val = Rp[ii*3+0]*vp[0] + Rp[ii*3+1]*vp[1] + Rp[ii*3+2]*vp[2];
    out[(size_t)NN*EMB + (size_t)n*V3 + t] = val;
  }
}

// ---------------- host ----------------
extern "C" void kernel_launch(void* const* d_in, const int* in_sizes, int n_in,
                              void* d_out, int out_size, void* d_ws, size_t ws_size,
                              hipStream_t stream){
  (void)in_sizes; (void)n_in; (void)out_size; (void)ws_size;
  const float* x       = (const float*)d_in[0];
  const float* bb      = (const float*)d_in[1];
  const float* in_ln_g = (const float*)d_in[2];
  const float* in_ln_b = (const float*)d_in[3];
  const float* in_W    = (const float*)d_in[4];
  const float* in_b    = (const float*)d_in[5];
  const float* msg_W1  = (const float*)d_in[6];
  const float* msg_b1  = (const float*)d_in[7];
  const float* msg_W2  = (const float*)d_in[8];
  const float* msg_b2  = (const float*)d_in[9];
  const float* msg_W3  = (const float*)d_in[10];
  const float* msg_b3  = (const float*)d_in[11];
  const float* vect_W  = (const float*)d_in[12];
  const float* ln_g    = (const float*)d_in[13];
  const float* ln_b    = (const float*)d_in[14];
  const int*   col     = (const int*)d_in[16];

  char* p = (char*)d_ws;
  auto alloc = [&](size_t bytes)->void*{ void* r = (void*)p; p += (bytes + 255) & ~(size_t)255; return r; };
  float*  Rg    = (float*) alloc((size_t)NN*9*4);
  float*  tg    = (float*) alloc((size_t)NN*3*4);
  float*  eA    = (float*) alloc((size_t)NN*EMB*4);
  float*  eB    = (float*) alloc((size_t)NN*EMB*4);
  float*  vA    = (float*) alloc((size_t)NN*V3*4);
  float*  vB    = (float*) alloc((size_t)NN*V3*4);
  float*  vu    = (float*) alloc((size_t)NN*V3*4);
  float*  Redge = (float*) alloc((size_t)EE*9*4);
  float*  eattr = (float*) alloc((size_t)EE*EAP*4);
  unsigned short* W2Thi = (unsigned short*)alloc((size_t)3*65536*2);
  unsigned short* W2Tlo = (unsigned short*)alloc((size_t)3*65536*2);
  unsigned short* W1Thi = (unsigned short*)alloc((size_t)3*256*WK*2);
  unsigned short* W1Tlo = (unsigned short*)alloc((size_t)3*256*WK*2);
  unsigned short* W0Thi = (unsigned short*)alloc((size_t)IND*EMB*2);
  unsigned short* W0Tlo = (unsigned short*)alloc((size_t)IND*EMB*2);

  const int NV = NN*V3;
  fill_kernel<<<(NV+255)/256, 256, 0, stream>>>(vA, NV, 0.0f);
  wsplit2_kernel<<<768, 256, 0, stream>>>(msg_W2, W2Thi, W2Tlo);
  wsplit1_kernel<<<(3*256*WK+255)/256, 256, 0, stream>>>(msg_W1, W1Thi, W1Tlo);
  wsplit0_kernel<<<(IND*EMB+255)/256, 256, 0, stream>>>(in_W, W0Thi, W0Tlo);
  rigid_kernel<<<(NN+63)/64, 64, 0, stream>>>(bb, Rg, tg);
  ln_emb0_kernel<<<NN/16, 256, 0, stream>>>(x, in_ln_g, in_ln_b, W0Thi, W0Tlo, in_b, eA);
  edge_kernel<<<(EE+63)/64, 64, 0, stream>>>(bb, Rg, tg, col, Redge, eattr);

  float* ein = eA; float* eout = eB; float* vin = vA; float* vout = vB;
  for (int l=0; l<3; ++l){
    fused_kernel<<<NN, 256, 0, stream>>>(ein, vin, Redge, eattr, col,
        msg_W1 + (size_t)l*710*EMB, msg_b1 + (size_t)l*EMB,
        W1Thi + (size_t)l*256*WK, W1Tlo + (size_t)l*256*WK,
        W2Thi + (size_t)l*65536, W2Tlo + (size_t)l*65536,
        msg_b2 + (size_t)l*EMB,
        msg_W3 + (size_t)l*EMB*EMB, msg_b3 + (size_t)l*EMB,
        vect_W + (size_t)l*(EMB+V3)*V3,
        ln_g + (size_t)l*EMB, ln_b + (size_t)l*EMB, eout, vu);
    qr_kernel<<<NG, 256, 0, stream>>>(vu, vout);
    float* tmp = ein; ein = eout; eout = tmp;
    tmp = vin; vin = vout; vout = tmp;
  }
  final_kernel<<<NN, 256, 0, stream>>>(ein, vin, Rg, (float*)d_out);
}